// Round 15
// baseline (878.622 us; speedup 1.0000x reference)
//
#include <hip/hip_runtime.h>
#include <stdint.h>

typedef unsigned int u32;
typedef unsigned long long u64;
typedef __attribute__((ext_vector_type(8))) short v8s;   // 8 bf16 = 4 VGPR (MFMA A/B frag)
typedef __attribute__((ext_vector_type(4))) float v4f;   // MFMA C/D frag

#define HH 64
#define WW 96
#define HW 6144
#define CC 512
#define NANCH 55296
#define PRE 6000
#define POST 300
#define CAP 8192
#define PW 98
#define PH 66
#define ICPAD 40

__device__ __constant__ float c_aw[9] = {184.f,368.f,736.f,128.f,256.f,512.f,88.f,176.f,352.f};
__device__ __constant__ float c_ah[9] = {96.f,192.f,384.f,128.f,256.f,512.f,176.f,352.f,704.f};

__device__ __forceinline__ unsigned short bf16_rne(float x){
  u32 u = __float_as_uint(x);
  return (unsigned short)((u + 0x7FFFu + ((u >> 16) & 1u)) >> 16);
}
__device__ __forceinline__ u32 sortkey(float s){
  u32 u = __float_as_uint(s);
  return u ^ ((u & 0x80000000u) ? 0xFFFFFFFFu : 0x80000000u);
}

// ---------- K0: merged convert (X: 528 blocks, W: 512 blocks) + ws zeroing ----------
__global__ __launch_bounds__(256) void k_cvt(const float* __restrict__ X, const float* __restrict__ Wt,
                                             unsigned short* __restrict__ Xih, unsigned short* __restrict__ Xil,
                                             unsigned short* __restrict__ Wh2, unsigned short* __restrict__ Wl2,
                                             u32* __restrict__ zero_region){
  __shared__ float Ls[64][97];
  __shared__ float Ws[4608];
  const int b = blockIdx.x, tid = threadIdx.x;
  { int gid = b*256 + tid;
    if (gid < 131072) zero_region[gid] = 0u;          // hist + hist2
    if (gid < 16) zero_region[131072 + gid] = 0u; }   // ctr
  if (b < 528){
    const int rp  = b % 66;
    const int ic0 = (b / 66) * 64;
    const bool zrow = (rp == 0 || rp == PH-1);
    if (!zrow){
      int r = rp - 1;
      for (int i = tid; i < 6144; i += 256){
        int ii = i / 96, c = i - ii*96;
        Ls[ii][c] = X[(ic0+ii)*HW + r*WW + c];
      }
    }
    __syncthreads();
    for (int i = tid; i < PW*64; i += 256){
      int cp = i >> 6, icl = i & 63;
      float x = 0.f;
      if (!zrow && cp >= 1 && cp <= 96) x = Ls[icl][cp-1];
      unsigned short h = bf16_rne(x);
      float hf = __uint_as_float(((u32)h) << 16);
      unsigned short l = bf16_rne(x - hf);
      long o = ((long)(rp*PW + cp) << 9) + ic0 + icl;
      Xih[o] = h; Xil[o] = l;
    }
  } else {
    const int oc = b - 528;
    for (int i = tid; i < 4608; i += 256) Ws[i] = Wt[oc*4608 + i];
    __syncthreads();
    for (int i = tid; i < 4608; i += 256){
      int tap = i / 512, ic = i - tap*512;
      float x = Ws[ic*9 + tap];
      unsigned short h = bf16_rne(x);
      float hf = __uint_as_float(((u32)h) << 16);
      unsigned short l = bf16_rne(x - hf);
      long o = ((long)(tap*512 + oc) << 9) + ic;
      Wh2[o] = h; Wl2[o] = l;
    }
  }
}

// ---------- K1: MFMA conv, LDS-staged + R15 register double-buffer ----------
// R14 busy-cycle sum (~80 us) vs measured 184 us -> ~100 us exposed staging/barrier
// latency at 1 wave/SIMD. Slab k+1's A/B u64s now held in registers during compute
// of slab k (+112 VGPR; 1 wave/SIMD has 512). MFMA order IDENTICAL -> bit-exact Y.
__global__ __launch_bounds__(256, 1) void k_conv3(
    const unsigned short* __restrict__ Xih, const unsigned short* __restrict__ Xil,
    const unsigned short* __restrict__ Wh2, const unsigned short* __restrict__ Wl2,
    const float* __restrict__ Bc, float* __restrict__ Y)
{
  __shared__ __attribute__((aligned(16))) unsigned short Ah[6*98*ICPAD];
  __shared__ __attribute__((aligned(16))) unsigned short Al[6*98*ICPAD];
  __shared__ __attribute__((aligned(16))) unsigned short Bh[9*32*ICPAD];
  __shared__ __attribute__((aligned(16))) unsigned short Bl[9*32*ICPAD];
  const int tid  = threadIdx.x;
  const int w    = tid >> 6;
  const int lane = tid & 63;
  const int lm   = lane & 15;
  const int q    = lane >> 4;
  const int y0   = blockIdx.x * 4;
  const int oc0  = blockIdx.y * 32;

  v4f acc[6][2];
  #pragma unroll
  for (int t = 0; t < 6; ++t)
    #pragma unroll
    for (int n = 0; n < 2; ++n)
      acc[t][n] = (v4f){0.f,0.f,0.f,0.f};

  u64 ra[19][2], rb[9][2];
  auto loadSlab = [&](int icg){
    #pragma unroll
    for (int n = 0; n < 19; ++n){
      int it = tid + 256*n;
      if (it < 4704){
        int i4 = it & 7, rc = it >> 3;
        int c = rc % 98, r = rc / 98;
        long src = ((long)((y0 + r)*PW + c) << 9) + icg*32 + i4*4;
        ra[n][0] = *reinterpret_cast<const u64*>(Xih + src);
        ra[n][1] = *reinterpret_cast<const u64*>(Xil + src);
      }
    }
    #pragma unroll
    for (int n = 0; n < 9; ++n){
      int it = tid + 256*n;
      if (it < 2304){
        int i4 = it & 7, to = it >> 3;
        int oc = to & 31, tap = to >> 5;
        long src = ((long)(tap*512 + oc0 + oc) << 9) + icg*32 + i4*4;
        rb[n][0] = *reinterpret_cast<const u64*>(Wh2 + src);
        rb[n][1] = *reinterpret_cast<const u64*>(Wl2 + src);
      }
    }
  };
  auto storeSlab = [&](){
    #pragma unroll
    for (int n = 0; n < 19; ++n){
      int it = tid + 256*n;
      if (it < 4704){
        int i4 = it & 7, rc = it >> 3;
        int dst = rc*ICPAD + i4*4;
        *reinterpret_cast<u64*>(Ah + dst) = ra[n][0];
        *reinterpret_cast<u64*>(Al + dst) = ra[n][1];
      }
    }
    #pragma unroll
    for (int n = 0; n < 9; ++n){
      int it = tid + 256*n;
      if (it < 2304){
        int i4 = it & 7, to = it >> 3;
        int dst = to*ICPAD + i4*4;
        *reinterpret_cast<u64*>(Bh + dst) = rb[n][0];
        *reinterpret_cast<u64*>(Bl + dst) = rb[n][1];
      }
    }
  };

  loadSlab(0);
  for (int icg = 0; icg < 16; ++icg){
    __syncthreads();                 // previous compute done reading LDS
    storeSlab();
    __syncthreads();                 // LDS ready
    if (icg < 15) loadSlab(icg + 1); // next slab in flight during compute
    #pragma unroll
    for (int tap = 0; tap < 9; ++tap){
      const int dy = tap / 3, dx = tap - dy*3;
      v8s ah[6], al[6], bh[2], bl[2];
      #pragma unroll
      for (int t = 0; t < 6; ++t){
        int a = ((w + dy)*98 + 16*t + lm + dx)*ICPAD + q*8;
        ah[t] = *reinterpret_cast<const v8s*>(Ah + a);
        al[t] = *reinterpret_cast<const v8s*>(Al + a);
      }
      #pragma unroll
      for (int n = 0; n < 2; ++n){
        int a = (tap*32 + n*16 + lm)*ICPAD + q*8;
        bh[n] = *reinterpret_cast<const v8s*>(Bh + a);
        bl[n] = *reinterpret_cast<const v8s*>(Bl + a);
      }
      #pragma unroll
      for (int t = 0; t < 6; ++t)
        #pragma unroll
        for (int n = 0; n < 2; ++n){
          acc[t][n] = __builtin_amdgcn_mfma_f32_16x16x32_bf16(al[t], bl[n], acc[t][n], 0, 0, 0);
          acc[t][n] = __builtin_amdgcn_mfma_f32_16x16x32_bf16(al[t], bh[n], acc[t][n], 0, 0, 0);
          acc[t][n] = __builtin_amdgcn_mfma_f32_16x16x32_bf16(ah[t], bl[n], acc[t][n], 0, 0, 0);
          acc[t][n] = __builtin_amdgcn_mfma_f32_16x16x32_bf16(ah[t], bh[n], acc[t][n], 0, 0, 0);
        }
    }
  }
  const int yrow = y0 + w;
  #pragma unroll
  for (int n = 0; n < 2; ++n){
    int oc = oc0 + n*16 + lm;
    float b = Bc[oc];
    #pragma unroll
    for (int t = 0; t < 6; ++t){
      float4 v;
      v.x = fmaxf(acc[t][n].x + b, 0.f);
      v.y = fmaxf(acc[t][n].y + b, 0.f);
      v.z = fmaxf(acc[t][n].z + b, 0.f);
      v.w = fmaxf(acc[t][n].w + b, 0.f);
      *reinterpret_cast<float4*>(Y + (long)oc*HW + yrow*WW + 16*t + q*4) = v;
    }
  }
}

// ---------------- K2: 1x1 heads + softmax + box decode (+ hist) — verbatim ----------------
__global__ __launch_bounds__(256) void k_head(
    const float* __restrict__ Y, const float* __restrict__ cw,
    const float* __restrict__ cb, const float* __restrict__ bw,
    const float* __restrict__ bb, const float* __restrict__ info,
    float* __restrict__ scores, float4* __restrict__ boxes, u32* __restrict__ hist)
{
  __shared__ float Ys[4096];
  __shared__ float Wsh[4096];
  const int tid = threadIdx.x;
  const int p0  = blockIdx.x * 64;
  const int po  = tid & 15;
  const int oj  = tid >> 4;
  float accM[4][4], accC[4][4];
  #pragma unroll
  for (int p = 0; p < 4; ++p)
    #pragma unroll
    for (int k = 0; k < 4; ++k){ accM[p][k] = 0.f; accC[p][k] = 0.f; }

  for (int c0 = 0; c0 < CC; c0 += 64){
    __syncthreads();
    for (int i = tid; i < 4096; i += 256){
      int c = i >> 6, p = i & 63;
      Ys[i] = Y[(c0 + c) * HW + p0 + p];
    }
    for (int i = tid; i < 4096; i += 256){
      int c = i >> 6, o = i & 63;
      int gc = c0 + c;
      float v = 0.f;
      if (o < 18) v = cw[o * 512 + gc];
      else if (o < 54) v = bw[(o - 18) * 512 + gc];
      Wsh[i] = v;
    }
    __syncthreads();
    for (int c = 0; c < 64; ++c){
      const float4 xv = *reinterpret_cast<const float4*>(Ys + c*64 + po*4);
      float xa[4] = {xv.x, xv.y, xv.z, xv.w};
      const float* wrd = Wsh + c*64 + oj;
      float wv[4] = {wrd[0], wrd[16], wrd[32], wrd[48]};
      #pragma unroll
      for (int p = 0; p < 4; ++p)
        #pragma unroll
        for (int k = 0; k < 4; ++k)
          accC[p][k] = __fmaf_rn(xa[p], wv[k], accC[p][k]);
    }
    #pragma unroll
    for (int p = 0; p < 4; ++p)
      #pragma unroll
      for (int k = 0; k < 4; ++k){ accM[p][k] += accC[p][k]; accC[p][k] = 0.f; }
  }
  __syncthreads();
  #pragma unroll
  for (int p = 0; p < 4; ++p)
    #pragma unroll
    for (int k = 0; k < 4; ++k){
      int o = oj + 16*k;
      float bias = (o < 18) ? cb[o] : ((o < 54) ? bb[o - 18] : 0.f);
      Ys[(po*4 + p)*64 + o] = accM[p][k] + bias;
    }
  __syncthreads();
  float imH = info[0], imW = info[1], imS = info[2];
  for (int it = tid; it < 576; it += 256){
    int pl = it / 9;
    int a  = it - pl*9;
    const float* L = Ys + pl*64;
    float l0 = L[a], l1 = L[9 + a];
    float mx = fmaxf(l0, l1);
    float e0 = expf(l0 - mx), e1 = expf(l1 - mx);
    float sc = e1 / (e0 + e1);
    float d0 = L[18 + a*4 + 0], d1 = L[18 + a*4 + 1];
    float d2 = L[18 + a*4 + 2], d3 = L[18 + a*4 + 3];
    int pos = p0 + pl;
    int yy = pos / 96;
    int xx = pos - yy * 96;
    float aw = c_aw[a], ah = c_ah[a];
    float acx = (float)(xx * 16 + 8);
    float acy = (float)(yy * 16 + 8);
    float cx = __fadd_rn(__fmul_rn(d0, aw), acx);
    float cy = __fadd_rn(__fmul_rn(d1, ah), acy);
    float pw = __fmul_rn(expf(d2), aw);
    float ph = __fmul_rn(expf(d3), ah);
    float hx = __fmul_rn(0.5f, pw);
    float hy = __fmul_rn(0.5f, ph);
    float x1 = fminf(fmaxf(__fadd_rn(cx, -hx), 0.f), imW - 1.f);
    float y1 = fminf(fmaxf(__fadd_rn(cy, -hy), 0.f), imH - 1.f);
    float x2 = fminf(fmaxf(__fadd_rn(cx,  hx), 0.f), imW - 1.f);
    float y2 = fminf(fmaxf(__fadd_rn(cy,  hy), 0.f), imH - 1.f);
    float ms = 16.f * imS;
    bool keep = ((x2 - x1 + 1.f) >= ms) && ((y2 - y1 + 1.f) >= ms);
    int g = pos * 9 + a;
    float val = keep ? sc : -__builtin_inff();
    scores[g] = val;
    boxes[g]  = make_float4(x1, y1, x2, y2);
    atomicAdd(&hist[sortkey(val) >> 16], 1u);
  }
}

// ---------- K3: fused selection — thresh1+hist2+thresh2+compact, ONE block (verbatim) ----------
__global__ __launch_bounds__(1024) void k_sel(const u32* __restrict__ hist, u32* __restrict__ hist2,
                                              const float* __restrict__ scores,
                                              u32* __restrict__ ctr, u64* __restrict__ keys){
  __shared__ u32 cs[1024];
  __shared__ u32 bs[64];
  __shared__ int selg;
  __shared__ u32 afterv, T16s, aboves, K32s;
  const int t = threadIdx.x;
  const int b0 = t * 64;

  if (t == 0) selg = -1;
  __syncthreads();
  { u32 s = 0;
    for (int i = 0; i < 64; ++i) s += hist[b0 + i];
    cs[t] = s; }
  __syncthreads();
  for (int off = 1; off < 1024; off <<= 1){
    u32 v = cs[t];
    u32 ad = (t + off < 1024) ? cs[t + off] : 0u;
    __syncthreads();
    cs[t] = v + ad;
    __syncthreads();
  }
  { u32 here  = cs[t];
    u32 after = (t < 1023) ? cs[t + 1] : 0u;
    if (here >= 6000u && after < 6000u){ selg = t; afterv = after; } }
  __syncthreads();
  { int g = selg;
    if (g >= 0 && t < 64) bs[t] = hist[g*64 + t];
    __syncthreads();
    if (t == 0){
      if (g < 0){ T16s = 0u; aboves = 0u; }
      else {
        u32 acc = afterv;
        for (int b = 63; b >= 0; --b){
          u32 h = bs[b];
          acc += h;
          if (acc >= 6000u){ T16s = (u32)(g*64 + b); aboves = acc - h; break; }
        }
      }
    } }
  __syncthreads();

  { u32 pfx = T16s;
    for (int i = t; i < NANCH; i += 1024){
      u32 key = sortkey(scores[i]);
      if ((key >> 16) == pfx) atomicAdd(&hist2[key & 0xFFFFu], 1u);
    } }
  __threadfence();
  __syncthreads();

  if (t == 0) selg = -1;
  __syncthreads();
  const u32 target = 6000u - aboves;
  { u32 s = 0;
    for (int i = 0; i < 64; ++i) s += hist2[b0 + i];
    cs[t] = s; }
  __syncthreads();
  for (int off = 1; off < 1024; off <<= 1){
    u32 v = cs[t];
    u32 ad = (t + off < 1024) ? cs[t + off] : 0u;
    __syncthreads();
    cs[t] = v + ad;
    __syncthreads();
  }
  { u32 here  = cs[t];
    u32 after = (t < 1023) ? cs[t + 1] : 0u;
    if (here >= target && after < target){ selg = t; afterv = after; } }
  __syncthreads();
  { int g = selg;
    if (g >= 0 && t < 64) bs[t] = hist2[g*64 + t];
    __syncthreads();
    if (t == 0){
      if (g < 0) K32s = (T16s << 16);
      else {
        u32 acc = afterv;
        for (int b = 63; b >= 0; --b){
          u32 h = bs[b];
          acc += h;
          if (acc >= target){ K32s = (T16s << 16) | (u32)(g*64 + b); break; }
        }
      }
      ctr[4] = 6000u;
    } }
  __syncthreads();

  { u32 K = K32s;
    for (int i = t; i < NANCH; i += 1024){
      u32 key = sortkey(scores[i]);
      if (key >= K){
        u32 pos = atomicAdd(&ctr[0], 1u);
        if (pos < CAP) keys[pos] = ((u64)key << 32) | (u64)(u32)(~(u32)i);
      }
    } }
}

// ---------------- K-rank (verbatim) ----------------
__global__ __launch_bounds__(128) void k_rank(const u64* __restrict__ keys, u32* __restrict__ ctr,
                                              const float4* __restrict__ boxes,
                                              float4* __restrict__ topB, float* __restrict__ topA){
  __shared__ u64 ks[2048];
  const int t  = threadIdx.x;
  const int gi = blockIdx.x * 128 + t;
  u32 count = ctr[0]; if (count > CAP) count = CAP;
  u64 my = (gi < (int)count) ? keys[gi] : 0ull;
  int rank = 0;
  for (int c0 = 0; c0 < CAP; c0 += 2048){
    __syncthreads();
    for (int s = t; s < 2048; s += 128){
      int j = c0 + s;
      ks[s] = (j < (int)count) ? keys[j] : 0ull;
    }
    __syncthreads();
    if (gi < (int)count){
      const ulonglong2* kp = reinterpret_cast<const ulonglong2*>(ks);
      #pragma unroll 8
      for (int s = 0; s < 1024; ++s){
        ulonglong2 kv = kp[s];
        rank += (kv.x > my) + (kv.y > my);
      }
    }
  }
  if (gi < (int)count && rank < PRE){
    if (!((my >> 32) & 0x80000000ull))
      atomicMin((int*)(ctr + 4), rank);
    u32 idx = ~(u32)my;
    float4 bv = make_float4(0.f,0.f,0.f,0.f);
    float area = 1.f;
    if (idx < NANCH){
      bv = boxes[idx];
      area = (bv.z - bv.x + 1.f) * (bv.w - bv.y + 1.f);
    }
    topB[rank] = bv;
    topA[rank] = area;
  }
}

// ---------------- NMS stage A: suppression bit-matrix M[6000][188] (verbatim) ----------------
__global__ __launch_bounds__(256) void k_iou(const float4* __restrict__ topB, const float* __restrict__ topA,
                                             u32* __restrict__ M){
  __shared__ float4 jb[3072];
  const int tid = threadIdx.x;
  const int rr  = tid & 31;
  const int wg  = tid >> 5;
  const int i   = blockIdx.x * 32 + rr;
  float4 bi = make_float4(0.f,0.f,0.f,0.f); float ai = 1.f;
  if (i < PRE){ bi = topB[i]; ai = topA[i]; }
  for (int ph = 0; ph < 2; ++ph){
    __syncthreads();
    for (int s = tid; s < 3072; s += 256){
      int j = ph*3072 + s;
      jb[s] = (j < PRE) ? topB[j] : make_float4(0.f,0.f,0.f,0.f);
    }
    __syncthreads();
    if (i >= PRE) continue;
    int nw = (ph == 0) ? 96 : 92;
    #pragma unroll
    for (int m = 0; m < 12; ++m){
      int wl = wg + 8*m;
      if (wl >= nw) continue;
      int w = ph*96 + wl;
      int jbase = w * 32;
      if (jbase + 31 <= i){ M[(size_t)i*188 + w] = 0u; continue; }
      u32 bits = 0u;
      for (int s = 0; s < 32; ++s){
        int j = jbase + s;
        if (j <= i || j >= PRE) continue;
        float4 bj = jb[j - ph*3072];
        float aj = (bj.z - bj.x + 1.f) * (bj.w - bj.y + 1.f);
        float xx1 = fmaxf(bi.x, bj.x);
        float yy1 = fmaxf(bi.y, bj.y);
        float xx2 = fminf(bi.z, bj.z);
        float yy2 = fminf(bi.w, bj.w);
        float iw = fmaxf(xx2 - xx1 + 1.f, 0.f);
        float ih = fmaxf(yy2 - yy1 + 1.f, 0.f);
        float inter = iw * ih;
        float iou = inter / (ai + aj - inter);
        if (iou > 0.7f) bits |= (1u << s);
      }
      M[(size_t)i*188 + w] = bits;
    }
  }
}

// ---------------- NMS stage B: single-wave greedy scan + depth-1 branchless spec prefetch ----------------
// R15: after picking i, compute c1 = next clear bit IGNORING row(i) and issue its row
// load; next step, if pick==c1 (one wave-uniform compare), the row has been in flight
// a full step (~900 cyc hidden). Rows are static, so stale prefetches remain valid.
// (R6's failure was 4-deep + data-dependent reuse branches; this is depth-1, uniform.)
__global__ __launch_bounds__(64) void k_reduce(const u32* __restrict__ M, const float4* __restrict__ topB,
                                               const u32* __restrict__ ctr, float* __restrict__ out){
  __shared__ int kept[POST];
  const int t = threadIdx.x;
  int validN = (int)ctr[0];
  int finN   = (int)ctr[4];
  if (finN < validN) validN = finN;
  if (validN > PRE)  validN = PRE;
  auto initw = [&](int w)->u32{
    if (w >= 188) return 0xFFFFFFFFu;
    int lo = w * 32;
    if (lo + 32 <= validN) return 0u;
    if (lo >= validN) return 0xFFFFFFFFu;
    return ~((1u << (validN - lo)) - 1u);
  };
  u32 s0 = initw(t), s1 = initw(64 + t), s2 = initw(128 + t);

  auto ffc = [&](u32 a0, u32 a1, u32 a2)->int{
    u64 b0 = __ballot(a0 != 0xFFFFFFFFu);
    if (b0){
      int L = (int)__ffsll((unsigned long long)b0) - 1;
      u32 v = (u32)__shfl((int)a0, L, 64);
      return L*32 + (__ffs((int)(~v)) - 1);
    }
    u64 b1 = __ballot(a1 != 0xFFFFFFFFu);
    if (b1){
      int L = (int)__ffsll((unsigned long long)b1) - 1;
      u32 v = (u32)__shfl((int)a1, L, 64);
      return 2048 + L*32 + (__ffs((int)(~v)) - 1);
    }
    u64 b2 = __ballot(a2 != 0xFFFFFFFFu);
    if (b2){
      int L = (int)__ffsll((unsigned long long)b2) - 1;
      u32 v = (u32)__shfl((int)a2, L, 64);
      return 4096 + L*32 + (__ffs((int)(~v)) - 1);
    }
    return -1;
  };
  auto setbit = [&](u32& a0, u32& a1, u32& a2, int i){
    int iw = i >> 5, ib = i & 31;
    if (iw == t) a0 |= (1u << ib);
    else if (iw == 64 + t) a1 |= (1u << ib);
    else if (iw == 128 + t) a2 |= (1u << ib);
  };

  u32 P0 = 0u, P1 = 0u, P2 = 0u;
  int pc = -1;
  for (int k = 0; k < POST; ++k){
    int i = ffc(s0, s1, s2);
    if (t == 0) kept[k] = i;
    if (i < 0) continue;
    u32 r0, r1, r2;
    if (i == pc){ r0 = P0; r1 = P1; r2 = P2; }      // spec hit: row in flight since last step
    else {
      const u32* row = M + (size_t)i * 188;
      r0 = row[t];
      r1 = (64 + t < 188) ? row[64 + t] : 0u;
      r2 = (128 + t < 188) ? row[128 + t] : 0u;
    }
    // speculate next pick assuming row(i) suppresses nothing among remaining
    {
      u32 a0 = s0, a1 = s1, a2 = s2;
      setbit(a0, a1, a2, i);
      int c1 = ffc(a0, a1, a2);
      if (c1 >= 0 && c1 != pc){
        const u32* prow = M + (size_t)c1 * 188;
        P0 = prow[t];
        P1 = (64 + t < 188) ? prow[64 + t] : 0u;
        P2 = (128 + t < 188) ? prow[128 + t] : 0u;
        pc = c1;
      } else if (c1 < 0) pc = -1;
    }
    s0 |= r0; s1 |= r1; s2 |= r2;
    setbit(s0, s1, s2, i);
  }
  __syncthreads();
  for (int q = t; q < 1500; q += 64){
    int r = q / 5, c = q - r*5;
    int i = kept[r];
    float v = 0.f;
    if (i >= 0 && c > 0){
      float4 bx = topB[i];
      v = (c == 1) ? bx.x : (c == 2) ? bx.y : (c == 3) ? bx.z : bx.w;
    }
    out[q] = v;
  }
}

// ---------------- launch ----------------
extern "C" void kernel_launch(void* const* d_in, const int* in_sizes, int n_in,
                              void* d_out, int out_size, void* d_ws, size_t ws_size,
                              hipStream_t stream)
{
  const float* fm   = (const float*)d_in[0];
  const float* info = (const float*)d_in[1];
  const float* cw3  = (const float*)d_in[2];
  const float* cb3  = (const float*)d_in[3];
  const float* clw  = (const float*)d_in[4];
  const float* clb  = (const float*)d_in[5];
  const float* bbw  = (const float*)d_in[6];
  const float* bbb  = (const float*)d_in[7];
  float* out = (float*)d_out;

  char* base = (char*)d_ws;
  u32*   hist   = (u32*)  (base + 0);          // 65536 u32
  u32*   hist2  = (u32*)  (base + 262144);     // 65536 u32
  u32*   ctr    = (u32*)  (base + 524288);     // [0]=count [4]=finiteN
  float* Y      = (float*)(base + 524544);     // 12.58 MB
  u32*   M      = (u32*)  (base + 524544);     // overlays Y (dead after k_head): 4.5 MB
  float* scores = (float*)(base + 13107456);
  float4* boxes = (float4*)(base + 13328640);
  u64*   keys   = (u64*)  (base + 14213376);
  float4* topB  = (float4*)(base + 14278912);
  float* topA   = (float*)(base + 14375168);
  unsigned short* Xih = (unsigned short*)(base + 14399488);
  unsigned short* Xil = (unsigned short*)(base + 21022720);
  unsigned short* Wh2 = (unsigned short*)(base + 27645952);
  unsigned short* Wl2 = (unsigned short*)(base + 32364544);
  // total ws use: ~37.1 MB

  k_cvt   <<<1040, 256, 0, stream>>>(fm, cw3, Xih, Xil, Wh2, Wl2, (u32*)base);
  k_conv3 <<<dim3(16, 16), 256, 0, stream>>>(Xih, Xil, Wh2, Wl2, cb3, Y);
  k_head  <<<96,  256, 0, stream>>>(Y, clw, clb, bbw, bbb, info, scores, boxes, hist);
  k_sel   <<<1,  1024, 0, stream>>>(hist, hist2, scores, ctr, keys);
  k_rank  <<<64,  128, 0, stream>>>(keys, ctr, boxes, topB, topA);
  k_iou   <<<188, 256, 0, stream>>>(topB, topA, M);
  k_reduce<<<1,    64, 0, stream>>>(M, topB, ctr, out);
}

// Round 16
// 763.837 us; speedup vs baseline: 1.1503x; 1.1503x over previous
//
#include <hip/hip_runtime.h>
#include <stdint.h>

typedef unsigned int u32;
typedef unsigned long long u64;
typedef __attribute__((ext_vector_type(8))) short v8s;   // 8 bf16 = 4 VGPR (MFMA A/B frag)
typedef __attribute__((ext_vector_type(4))) float v4f;   // MFMA C/D frag

#define HH 64
#define WW 96
#define HW 6144
#define CC 512
#define NANCH 55296
#define PRE 6000
#define POST 300
#define CAP 8192
#define PW 98
#define PH 66
#define ICPAD 40

__device__ __constant__ float c_aw[9] = {184.f,368.f,736.f,128.f,256.f,512.f,88.f,176.f,352.f};
__device__ __constant__ float c_ah[9] = {96.f,192.f,384.f,128.f,256.f,512.f,176.f,352.f,704.f};

__device__ __forceinline__ unsigned short bf16_rne(float x){
  u32 u = __float_as_uint(x);
  return (unsigned short)((u + 0x7FFFu + ((u >> 16) & 1u)) >> 16);
}
__device__ __forceinline__ u32 sortkey(float s){
  u32 u = __float_as_uint(s);
  return u ^ ((u & 0x80000000u) ? 0xFFFFFFFFu : 0x80000000u);
}

// ---------- K0: merged convert (X: 528 blocks, W: 512 blocks) + ws zeroing ----------
__global__ __launch_bounds__(256) void k_cvt(const float* __restrict__ X, const float* __restrict__ Wt,
                                             unsigned short* __restrict__ Xih, unsigned short* __restrict__ Xil,
                                             unsigned short* __restrict__ Wh2, unsigned short* __restrict__ Wl2,
                                             u32* __restrict__ zero_region){
  __shared__ float Ls[64][97];
  __shared__ float Ws[4608];
  const int b = blockIdx.x, tid = threadIdx.x;
  { int gid = b*256 + tid;
    if (gid < 131072) zero_region[gid] = 0u;          // hist + hist2
    if (gid < 16) zero_region[131072 + gid] = 0u; }   // ctr
  if (b < 528){
    const int rp  = b % 66;
    const int ic0 = (b / 66) * 64;
    const bool zrow = (rp == 0 || rp == PH-1);
    if (!zrow){
      int r = rp - 1;
      for (int i = tid; i < 6144; i += 256){
        int ii = i / 96, c = i - ii*96;
        Ls[ii][c] = X[(ic0+ii)*HW + r*WW + c];
      }
    }
    __syncthreads();
    for (int i = tid; i < PW*64; i += 256){
      int cp = i >> 6, icl = i & 63;
      float x = 0.f;
      if (!zrow && cp >= 1 && cp <= 96) x = Ls[icl][cp-1];
      unsigned short h = bf16_rne(x);
      float hf = __uint_as_float(((u32)h) << 16);
      unsigned short l = bf16_rne(x - hf);
      long o = ((long)(rp*PW + cp) << 9) + ic0 + icl;
      Xih[o] = h; Xil[o] = l;
    }
  } else {
    const int oc = b - 528;
    for (int i = tid; i < 4608; i += 256) Ws[i] = Wt[oc*4608 + i];
    __syncthreads();
    for (int i = tid; i < 4608; i += 256){
      int tap = i / 512, ic = i - tap*512;
      float x = Ws[ic*9 + tap];
      unsigned short h = bf16_rne(x);
      float hf = __uint_as_float(((u32)h) << 16);
      unsigned short l = bf16_rne(x - hf);
      long o = ((long)(tap*512 + oc) << 9) + ic;
      Wh2[o] = h; Wl2[o] = l;
    }
  }
}

// ---------- K1: MFMA conv, LDS-staged + register double-buffer (R15-proven, bit-exact) ----------
__global__ __launch_bounds__(256, 1) void k_conv3(
    const unsigned short* __restrict__ Xih, const unsigned short* __restrict__ Xil,
    const unsigned short* __restrict__ Wh2, const unsigned short* __restrict__ Wl2,
    const float* __restrict__ Bc, float* __restrict__ Y)
{
  __shared__ __attribute__((aligned(16))) unsigned short Ah[6*98*ICPAD];
  __shared__ __attribute__((aligned(16))) unsigned short Al[6*98*ICPAD];
  __shared__ __attribute__((aligned(16))) unsigned short Bh[9*32*ICPAD];
  __shared__ __attribute__((aligned(16))) unsigned short Bl[9*32*ICPAD];
  const int tid  = threadIdx.x;
  const int w    = tid >> 6;
  const int lane = tid & 63;
  const int lm   = lane & 15;
  const int q    = lane >> 4;
  const int y0   = blockIdx.x * 4;
  const int oc0  = blockIdx.y * 32;

  v4f acc[6][2];
  #pragma unroll
  for (int t = 0; t < 6; ++t)
    #pragma unroll
    for (int n = 0; n < 2; ++n)
      acc[t][n] = (v4f){0.f,0.f,0.f,0.f};

  u64 ra[19][2], rb[9][2];
  auto loadSlab = [&](int icg){
    #pragma unroll
    for (int n = 0; n < 19; ++n){
      int it = tid + 256*n;
      if (it < 4704){
        int i4 = it & 7, rc = it >> 3;
        int c = rc % 98, r = rc / 98;
        long src = ((long)((y0 + r)*PW + c) << 9) + icg*32 + i4*4;
        ra[n][0] = *reinterpret_cast<const u64*>(Xih + src);
        ra[n][1] = *reinterpret_cast<const u64*>(Xil + src);
      }
    }
    #pragma unroll
    for (int n = 0; n < 9; ++n){
      int it = tid + 256*n;
      if (it < 2304){
        int i4 = it & 7, to = it >> 3;
        int oc = to & 31, tap = to >> 5;
        long src = ((long)(tap*512 + oc0 + oc) << 9) + icg*32 + i4*4;
        rb[n][0] = *reinterpret_cast<const u64*>(Wh2 + src);
        rb[n][1] = *reinterpret_cast<const u64*>(Wl2 + src);
      }
    }
  };
  auto storeSlab = [&](){
    #pragma unroll
    for (int n = 0; n < 19; ++n){
      int it = tid + 256*n;
      if (it < 4704){
        int i4 = it & 7, rc = it >> 3;
        int dst = rc*ICPAD + i4*4;
        *reinterpret_cast<u64*>(Ah + dst) = ra[n][0];
        *reinterpret_cast<u64*>(Al + dst) = ra[n][1];
      }
    }
    #pragma unroll
    for (int n = 0; n < 9; ++n){
      int it = tid + 256*n;
      if (it < 2304){
        int i4 = it & 7, to = it >> 3;
        int dst = to*ICPAD + i4*4;
        *reinterpret_cast<u64*>(Bh + dst) = rb[n][0];
        *reinterpret_cast<u64*>(Bl + dst) = rb[n][1];
      }
    }
  };

  loadSlab(0);
  for (int icg = 0; icg < 16; ++icg){
    __syncthreads();
    storeSlab();
    __syncthreads();
    if (icg < 15) loadSlab(icg + 1);
    #pragma unroll
    for (int tap = 0; tap < 9; ++tap){
      const int dy = tap / 3, dx = tap - dy*3;
      v8s ah[6], al[6], bh[2], bl[2];
      #pragma unroll
      for (int t = 0; t < 6; ++t){
        int a = ((w + dy)*98 + 16*t + lm + dx)*ICPAD + q*8;
        ah[t] = *reinterpret_cast<const v8s*>(Ah + a);
        al[t] = *reinterpret_cast<const v8s*>(Al + a);
      }
      #pragma unroll
      for (int n = 0; n < 2; ++n){
        int a = (tap*32 + n*16 + lm)*ICPAD + q*8;
        bh[n] = *reinterpret_cast<const v8s*>(Bh + a);
        bl[n] = *reinterpret_cast<const v8s*>(Bl + a);
      }
      #pragma unroll
      for (int t = 0; t < 6; ++t)
        #pragma unroll
        for (int n = 0; n < 2; ++n){
          acc[t][n] = __builtin_amdgcn_mfma_f32_16x16x32_bf16(al[t], bl[n], acc[t][n], 0, 0, 0);
          acc[t][n] = __builtin_amdgcn_mfma_f32_16x16x32_bf16(al[t], bh[n], acc[t][n], 0, 0, 0);
          acc[t][n] = __builtin_amdgcn_mfma_f32_16x16x32_bf16(ah[t], bl[n], acc[t][n], 0, 0, 0);
          acc[t][n] = __builtin_amdgcn_mfma_f32_16x16x32_bf16(ah[t], bh[n], acc[t][n], 0, 0, 0);
        }
    }
  }
  const int yrow = y0 + w;
  #pragma unroll
  for (int n = 0; n < 2; ++n){
    int oc = oc0 + n*16 + lm;
    float b = Bc[oc];
    #pragma unroll
    for (int t = 0; t < 6; ++t){
      float4 v;
      v.x = fmaxf(acc[t][n].x + b, 0.f);
      v.y = fmaxf(acc[t][n].y + b, 0.f);
      v.z = fmaxf(acc[t][n].z + b, 0.f);
      v.w = fmaxf(acc[t][n].w + b, 0.f);
      *reinterpret_cast<float4*>(Y + (long)oc*HW + yrow*WW + 16*t + q*4) = v;
    }
  }
}

// ---------------- K2: 1x1 heads + softmax + box decode (+ hist) — verbatim ----------------
__global__ __launch_bounds__(256) void k_head(
    const float* __restrict__ Y, const float* __restrict__ cw,
    const float* __restrict__ cb, const float* __restrict__ bw,
    const float* __restrict__ bb, const float* __restrict__ info,
    float* __restrict__ scores, float4* __restrict__ boxes, u32* __restrict__ hist)
{
  __shared__ float Ys[4096];
  __shared__ float Wsh[4096];
  const int tid = threadIdx.x;
  const int p0  = blockIdx.x * 64;
  const int po  = tid & 15;
  const int oj  = tid >> 4;
  float accM[4][4], accC[4][4];
  #pragma unroll
  for (int p = 0; p < 4; ++p)
    #pragma unroll
    for (int k = 0; k < 4; ++k){ accM[p][k] = 0.f; accC[p][k] = 0.f; }

  for (int c0 = 0; c0 < CC; c0 += 64){
    __syncthreads();
    for (int i = tid; i < 4096; i += 256){
      int c = i >> 6, p = i & 63;
      Ys[i] = Y[(c0 + c) * HW + p0 + p];
    }
    for (int i = tid; i < 4096; i += 256){
      int c = i >> 6, o = i & 63;
      int gc = c0 + c;
      float v = 0.f;
      if (o < 18) v = cw[o * 512 + gc];
      else if (o < 54) v = bw[(o - 18) * 512 + gc];
      Wsh[i] = v;
    }
    __syncthreads();
    for (int c = 0; c < 64; ++c){
      const float4 xv = *reinterpret_cast<const float4*>(Ys + c*64 + po*4);
      float xa[4] = {xv.x, xv.y, xv.z, xv.w};
      const float* wrd = Wsh + c*64 + oj;
      float wv[4] = {wrd[0], wrd[16], wrd[32], wrd[48]};
      #pragma unroll
      for (int p = 0; p < 4; ++p)
        #pragma unroll
        for (int k = 0; k < 4; ++k)
          accC[p][k] = __fmaf_rn(xa[p], wv[k], accC[p][k]);
    }
    #pragma unroll
    for (int p = 0; p < 4; ++p)
      #pragma unroll
      for (int k = 0; k < 4; ++k){ accM[p][k] += accC[p][k]; accC[p][k] = 0.f; }
  }
  __syncthreads();
  #pragma unroll
  for (int p = 0; p < 4; ++p)
    #pragma unroll
    for (int k = 0; k < 4; ++k){
      int o = oj + 16*k;
      float bias = (o < 18) ? cb[o] : ((o < 54) ? bb[o - 18] : 0.f);
      Ys[(po*4 + p)*64 + o] = accM[p][k] + bias;
    }
  __syncthreads();
  float imH = info[0], imW = info[1], imS = info[2];
  for (int it = tid; it < 576; it += 256){
    int pl = it / 9;
    int a  = it - pl*9;
    const float* L = Ys + pl*64;
    float l0 = L[a], l1 = L[9 + a];
    float mx = fmaxf(l0, l1);
    float e0 = expf(l0 - mx), e1 = expf(l1 - mx);
    float sc = e1 / (e0 + e1);
    float d0 = L[18 + a*4 + 0], d1 = L[18 + a*4 + 1];
    float d2 = L[18 + a*4 + 2], d3 = L[18 + a*4 + 3];
    int pos = p0 + pl;
    int yy = pos / 96;
    int xx = pos - yy * 96;
    float aw = c_aw[a], ah = c_ah[a];
    float acx = (float)(xx * 16 + 8);
    float acy = (float)(yy * 16 + 8);
    float cx = __fadd_rn(__fmul_rn(d0, aw), acx);
    float cy = __fadd_rn(__fmul_rn(d1, ah), acy);
    float pw = __fmul_rn(expf(d2), aw);
    float ph = __fmul_rn(expf(d3), ah);
    float hx = __fmul_rn(0.5f, pw);
    float hy = __fmul_rn(0.5f, ph);
    float x1 = fminf(fmaxf(__fadd_rn(cx, -hx), 0.f), imW - 1.f);
    float y1 = fminf(fmaxf(__fadd_rn(cy, -hy), 0.f), imH - 1.f);
    float x2 = fminf(fmaxf(__fadd_rn(cx,  hx), 0.f), imW - 1.f);
    float y2 = fminf(fmaxf(__fadd_rn(cy,  hy), 0.f), imH - 1.f);
    float ms = 16.f * imS;
    bool keep = ((x2 - x1 + 1.f) >= ms) && ((y2 - y1 + 1.f) >= ms);
    int g = pos * 9 + a;
    float val = keep ? sc : -__builtin_inff();
    scores[g] = val;
    boxes[g]  = make_float4(x1, y1, x2, y2);
    atomicAdd(&hist[sortkey(val) >> 16], 1u);
  }
}

// ---------- K3: fused selection — thresh1+hist2+thresh2+compact, ONE block (verbatim) ----------
__global__ __launch_bounds__(1024) void k_sel(const u32* __restrict__ hist, u32* __restrict__ hist2,
                                              const float* __restrict__ scores,
                                              u32* __restrict__ ctr, u64* __restrict__ keys){
  __shared__ u32 cs[1024];
  __shared__ u32 bs[64];
  __shared__ int selg;
  __shared__ u32 afterv, T16s, aboves, K32s;
  const int t = threadIdx.x;
  const int b0 = t * 64;

  if (t == 0) selg = -1;
  __syncthreads();
  { u32 s = 0;
    for (int i = 0; i < 64; ++i) s += hist[b0 + i];
    cs[t] = s; }
  __syncthreads();
  for (int off = 1; off < 1024; off <<= 1){
    u32 v = cs[t];
    u32 ad = (t + off < 1024) ? cs[t + off] : 0u;
    __syncthreads();
    cs[t] = v + ad;
    __syncthreads();
  }
  { u32 here  = cs[t];
    u32 after = (t < 1023) ? cs[t + 1] : 0u;
    if (here >= 6000u && after < 6000u){ selg = t; afterv = after; } }
  __syncthreads();
  { int g = selg;
    if (g >= 0 && t < 64) bs[t] = hist[g*64 + t];
    __syncthreads();
    if (t == 0){
      if (g < 0){ T16s = 0u; aboves = 0u; }
      else {
        u32 acc = afterv;
        for (int b = 63; b >= 0; --b){
          u32 h = bs[b];
          acc += h;
          if (acc >= 6000u){ T16s = (u32)(g*64 + b); aboves = acc - h; break; }
        }
      }
    } }
  __syncthreads();

  { u32 pfx = T16s;
    for (int i = t; i < NANCH; i += 1024){
      u32 key = sortkey(scores[i]);
      if ((key >> 16) == pfx) atomicAdd(&hist2[key & 0xFFFFu], 1u);
    } }
  __threadfence();
  __syncthreads();

  if (t == 0) selg = -1;
  __syncthreads();
  const u32 target = 6000u - aboves;
  { u32 s = 0;
    for (int i = 0; i < 64; ++i) s += hist2[b0 + i];
    cs[t] = s; }
  __syncthreads();
  for (int off = 1; off < 1024; off <<= 1){
    u32 v = cs[t];
    u32 ad = (t + off < 1024) ? cs[t + off] : 0u;
    __syncthreads();
    cs[t] = v + ad;
    __syncthreads();
  }
  { u32 here  = cs[t];
    u32 after = (t < 1023) ? cs[t + 1] : 0u;
    if (here >= target && after < target){ selg = t; afterv = after; } }
  __syncthreads();
  { int g = selg;
    if (g >= 0 && t < 64) bs[t] = hist2[g*64 + t];
    __syncthreads();
    if (t == 0){
      if (g < 0) K32s = (T16s << 16);
      else {
        u32 acc = afterv;
        for (int b = 63; b >= 0; --b){
          u32 h = bs[b];
          acc += h;
          if (acc >= target){ K32s = (T16s << 16) | (u32)(g*64 + b); break; }
        }
      }
      ctr[4] = 6000u;
    } }
  __syncthreads();

  { u32 K = K32s;
    for (int i = t; i < NANCH; i += 1024){
      u32 key = sortkey(scores[i]);
      if (key >= K){
        u32 pos = atomicAdd(&ctr[0], 1u);
        if (pos < CAP) keys[pos] = ((u64)key << 32) | (u64)(u32)(~(u32)i);
      }
    } }
}

// ---------------- K-rank (verbatim) ----------------
__global__ __launch_bounds__(128) void k_rank(const u64* __restrict__ keys, u32* __restrict__ ctr,
                                              const float4* __restrict__ boxes,
                                              float4* __restrict__ topB, float* __restrict__ topA){
  __shared__ u64 ks[2048];
  const int t  = threadIdx.x;
  const int gi = blockIdx.x * 128 + t;
  u32 count = ctr[0]; if (count > CAP) count = CAP;
  u64 my = (gi < (int)count) ? keys[gi] : 0ull;
  int rank = 0;
  for (int c0 = 0; c0 < CAP; c0 += 2048){
    __syncthreads();
    for (int s = t; s < 2048; s += 128){
      int j = c0 + s;
      ks[s] = (j < (int)count) ? keys[j] : 0ull;
    }
    __syncthreads();
    if (gi < (int)count){
      const ulonglong2* kp = reinterpret_cast<const ulonglong2*>(ks);
      #pragma unroll 8
      for (int s = 0; s < 1024; ++s){
        ulonglong2 kv = kp[s];
        rank += (kv.x > my) + (kv.y > my);
      }
    }
  }
  if (gi < (int)count && rank < PRE){
    if (!((my >> 32) & 0x80000000ull))
      atomicMin((int*)(ctr + 4), rank);
    u32 idx = ~(u32)my;
    float4 bv = make_float4(0.f,0.f,0.f,0.f);
    float area = 1.f;
    if (idx < NANCH){
      bv = boxes[idx];
      area = (bv.z - bv.x + 1.f) * (bv.w - bv.y + 1.f);
    }
    topB[rank] = bv;
    topA[rank] = area;
  }
}

// ---------------- NMS stage A: suppression bit-matrix M[6000][188] (verbatim) ----------------
__global__ __launch_bounds__(256) void k_iou(const float4* __restrict__ topB, const float* __restrict__ topA,
                                             u32* __restrict__ M){
  __shared__ float4 jb[3072];
  const int tid = threadIdx.x;
  const int rr  = tid & 31;
  const int wg  = tid >> 5;
  const int i   = blockIdx.x * 32 + rr;
  float4 bi = make_float4(0.f,0.f,0.f,0.f); float ai = 1.f;
  if (i < PRE){ bi = topB[i]; ai = topA[i]; }
  for (int ph = 0; ph < 2; ++ph){
    __syncthreads();
    for (int s = tid; s < 3072; s += 256){
      int j = ph*3072 + s;
      jb[s] = (j < PRE) ? topB[j] : make_float4(0.f,0.f,0.f,0.f);
    }
    __syncthreads();
    if (i >= PRE) continue;
    int nw = (ph == 0) ? 96 : 92;
    #pragma unroll
    for (int m = 0; m < 12; ++m){
      int wl = wg + 8*m;
      if (wl >= nw) continue;
      int w = ph*96 + wl;
      int jbase = w * 32;
      if (jbase + 31 <= i){ M[(size_t)i*188 + w] = 0u; continue; }
      u32 bits = 0u;
      for (int s = 0; s < 32; ++s){
        int j = jbase + s;
        if (j <= i || j >= PRE) continue;
        float4 bj = jb[j - ph*3072];
        float aj = (bj.z - bj.x + 1.f) * (bj.w - bj.y + 1.f);
        float xx1 = fmaxf(bi.x, bj.x);
        float yy1 = fmaxf(bi.y, bj.y);
        float xx2 = fminf(bi.z, bj.z);
        float yy2 = fminf(bi.w, bj.w);
        float iw = fmaxf(xx2 - xx1 + 1.f, 0.f);
        float ih = fmaxf(yy2 - yy1 + 1.f, 0.f);
        float inter = iw * ih;
        float iou = inter / (ai + aj - inter);
        if (iou > 0.7f) bits |= (1u << s);
      }
      M[(size_t)i*188 + w] = bits;
    }
  }
}

// ---------------- NMS stage B: single-wave greedy scan — SIMPLE form (final; spec loses 3x over) ----------------
__global__ __launch_bounds__(64) void k_reduce(const u32* __restrict__ M, const float4* __restrict__ topB,
                                               const u32* __restrict__ ctr, float* __restrict__ out){
  __shared__ int kept[POST];
  const int t = threadIdx.x;
  int validN = (int)ctr[0];
  int finN   = (int)ctr[4];
  if (finN < validN) validN = finN;
  if (validN > PRE)  validN = PRE;
  auto initw = [&](int w)->u32{
    if (w >= 188) return 0xFFFFFFFFu;
    int lo = w * 32;
    if (lo + 32 <= validN) return 0u;
    if (lo >= validN) return 0xFFFFFFFFu;
    return ~((1u << (validN - lo)) - 1u);
  };
  u32 s0 = initw(t), s1 = initw(64 + t), s2 = initw(128 + t);
  for (int k = 0; k < POST; ++k){
    int i = -1;
    u64 b0 = __ballot(s0 != 0xFFFFFFFFu);
    if (b0){
      int L = (int)__ffsll((unsigned long long)b0) - 1;
      u32 v = (u32)__shfl((int)s0, L, 64);
      i = L*32 + (__ffs((int)(~v)) - 1);
    } else {
      u64 b1 = __ballot(s1 != 0xFFFFFFFFu);
      if (b1){
        int L = (int)__ffsll((unsigned long long)b1) - 1;
        u32 v = (u32)__shfl((int)s1, L, 64);
        i = 2048 + L*32 + (__ffs((int)(~v)) - 1);
      } else {
        u64 b2 = __ballot(s2 != 0xFFFFFFFFu);
        if (b2){
          int L = (int)__ffsll((unsigned long long)b2) - 1;
          u32 v = (u32)__shfl((int)s2, L, 64);
          i = 4096 + L*32 + (__ffs((int)(~v)) - 1);
        }
      }
    }
    if (t == 0) kept[k] = i;
    if (i >= 0){
      const u32* row = M + (size_t)i * 188;
      u32 r0 = row[t];
      u32 r1 = (64 + t < 188) ? row[64 + t] : 0u;
      u32 r2 = (128 + t < 188) ? row[128 + t] : 0u;
      s0 |= r0; s1 |= r1; s2 |= r2;
      int iw = i >> 5, ib = i & 31;
      if (iw == t) s0 |= (1u << ib);
      else if (iw == 64 + t) s1 |= (1u << ib);
      else if (iw == 128 + t) s2 |= (1u << ib);
    }
  }
  __syncthreads();
  for (int q = t; q < 1500; q += 64){
    int r = q / 5, c = q - r*5;
    int i = kept[r];
    float v = 0.f;
    if (i >= 0 && c > 0){
      float4 bx = topB[i];
      v = (c == 1) ? bx.x : (c == 2) ? bx.y : (c == 3) ? bx.z : bx.w;
    }
    out[q] = v;
  }
}

// ---------------- launch ----------------
extern "C" void kernel_launch(void* const* d_in, const int* in_sizes, int n_in,
                              void* d_out, int out_size, void* d_ws, size_t ws_size,
                              hipStream_t stream)
{
  const float* fm   = (const float*)d_in[0];
  const float* info = (const float*)d_in[1];
  const float* cw3  = (const float*)d_in[2];
  const float* cb3  = (const float*)d_in[3];
  const float* clw  = (const float*)d_in[4];
  const float* clb  = (const float*)d_in[5];
  const float* bbw  = (const float*)d_in[6];
  const float* bbb  = (const float*)d_in[7];
  float* out = (float*)d_out;

  char* base = (char*)d_ws;
  u32*   hist   = (u32*)  (base + 0);          // 65536 u32
  u32*   hist2  = (u32*)  (base + 262144);     // 65536 u32
  u32*   ctr    = (u32*)  (base + 524288);     // [0]=count [4]=finiteN
  float* Y      = (float*)(base + 524544);     // 12.58 MB
  u32*   M      = (u32*)  (base + 524544);     // overlays Y (dead after k_head): 4.5 MB
  float* scores = (float*)(base + 13107456);
  float4* boxes = (float4*)(base + 13328640);
  u64*   keys   = (u64*)  (base + 14213376);
  float4* topB  = (float4*)(base + 14278912);
  float* topA   = (float*)(base + 14375168);
  unsigned short* Xih = (unsigned short*)(base + 14399488);
  unsigned short* Xil = (unsigned short*)(base + 21022720);
  unsigned short* Wh2 = (unsigned short*)(base + 27645952);
  unsigned short* Wl2 = (unsigned short*)(base + 32364544);
  // total ws use: ~37.1 MB

  k_cvt   <<<1040, 256, 0, stream>>>(fm, cw3, Xih, Xil, Wh2, Wl2, (u32*)base);
  k_conv3 <<<dim3(16, 16), 256, 0, stream>>>(Xih, Xil, Wh2, Wl2, cb3, Y);
  k_head  <<<96,  256, 0, stream>>>(Y, clw, clb, bbw, bbb, info, scores, boxes, hist);
  k_sel   <<<1,  1024, 0, stream>>>(hist, hist2, scores, ctr, keys);
  k_rank  <<<64,  128, 0, stream>>>(keys, ctr, boxes, topB, topA);
  k_iou   <<<188, 256, 0, stream>>>(topB, topA, M);
  k_reduce<<<1,    64, 0, stream>>>(M, topB, ctr, out);
}

// Round 17
// 745.041 us; speedup vs baseline: 1.1793x; 1.0252x over previous
//
#include <hip/hip_runtime.h>
#include <stdint.h>

typedef unsigned int u32;
typedef unsigned long long u64;
typedef __attribute__((ext_vector_type(8))) short v8s;   // 8 bf16 = 4 VGPR (MFMA A/B frag)
typedef __attribute__((ext_vector_type(4))) float v4f;   // MFMA C/D frag

#define HH 64
#define WW 96
#define HW 6144
#define CC 512
#define NANCH 55296
#define PRE 6000
#define POST 300
#define CAP 8192
#define PW 98
#define PH 66
#define ICPAD 40

__device__ __constant__ float c_aw[9] = {184.f,368.f,736.f,128.f,256.f,512.f,88.f,176.f,352.f};
__device__ __constant__ float c_ah[9] = {96.f,192.f,384.f,128.f,256.f,512.f,176.f,352.f,704.f};

__device__ __forceinline__ unsigned short bf16_rne(float x){
  u32 u = __float_as_uint(x);
  return (unsigned short)((u + 0x7FFFu + ((u >> 16) & 1u)) >> 16);
}
__device__ __forceinline__ u32 sortkey(float s){
  u32 u = __float_as_uint(s);
  return u ^ ((u & 0x80000000u) ? 0xFFFFFFFFu : 0x80000000u);
}

// ---------- K0: merged convert (X: 528 blocks, W: 512 blocks) + ws zeroing ----------
__global__ __launch_bounds__(256) void k_cvt(const float* __restrict__ X, const float* __restrict__ Wt,
                                             unsigned short* __restrict__ Xih, unsigned short* __restrict__ Xil,
                                             unsigned short* __restrict__ Wh2, unsigned short* __restrict__ Wl2,
                                             u32* __restrict__ zero_region){
  __shared__ float Ls[64][97];
  __shared__ float Ws[4608];
  const int b = blockIdx.x, tid = threadIdx.x;
  { int gid = b*256 + tid;
    if (gid < 131072) zero_region[gid] = 0u;          // hist + hist2
    if (gid < 16) zero_region[131072 + gid] = 0u; }   // ctr
  if (b < 528){
    const int rp  = b % 66;
    const int ic0 = (b / 66) * 64;
    const bool zrow = (rp == 0 || rp == PH-1);
    if (!zrow){
      int r = rp - 1;
      for (int i = tid; i < 6144; i += 256){
        int ii = i / 96, c = i - ii*96;
        Ls[ii][c] = X[(ic0+ii)*HW + r*WW + c];
      }
    }
    __syncthreads();
    for (int i = tid; i < PW*64; i += 256){
      int cp = i >> 6, icl = i & 63;
      float x = 0.f;
      if (!zrow && cp >= 1 && cp <= 96) x = Ls[icl][cp-1];
      unsigned short h = bf16_rne(x);
      float hf = __uint_as_float(((u32)h) << 16);
      unsigned short l = bf16_rne(x - hf);
      long o = ((long)(rp*PW + cp) << 9) + ic0 + icl;
      Xih[o] = h; Xil[o] = l;
    }
  } else {
    const int oc = b - 528;
    for (int i = tid; i < 4608; i += 256) Ws[i] = Wt[oc*4608 + i];
    __syncthreads();
    for (int i = tid; i < 4608; i += 256){
      int tap = i / 512, ic = i - tap*512;
      float x = Ws[ic*9 + tap];
      unsigned short h = bf16_rne(x);
      float hf = __uint_as_float(((u32)h) << 16);
      unsigned short l = bf16_rne(x - hf);
      long o = ((long)(tap*512 + oc) << 9) + ic;
      Wh2[o] = h; Wl2[o] = l;
    }
  }
}

// ---------- K1: MFMA conv, LDS-staged + register double-buffer (R15-proven, bit-exact) ----------
__global__ __launch_bounds__(256, 1) void k_conv3(
    const unsigned short* __restrict__ Xih, const unsigned short* __restrict__ Xil,
    const unsigned short* __restrict__ Wh2, const unsigned short* __restrict__ Wl2,
    const float* __restrict__ Bc, float* __restrict__ Y)
{
  __shared__ __attribute__((aligned(16))) unsigned short Ah[6*98*ICPAD];
  __shared__ __attribute__((aligned(16))) unsigned short Al[6*98*ICPAD];
  __shared__ __attribute__((aligned(16))) unsigned short Bh[9*32*ICPAD];
  __shared__ __attribute__((aligned(16))) unsigned short Bl[9*32*ICPAD];
  const int tid  = threadIdx.x;
  const int w    = tid >> 6;
  const int lane = tid & 63;
  const int lm   = lane & 15;
  const int q    = lane >> 4;
  const int y0   = blockIdx.x * 4;
  const int oc0  = blockIdx.y * 32;

  v4f acc[6][2];
  #pragma unroll
  for (int t = 0; t < 6; ++t)
    #pragma unroll
    for (int n = 0; n < 2; ++n)
      acc[t][n] = (v4f){0.f,0.f,0.f,0.f};

  u64 ra[19][2], rb[9][2];
  auto loadSlab = [&](int icg){
    #pragma unroll
    for (int n = 0; n < 19; ++n){
      int it = tid + 256*n;
      if (it < 4704){
        int i4 = it & 7, rc = it >> 3;
        int c = rc % 98, r = rc / 98;
        long src = ((long)((y0 + r)*PW + c) << 9) + icg*32 + i4*4;
        ra[n][0] = *reinterpret_cast<const u64*>(Xih + src);
        ra[n][1] = *reinterpret_cast<const u64*>(Xil + src);
      }
    }
    #pragma unroll
    for (int n = 0; n < 9; ++n){
      int it = tid + 256*n;
      if (it < 2304){
        int i4 = it & 7, to = it >> 3;
        int oc = to & 31, tap = to >> 5;
        long src = ((long)(tap*512 + oc0 + oc) << 9) + icg*32 + i4*4;
        rb[n][0] = *reinterpret_cast<const u64*>(Wh2 + src);
        rb[n][1] = *reinterpret_cast<const u64*>(Wl2 + src);
      }
    }
  };
  auto storeSlab = [&](){
    #pragma unroll
    for (int n = 0; n < 19; ++n){
      int it = tid + 256*n;
      if (it < 4704){
        int i4 = it & 7, rc = it >> 3;
        int dst = rc*ICPAD + i4*4;
        *reinterpret_cast<u64*>(Ah + dst) = ra[n][0];
        *reinterpret_cast<u64*>(Al + dst) = ra[n][1];
      }
    }
    #pragma unroll
    for (int n = 0; n < 9; ++n){
      int it = tid + 256*n;
      if (it < 2304){
        int i4 = it & 7, to = it >> 3;
        int dst = to*ICPAD + i4*4;
        *reinterpret_cast<u64*>(Bh + dst) = rb[n][0];
        *reinterpret_cast<u64*>(Bl + dst) = rb[n][1];
      }
    }
  };

  loadSlab(0);
  for (int icg = 0; icg < 16; ++icg){
    __syncthreads();
    storeSlab();
    __syncthreads();
    if (icg < 15) loadSlab(icg + 1);
    #pragma unroll
    for (int tap = 0; tap < 9; ++tap){
      const int dy = tap / 3, dx = tap - dy*3;
      v8s ah[6], al[6], bh[2], bl[2];
      #pragma unroll
      for (int t = 0; t < 6; ++t){
        int a = ((w + dy)*98 + 16*t + lm + dx)*ICPAD + q*8;
        ah[t] = *reinterpret_cast<const v8s*>(Ah + a);
        al[t] = *reinterpret_cast<const v8s*>(Al + a);
      }
      #pragma unroll
      for (int n = 0; n < 2; ++n){
        int a = (tap*32 + n*16 + lm)*ICPAD + q*8;
        bh[n] = *reinterpret_cast<const v8s*>(Bh + a);
        bl[n] = *reinterpret_cast<const v8s*>(Bl + a);
      }
      #pragma unroll
      for (int t = 0; t < 6; ++t)
        #pragma unroll
        for (int n = 0; n < 2; ++n){
          acc[t][n] = __builtin_amdgcn_mfma_f32_16x16x32_bf16(al[t], bl[n], acc[t][n], 0, 0, 0);
          acc[t][n] = __builtin_amdgcn_mfma_f32_16x16x32_bf16(al[t], bh[n], acc[t][n], 0, 0, 0);
          acc[t][n] = __builtin_amdgcn_mfma_f32_16x16x32_bf16(ah[t], bl[n], acc[t][n], 0, 0, 0);
          acc[t][n] = __builtin_amdgcn_mfma_f32_16x16x32_bf16(ah[t], bh[n], acc[t][n], 0, 0, 0);
        }
    }
  }
  const int yrow = y0 + w;
  #pragma unroll
  for (int n = 0; n < 2; ++n){
    int oc = oc0 + n*16 + lm;
    float b = Bc[oc];
    #pragma unroll
    for (int t = 0; t < 6; ++t){
      float4 v;
      v.x = fmaxf(acc[t][n].x + b, 0.f);
      v.y = fmaxf(acc[t][n].y + b, 0.f);
      v.z = fmaxf(acc[t][n].z + b, 0.f);
      v.w = fmaxf(acc[t][n].w + b, 0.f);
      *reinterpret_cast<float4*>(Y + (long)oc*HW + yrow*WW + 16*t + q*4) = v;
    }
  }
}

// ---------------- K2: 1x1 heads + softmax + box decode (+ hist) ----------------
// R17: 192 blocks x 32 positions (was 96 x 64) — 2x CU coverage for this
// latency-bound kernel (R16: 151 us at VALUBusy 3.6%, Occ 3.8%). Thread tile
// 2 pos x 4 outs. Per-(pos,out) accumulation order (64-ch chunks ascending,
// inner c ascending, chunk-fold) IDENTICAL -> bit-identical scores/boxes.
__global__ __launch_bounds__(256) void k_head(
    const float* __restrict__ Y, const float* __restrict__ cw,
    const float* __restrict__ cb, const float* __restrict__ bw,
    const float* __restrict__ bb, const float* __restrict__ info,
    float* __restrict__ scores, float4* __restrict__ boxes, u32* __restrict__ hist)
{
  __shared__ float Ys[4096];    // chunk: [c][32 pos] (2048 used); epilogue: [32 pos][64 outs]
  __shared__ float Wsh[4096];   // [c][64 outs]
  const int tid = threadIdx.x;
  const int p0  = blockIdx.x * 32;
  const int po  = tid & 15;     // 2 positions: po*2, po*2+1
  const int oj  = tid >> 4;     // outputs oj + 16k
  float accM[2][4], accC[2][4];
  #pragma unroll
  for (int p = 0; p < 2; ++p)
    #pragma unroll
    for (int k = 0; k < 4; ++k){ accM[p][k] = 0.f; accC[p][k] = 0.f; }

  for (int c0 = 0; c0 < CC; c0 += 64){
    __syncthreads();
    for (int i = tid; i < 2048; i += 256){
      int c = i >> 5, p = i & 31;
      Ys[i] = Y[(c0 + c) * HW + p0 + p];
    }
    for (int i = tid; i < 4096; i += 256){
      int c = i >> 6, o = i & 63;
      int gc = c0 + c;
      float v = 0.f;
      if (o < 18) v = cw[o * 512 + gc];
      else if (o < 54) v = bw[(o - 18) * 512 + gc];
      Wsh[i] = v;
    }
    __syncthreads();
    for (int c = 0; c < 64; ++c){
      const float2 xv = *reinterpret_cast<const float2*>(Ys + c*32 + po*2);
      float xa[2] = {xv.x, xv.y};
      const float* wrd = Wsh + c*64 + oj;
      float wv[4] = {wrd[0], wrd[16], wrd[32], wrd[48]};
      #pragma unroll
      for (int p = 0; p < 2; ++p)
        #pragma unroll
        for (int k = 0; k < 4; ++k)
          accC[p][k] = __fmaf_rn(xa[p], wv[k], accC[p][k]);
    }
    #pragma unroll
    for (int p = 0; p < 2; ++p)
      #pragma unroll
      for (int k = 0; k < 4; ++k){ accM[p][k] += accC[p][k]; accC[p][k] = 0.f; }
  }
  __syncthreads();
  #pragma unroll
  for (int p = 0; p < 2; ++p)
    #pragma unroll
    for (int k = 0; k < 4; ++k){
      int o = oj + 16*k;
      float bias = (o < 18) ? cb[o] : ((o < 54) ? bb[o - 18] : 0.f);
      Ys[(po*2 + p)*64 + o] = accM[p][k] + bias;
    }
  __syncthreads();
  float imH = info[0], imW = info[1], imS = info[2];
  for (int it = tid; it < 288; it += 256){
    int pl = it / 9;
    int a  = it - pl*9;
    const float* L = Ys + pl*64;
    float l0 = L[a], l1 = L[9 + a];
    float mx = fmaxf(l0, l1);
    float e0 = expf(l0 - mx), e1 = expf(l1 - mx);
    float sc = e1 / (e0 + e1);
    float d0 = L[18 + a*4 + 0], d1 = L[18 + a*4 + 1];
    float d2 = L[18 + a*4 + 2], d3 = L[18 + a*4 + 3];
    int pos = p0 + pl;
    int yy = pos / 96;
    int xx = pos - yy * 96;
    float aw = c_aw[a], ah = c_ah[a];
    float acx = (float)(xx * 16 + 8);
    float acy = (float)(yy * 16 + 8);
    float cx = __fadd_rn(__fmul_rn(d0, aw), acx);
    float cy = __fadd_rn(__fmul_rn(d1, ah), acy);
    float pw = __fmul_rn(expf(d2), aw);
    float ph = __fmul_rn(expf(d3), ah);
    float hx = __fmul_rn(0.5f, pw);
    float hy = __fmul_rn(0.5f, ph);
    float x1 = fminf(fmaxf(__fadd_rn(cx, -hx), 0.f), imW - 1.f);
    float y1 = fminf(fmaxf(__fadd_rn(cy, -hy), 0.f), imH - 1.f);
    float x2 = fminf(fmaxf(__fadd_rn(cx,  hx), 0.f), imW - 1.f);
    float y2 = fminf(fmaxf(__fadd_rn(cy,  hy), 0.f), imH - 1.f);
    float ms = 16.f * imS;
    bool keep = ((x2 - x1 + 1.f) >= ms) && ((y2 - y1 + 1.f) >= ms);
    int g = pos * 9 + a;
    float val = keep ? sc : -__builtin_inff();
    scores[g] = val;
    boxes[g]  = make_float4(x1, y1, x2, y2);
    atomicAdd(&hist[sortkey(val) >> 16], 1u);
  }
}

// ---------- K3: fused selection — thresh1+hist2+thresh2+compact, ONE block (verbatim) ----------
__global__ __launch_bounds__(1024) void k_sel(const u32* __restrict__ hist, u32* __restrict__ hist2,
                                              const float* __restrict__ scores,
                                              u32* __restrict__ ctr, u64* __restrict__ keys){
  __shared__ u32 cs[1024];
  __shared__ u32 bs[64];
  __shared__ int selg;
  __shared__ u32 afterv, T16s, aboves, K32s;
  const int t = threadIdx.x;
  const int b0 = t * 64;

  if (t == 0) selg = -1;
  __syncthreads();
  { u32 s = 0;
    for (int i = 0; i < 64; ++i) s += hist[b0 + i];
    cs[t] = s; }
  __syncthreads();
  for (int off = 1; off < 1024; off <<= 1){
    u32 v = cs[t];
    u32 ad = (t + off < 1024) ? cs[t + off] : 0u;
    __syncthreads();
    cs[t] = v + ad;
    __syncthreads();
  }
  { u32 here  = cs[t];
    u32 after = (t < 1023) ? cs[t + 1] : 0u;
    if (here >= 6000u && after < 6000u){ selg = t; afterv = after; } }
  __syncthreads();
  { int g = selg;
    if (g >= 0 && t < 64) bs[t] = hist[g*64 + t];
    __syncthreads();
    if (t == 0){
      if (g < 0){ T16s = 0u; aboves = 0u; }
      else {
        u32 acc = afterv;
        for (int b = 63; b >= 0; --b){
          u32 h = bs[b];
          acc += h;
          if (acc >= 6000u){ T16s = (u32)(g*64 + b); aboves = acc - h; break; }
        }
      }
    } }
  __syncthreads();

  { u32 pfx = T16s;
    for (int i = t; i < NANCH; i += 1024){
      u32 key = sortkey(scores[i]);
      if ((key >> 16) == pfx) atomicAdd(&hist2[key & 0xFFFFu], 1u);
    } }
  __threadfence();
  __syncthreads();

  if (t == 0) selg = -1;
  __syncthreads();
  const u32 target = 6000u - aboves;
  { u32 s = 0;
    for (int i = 0; i < 64; ++i) s += hist2[b0 + i];
    cs[t] = s; }
  __syncthreads();
  for (int off = 1; off < 1024; off <<= 1){
    u32 v = cs[t];
    u32 ad = (t + off < 1024) ? cs[t + off] : 0u;
    __syncthreads();
    cs[t] = v + ad;
    __syncthreads();
  }
  { u32 here  = cs[t];
    u32 after = (t < 1023) ? cs[t + 1] : 0u;
    if (here >= target && after < target){ selg = t; afterv = after; } }
  __syncthreads();
  { int g = selg;
    if (g >= 0 && t < 64) bs[t] = hist2[g*64 + t];
    __syncthreads();
    if (t == 0){
      if (g < 0) K32s = (T16s << 16);
      else {
        u32 acc = afterv;
        for (int b = 63; b >= 0; --b){
          u32 h = bs[b];
          acc += h;
          if (acc >= target){ K32s = (T16s << 16) | (u32)(g*64 + b); break; }
        }
      }
      ctr[4] = 6000u;
    } }
  __syncthreads();

  { u32 K = K32s;
    for (int i = t; i < NANCH; i += 1024){
      u32 key = sortkey(scores[i]);
      if (key >= K){
        u32 pos = atomicAdd(&ctr[0], 1u);
        if (pos < CAP) keys[pos] = ((u64)key << 32) | (u64)(u32)(~(u32)i);
      }
    } }
}

// ---------------- K-rank (verbatim) ----------------
__global__ __launch_bounds__(128) void k_rank(const u64* __restrict__ keys, u32* __restrict__ ctr,
                                              const float4* __restrict__ boxes,
                                              float4* __restrict__ topB, float* __restrict__ topA){
  __shared__ u64 ks[2048];
  const int t  = threadIdx.x;
  const int gi = blockIdx.x * 128 + t;
  u32 count = ctr[0]; if (count > CAP) count = CAP;
  u64 my = (gi < (int)count) ? keys[gi] : 0ull;
  int rank = 0;
  for (int c0 = 0; c0 < CAP; c0 += 2048){
    __syncthreads();
    for (int s = t; s < 2048; s += 128){
      int j = c0 + s;
      ks[s] = (j < (int)count) ? keys[j] : 0ull;
    }
    __syncthreads();
    if (gi < (int)count){
      const ulonglong2* kp = reinterpret_cast<const ulonglong2*>(ks);
      #pragma unroll 8
      for (int s = 0; s < 1024; ++s){
        ulonglong2 kv = kp[s];
        rank += (kv.x > my) + (kv.y > my);
      }
    }
  }
  if (gi < (int)count && rank < PRE){
    if (!((my >> 32) & 0x80000000ull))
      atomicMin((int*)(ctr + 4), rank);
    u32 idx = ~(u32)my;
    float4 bv = make_float4(0.f,0.f,0.f,0.f);
    float area = 1.f;
    if (idx < NANCH){
      bv = boxes[idx];
      area = (bv.z - bv.x + 1.f) * (bv.w - bv.y + 1.f);
    }
    topB[rank] = bv;
    topA[rank] = area;
  }
}

// ---------------- NMS stage A: suppression bit-matrix M[6000][188] (verbatim) ----------------
__global__ __launch_bounds__(256) void k_iou(const float4* __restrict__ topB, const float* __restrict__ topA,
                                             u32* __restrict__ M){
  __shared__ float4 jb[3072];
  const int tid = threadIdx.x;
  const int rr  = tid & 31;
  const int wg  = tid >> 5;
  const int i   = blockIdx.x * 32 + rr;
  float4 bi = make_float4(0.f,0.f,0.f,0.f); float ai = 1.f;
  if (i < PRE){ bi = topB[i]; ai = topA[i]; }
  for (int ph = 0; ph < 2; ++ph){
    __syncthreads();
    for (int s = tid; s < 3072; s += 256){
      int j = ph*3072 + s;
      jb[s] = (j < PRE) ? topB[j] : make_float4(0.f,0.f,0.f,0.f);
    }
    __syncthreads();
    if (i >= PRE) continue;
    int nw = (ph == 0) ? 96 : 92;
    #pragma unroll
    for (int m = 0; m < 12; ++m){
      int wl = wg + 8*m;
      if (wl >= nw) continue;
      int w = ph*96 + wl;
      int jbase = w * 32;
      if (jbase + 31 <= i){ M[(size_t)i*188 + w] = 0u; continue; }
      u32 bits = 0u;
      for (int s = 0; s < 32; ++s){
        int j = jbase + s;
        if (j <= i || j >= PRE) continue;
        float4 bj = jb[j - ph*3072];
        float aj = (bj.z - bj.x + 1.f) * (bj.w - bj.y + 1.f);
        float xx1 = fmaxf(bi.x, bj.x);
        float yy1 = fmaxf(bi.y, bj.y);
        float xx2 = fminf(bi.z, bj.z);
        float yy2 = fminf(bi.w, bj.w);
        float iw = fmaxf(xx2 - xx1 + 1.f, 0.f);
        float ih = fmaxf(yy2 - yy1 + 1.f, 0.f);
        float inter = iw * ih;
        float iou = inter / (ai + aj - inter);
        if (iou > 0.7f) bits |= (1u << s);
      }
      M[(size_t)i*188 + w] = bits;
    }
  }
}

// ---------------- NMS stage B: single-wave greedy scan — SIMPLE form (final) ----------------
__global__ __launch_bounds__(64) void k_reduce(const u32* __restrict__ M, const float4* __restrict__ topB,
                                               const u32* __restrict__ ctr, float* __restrict__ out){
  __shared__ int kept[POST];
  const int t = threadIdx.x;
  int validN = (int)ctr[0];
  int finN   = (int)ctr[4];
  if (finN < validN) validN = finN;
  if (validN > PRE)  validN = PRE;
  auto initw = [&](int w)->u32{
    if (w >= 188) return 0xFFFFFFFFu;
    int lo = w * 32;
    if (lo + 32 <= validN) return 0u;
    if (lo >= validN) return 0xFFFFFFFFu;
    return ~((1u << (validN - lo)) - 1u);
  };
  u32 s0 = initw(t), s1 = initw(64 + t), s2 = initw(128 + t);
  for (int k = 0; k < POST; ++k){
    int i = -1;
    u64 b0 = __ballot(s0 != 0xFFFFFFFFu);
    if (b0){
      int L = (int)__ffsll((unsigned long long)b0) - 1;
      u32 v = (u32)__shfl((int)s0, L, 64);
      i = L*32 + (__ffs((int)(~v)) - 1);
    } else {
      u64 b1 = __ballot(s1 != 0xFFFFFFFFu);
      if (b1){
        int L = (int)__ffsll((unsigned long long)b1) - 1;
        u32 v = (u32)__shfl((int)s1, L, 64);
        i = 2048 + L*32 + (__ffs((int)(~v)) - 1);
      } else {
        u64 b2 = __ballot(s2 != 0xFFFFFFFFu);
        if (b2){
          int L = (int)__ffsll((unsigned long long)b2) - 1;
          u32 v = (u32)__shfl((int)s2, L, 64);
          i = 4096 + L*32 + (__ffs((int)(~v)) - 1);
        }
      }
    }
    if (t == 0) kept[k] = i;
    if (i >= 0){
      const u32* row = M + (size_t)i * 188;
      u32 r0 = row[t];
      u32 r1 = (64 + t < 188) ? row[64 + t] : 0u;
      u32 r2 = (128 + t < 188) ? row[128 + t] : 0u;
      s0 |= r0; s1 |= r1; s2 |= r2;
      int iw = i >> 5, ib = i & 31;
      if (iw == t) s0 |= (1u << ib);
      else if (iw == 64 + t) s1 |= (1u << ib);
      else if (iw == 128 + t) s2 |= (1u << ib);
    }
  }
  __syncthreads();
  for (int q = t; q < 1500; q += 64){
    int r = q / 5, c = q - r*5;
    int i = kept[r];
    float v = 0.f;
    if (i >= 0 && c > 0){
      float4 bx = topB[i];
      v = (c == 1) ? bx.x : (c == 2) ? bx.y : (c == 3) ? bx.z : bx.w;
    }
    out[q] = v;
  }
}

// ---------------- launch ----------------
extern "C" void kernel_launch(void* const* d_in, const int* in_sizes, int n_in,
                              void* d_out, int out_size, void* d_ws, size_t ws_size,
                              hipStream_t stream)
{
  const float* fm   = (const float*)d_in[0];
  const float* info = (const float*)d_in[1];
  const float* cw3  = (const float*)d_in[2];
  const float* cb3  = (const float*)d_in[3];
  const float* clw  = (const float*)d_in[4];
  const float* clb  = (const float*)d_in[5];
  const float* bbw  = (const float*)d_in[6];
  const float* bbb  = (const float*)d_in[7];
  float* out = (float*)d_out;

  char* base = (char*)d_ws;
  u32*   hist   = (u32*)  (base + 0);          // 65536 u32
  u32*   hist2  = (u32*)  (base + 262144);     // 65536 u32
  u32*   ctr    = (u32*)  (base + 524288);     // [0]=count [4]=finiteN
  float* Y      = (float*)(base + 524544);     // 12.58 MB
  u32*   M      = (u32*)  (base + 524544);     // overlays Y (dead after k_head): 4.5 MB
  float* scores = (float*)(base + 13107456);
  float4* boxes = (float4*)(base + 13328640);
  u64*   keys   = (u64*)  (base + 14213376);
  float4* topB  = (float4*)(base + 14278912);
  float* topA   = (float*)(base + 14375168);
  unsigned short* Xih = (unsigned short*)(base + 14399488);
  unsigned short* Xil = (unsigned short*)(base + 21022720);
  unsigned short* Wh2 = (unsigned short*)(base + 27645952);
  unsigned short* Wl2 = (unsigned short*)(base + 32364544);
  // total ws use: ~37.1 MB

  k_cvt   <<<1040, 256, 0, stream>>>(fm, cw3, Xih, Xil, Wh2, Wl2, (u32*)base);
  k_conv3 <<<dim3(16, 16), 256, 0, stream>>>(Xih, Xil, Wh2, Wl2, cb3, Y);
  k_head  <<<192, 256, 0, stream>>>(Y, clw, clb, bbw, bbb, info, scores, boxes, hist);
  k_sel   <<<1,  1024, 0, stream>>>(hist, hist2, scores, ctr, keys);
  k_rank  <<<64,  128, 0, stream>>>(keys, ctr, boxes, topB, topA);
  k_iou   <<<188, 256, 0, stream>>>(topB, topA, M);
  k_reduce<<<1,    64, 0, stream>>>(M, topB, ctr, out);
}

// Round 18
// 637.095 us; speedup vs baseline: 1.3791x; 1.1694x over previous
//
#include <hip/hip_runtime.h>
#include <stdint.h>

typedef unsigned int u32;
typedef unsigned long long u64;
typedef __attribute__((ext_vector_type(8))) short v8s;   // 8 bf16 = 4 VGPR (MFMA A/B frag)
typedef __attribute__((ext_vector_type(4))) float v4f;   // MFMA C/D frag

#define HH 64
#define WW 96
#define HW 6144
#define CC 512
#define NANCH 55296
#define PRE 6000
#define POST 300
#define CAP 8192
#define PW 98
#define PH 66
#define ICPAD 40

__device__ __constant__ float c_aw[9] = {184.f,368.f,736.f,128.f,256.f,512.f,88.f,176.f,352.f};
__device__ __constant__ float c_ah[9] = {96.f,192.f,384.f,128.f,256.f,512.f,176.f,352.f,704.f};

__device__ __forceinline__ unsigned short bf16_rne(float x){
  u32 u = __float_as_uint(x);
  return (unsigned short)((u + 0x7FFFu + ((u >> 16) & 1u)) >> 16);
}
__device__ __forceinline__ u32 sortkey(float s){
  u32 u = __float_as_uint(s);
  return u ^ ((u & 0x80000000u) ? 0xFFFFFFFFu : 0x80000000u);
}

// ---------- K0: merged convert (X: 528 blocks, W: 512 blocks) + ws zeroing ----------
__global__ __launch_bounds__(256) void k_cvt(const float* __restrict__ X, const float* __restrict__ Wt,
                                             unsigned short* __restrict__ Xih, unsigned short* __restrict__ Xil,
                                             unsigned short* __restrict__ Wh2, unsigned short* __restrict__ Wl2,
                                             u32* __restrict__ zero_region){
  __shared__ float Ls[64][97];
  __shared__ float Ws[4608];
  const int b = blockIdx.x, tid = threadIdx.x;
  { int gid = b*256 + tid;
    if (gid < 131072) zero_region[gid] = 0u;          // hist + hist2
    if (gid < 16) zero_region[131072 + gid] = 0u; }   // ctr
  if (b < 528){
    const int rp  = b % 66;
    const int ic0 = (b / 66) * 64;
    const bool zrow = (rp == 0 || rp == PH-1);
    if (!zrow){
      int r = rp - 1;
      for (int i = tid; i < 6144; i += 256){
        int ii = i / 96, c = i - ii*96;
        Ls[ii][c] = X[(ic0+ii)*HW + r*WW + c];
      }
    }
    __syncthreads();
    for (int i = tid; i < PW*64; i += 256){
      int cp = i >> 6, icl = i & 63;
      float x = 0.f;
      if (!zrow && cp >= 1 && cp <= 96) x = Ls[icl][cp-1];
      unsigned short h = bf16_rne(x);
      float hf = __uint_as_float(((u32)h) << 16);
      unsigned short l = bf16_rne(x - hf);
      long o = ((long)(rp*PW + cp) << 9) + ic0 + icl;
      Xih[o] = h; Xil[o] = l;
    }
  } else {
    const int oc = b - 528;
    for (int i = tid; i < 4608; i += 256) Ws[i] = Wt[oc*4608 + i];
    __syncthreads();
    for (int i = tid; i < 4608; i += 256){
      int tap = i / 512, ic = i - tap*512;
      float x = Ws[ic*9 + tap];
      unsigned short h = bf16_rne(x);
      float hf = __uint_as_float(((u32)h) << 16);
      unsigned short l = bf16_rne(x - hf);
      long o = ((long)(tap*512 + oc) << 9) + ic;
      Wh2[o] = h; Wl2[o] = l;
    }
  }
}

// ---------- K1: MFMA conv, LDS-staged + register double-buffer (R15-proven, bit-exact) ----------
__global__ __launch_bounds__(256, 1) void k_conv3(
    const unsigned short* __restrict__ Xih, const unsigned short* __restrict__ Xil,
    const unsigned short* __restrict__ Wh2, const unsigned short* __restrict__ Wl2,
    const float* __restrict__ Bc, float* __restrict__ Y)
{
  __shared__ __attribute__((aligned(16))) unsigned short Ah[6*98*ICPAD];
  __shared__ __attribute__((aligned(16))) unsigned short Al[6*98*ICPAD];
  __shared__ __attribute__((aligned(16))) unsigned short Bh[9*32*ICPAD];
  __shared__ __attribute__((aligned(16))) unsigned short Bl[9*32*ICPAD];
  const int tid  = threadIdx.x;
  const int w    = tid >> 6;
  const int lane = tid & 63;
  const int lm   = lane & 15;
  const int q    = lane >> 4;
  const int y0   = blockIdx.x * 4;
  const int oc0  = blockIdx.y * 32;

  v4f acc[6][2];
  #pragma unroll
  for (int t = 0; t < 6; ++t)
    #pragma unroll
    for (int n = 0; n < 2; ++n)
      acc[t][n] = (v4f){0.f,0.f,0.f,0.f};

  u64 ra[19][2], rb[9][2];
  auto loadSlab = [&](int icg){
    #pragma unroll
    for (int n = 0; n < 19; ++n){
      int it = tid + 256*n;
      if (it < 4704){
        int i4 = it & 7, rc = it >> 3;
        int c = rc % 98, r = rc / 98;
        long src = ((long)((y0 + r)*PW + c) << 9) + icg*32 + i4*4;
        ra[n][0] = *reinterpret_cast<const u64*>(Xih + src);
        ra[n][1] = *reinterpret_cast<const u64*>(Xil + src);
      }
    }
    #pragma unroll
    for (int n = 0; n < 9; ++n){
      int it = tid + 256*n;
      if (it < 2304){
        int i4 = it & 7, to = it >> 3;
        int oc = to & 31, tap = to >> 5;
        long src = ((long)(tap*512 + oc0 + oc) << 9) + icg*32 + i4*4;
        rb[n][0] = *reinterpret_cast<const u64*>(Wh2 + src);
        rb[n][1] = *reinterpret_cast<const u64*>(Wl2 + src);
      }
    }
  };
  auto storeSlab = [&](){
    #pragma unroll
    for (int n = 0; n < 19; ++n){
      int it = tid + 256*n;
      if (it < 4704){
        int i4 = it & 7, rc = it >> 3;
        int dst = rc*ICPAD + i4*4;
        *reinterpret_cast<u64*>(Ah + dst) = ra[n][0];
        *reinterpret_cast<u64*>(Al + dst) = ra[n][1];
      }
    }
    #pragma unroll
    for (int n = 0; n < 9; ++n){
      int it = tid + 256*n;
      if (it < 2304){
        int i4 = it & 7, to = it >> 3;
        int dst = to*ICPAD + i4*4;
        *reinterpret_cast<u64*>(Bh + dst) = rb[n][0];
        *reinterpret_cast<u64*>(Bl + dst) = rb[n][1];
      }
    }
  };

  loadSlab(0);
  for (int icg = 0; icg < 16; ++icg){
    __syncthreads();
    storeSlab();
    __syncthreads();
    if (icg < 15) loadSlab(icg + 1);
    #pragma unroll
    for (int tap = 0; tap < 9; ++tap){
      const int dy = tap / 3, dx = tap - dy*3;
      v8s ah[6], al[6], bh[2], bl[2];
      #pragma unroll
      for (int t = 0; t < 6; ++t){
        int a = ((w + dy)*98 + 16*t + lm + dx)*ICPAD + q*8;
        ah[t] = *reinterpret_cast<const v8s*>(Ah + a);
        al[t] = *reinterpret_cast<const v8s*>(Al + a);
      }
      #pragma unroll
      for (int n = 0; n < 2; ++n){
        int a = (tap*32 + n*16 + lm)*ICPAD + q*8;
        bh[n] = *reinterpret_cast<const v8s*>(Bh + a);
        bl[n] = *reinterpret_cast<const v8s*>(Bl + a);
      }
      #pragma unroll
      for (int t = 0; t < 6; ++t)
        #pragma unroll
        for (int n = 0; n < 2; ++n){
          acc[t][n] = __builtin_amdgcn_mfma_f32_16x16x32_bf16(al[t], bl[n], acc[t][n], 0, 0, 0);
          acc[t][n] = __builtin_amdgcn_mfma_f32_16x16x32_bf16(al[t], bh[n], acc[t][n], 0, 0, 0);
          acc[t][n] = __builtin_amdgcn_mfma_f32_16x16x32_bf16(ah[t], bl[n], acc[t][n], 0, 0, 0);
          acc[t][n] = __builtin_amdgcn_mfma_f32_16x16x32_bf16(ah[t], bh[n], acc[t][n], 0, 0, 0);
        }
    }
  }
  const int yrow = y0 + w;
  #pragma unroll
  for (int n = 0; n < 2; ++n){
    int oc = oc0 + n*16 + lm;
    float b = Bc[oc];
    #pragma unroll
    for (int t = 0; t < 6; ++t){
      float4 v;
      v.x = fmaxf(acc[t][n].x + b, 0.f);
      v.y = fmaxf(acc[t][n].y + b, 0.f);
      v.z = fmaxf(acc[t][n].z + b, 0.f);
      v.w = fmaxf(acc[t][n].w + b, 0.f);
      *reinterpret_cast<float4*>(Y + (long)oc*HW + yrow*WW + 16*t + q*4) = v;
    }
  }
}

// ---------------- K2: 1x1 heads + softmax + box decode (+ hist) — R17 verbatim ----------------
__global__ __launch_bounds__(256) void k_head(
    const float* __restrict__ Y, const float* __restrict__ cw,
    const float* __restrict__ cb, const float* __restrict__ bw,
    const float* __restrict__ bb, const float* __restrict__ info,
    float* __restrict__ scores, float4* __restrict__ boxes, u32* __restrict__ hist)
{
  __shared__ float Ys[4096];
  __shared__ float Wsh[4096];
  const int tid = threadIdx.x;
  const int p0  = blockIdx.x * 32;
  const int po  = tid & 15;
  const int oj  = tid >> 4;
  float accM[2][4], accC[2][4];
  #pragma unroll
  for (int p = 0; p < 2; ++p)
    #pragma unroll
    for (int k = 0; k < 4; ++k){ accM[p][k] = 0.f; accC[p][k] = 0.f; }

  for (int c0 = 0; c0 < CC; c0 += 64){
    __syncthreads();
    for (int i = tid; i < 2048; i += 256){
      int c = i >> 5, p = i & 31;
      Ys[i] = Y[(c0 + c) * HW + p0 + p];
    }
    for (int i = tid; i < 4096; i += 256){
      int c = i >> 6, o = i & 63;
      int gc = c0 + c;
      float v = 0.f;
      if (o < 18) v = cw[o * 512 + gc];
      else if (o < 54) v = bw[(o - 18) * 512 + gc];
      Wsh[i] = v;
    }
    __syncthreads();
    for (int c = 0; c < 64; ++c){
      const float2 xv = *reinterpret_cast<const float2*>(Ys + c*32 + po*2);
      float xa[2] = {xv.x, xv.y};
      const float* wrd = Wsh + c*64 + oj;
      float wv[4] = {wrd[0], wrd[16], wrd[32], wrd[48]};
      #pragma unroll
      for (int p = 0; p < 2; ++p)
        #pragma unroll
        for (int k = 0; k < 4; ++k)
          accC[p][k] = __fmaf_rn(xa[p], wv[k], accC[p][k]);
    }
    #pragma unroll
    for (int p = 0; p < 2; ++p)
      #pragma unroll
      for (int k = 0; k < 4; ++k){ accM[p][k] += accC[p][k]; accC[p][k] = 0.f; }
  }
  __syncthreads();
  #pragma unroll
  for (int p = 0; p < 2; ++p)
    #pragma unroll
    for (int k = 0; k < 4; ++k){
      int o = oj + 16*k;
      float bias = (o < 18) ? cb[o] : ((o < 54) ? bb[o - 18] : 0.f);
      Ys[(po*2 + p)*64 + o] = accM[p][k] + bias;
    }
  __syncthreads();
  float imH = info[0], imW = info[1], imS = info[2];
  for (int it = tid; it < 288; it += 256){
    int pl = it / 9;
    int a  = it - pl*9;
    const float* L = Ys + pl*64;
    float l0 = L[a], l1 = L[9 + a];
    float mx = fmaxf(l0, l1);
    float e0 = expf(l0 - mx), e1 = expf(l1 - mx);
    float sc = e1 / (e0 + e1);
    float d0 = L[18 + a*4 + 0], d1 = L[18 + a*4 + 1];
    float d2 = L[18 + a*4 + 2], d3 = L[18 + a*4 + 3];
    int pos = p0 + pl;
    int yy = pos / 96;
    int xx = pos - yy * 96;
    float aw = c_aw[a], ah = c_ah[a];
    float acx = (float)(xx * 16 + 8);
    float acy = (float)(yy * 16 + 8);
    float cx = __fadd_rn(__fmul_rn(d0, aw), acx);
    float cy = __fadd_rn(__fmul_rn(d1, ah), acy);
    float pw = __fmul_rn(expf(d2), aw);
    float ph = __fmul_rn(expf(d3), ah);
    float hx = __fmul_rn(0.5f, pw);
    float hy = __fmul_rn(0.5f, ph);
    float x1 = fminf(fmaxf(__fadd_rn(cx, -hx), 0.f), imW - 1.f);
    float y1 = fminf(fmaxf(__fadd_rn(cy, -hy), 0.f), imH - 1.f);
    float x2 = fminf(fmaxf(__fadd_rn(cx,  hx), 0.f), imW - 1.f);
    float y2 = fminf(fmaxf(__fadd_rn(cy,  hy), 0.f), imH - 1.f);
    float ms = 16.f * imS;
    bool keep = ((x2 - x1 + 1.f) >= ms) && ((y2 - y1 + 1.f) >= ms);
    int g = pos * 9 + a;
    float val = keep ? sc : -__builtin_inff();
    scores[g] = val;
    boxes[g]  = make_float4(x1, y1, x2, y2);
    atomicAdd(&hist[sortkey(val) >> 16], 1u);
  }
}

// ---------- K3: fused selection — thresh1+hist2+thresh2+compact, ONE block (verbatim) ----------
__global__ __launch_bounds__(1024) void k_sel(const u32* __restrict__ hist, u32* __restrict__ hist2,
                                              const float* __restrict__ scores,
                                              u32* __restrict__ ctr, u64* __restrict__ keys){
  __shared__ u32 cs[1024];
  __shared__ u32 bs[64];
  __shared__ int selg;
  __shared__ u32 afterv, T16s, aboves, K32s;
  const int t = threadIdx.x;
  const int b0 = t * 64;

  if (t == 0) selg = -1;
  __syncthreads();
  { u32 s = 0;
    for (int i = 0; i < 64; ++i) s += hist[b0 + i];
    cs[t] = s; }
  __syncthreads();
  for (int off = 1; off < 1024; off <<= 1){
    u32 v = cs[t];
    u32 ad = (t + off < 1024) ? cs[t + off] : 0u;
    __syncthreads();
    cs[t] = v + ad;
    __syncthreads();
  }
  { u32 here  = cs[t];
    u32 after = (t < 1023) ? cs[t + 1] : 0u;
    if (here >= 6000u && after < 6000u){ selg = t; afterv = after; } }
  __syncthreads();
  { int g = selg;
    if (g >= 0 && t < 64) bs[t] = hist[g*64 + t];
    __syncthreads();
    if (t == 0){
      if (g < 0){ T16s = 0u; aboves = 0u; }
      else {
        u32 acc = afterv;
        for (int b = 63; b >= 0; --b){
          u32 h = bs[b];
          acc += h;
          if (acc >= 6000u){ T16s = (u32)(g*64 + b); aboves = acc - h; break; }
        }
      }
    } }
  __syncthreads();

  { u32 pfx = T16s;
    for (int i = t; i < NANCH; i += 1024){
      u32 key = sortkey(scores[i]);
      if ((key >> 16) == pfx) atomicAdd(&hist2[key & 0xFFFFu], 1u);
    } }
  __threadfence();
  __syncthreads();

  if (t == 0) selg = -1;
  __syncthreads();
  const u32 target = 6000u - aboves;
  { u32 s = 0;
    for (int i = 0; i < 64; ++i) s += hist2[b0 + i];
    cs[t] = s; }
  __syncthreads();
  for (int off = 1; off < 1024; off <<= 1){
    u32 v = cs[t];
    u32 ad = (t + off < 1024) ? cs[t + off] : 0u;
    __syncthreads();
    cs[t] = v + ad;
    __syncthreads();
  }
  { u32 here  = cs[t];
    u32 after = (t < 1023) ? cs[t + 1] : 0u;
    if (here >= target && after < target){ selg = t; afterv = after; } }
  __syncthreads();
  { int g = selg;
    if (g >= 0 && t < 64) bs[t] = hist2[g*64 + t];
    __syncthreads();
    if (t == 0){
      if (g < 0) K32s = (T16s << 16);
      else {
        u32 acc = afterv;
        for (int b = 63; b >= 0; --b){
          u32 h = bs[b];
          acc += h;
          if (acc >= target){ K32s = (T16s << 16) | (u32)(g*64 + b); break; }
        }
      }
      ctr[4] = 6000u;
    } }
  __syncthreads();

  { u32 K = K32s;
    for (int i = t; i < NANCH; i += 1024){
      u32 key = sortkey(scores[i]);
      if (key >= K){
        u32 pos = atomicAdd(&ctr[0], 1u);
        if (pos < CAP) keys[pos] = ((u64)key << 32) | (u64)(u32)(~(u32)i);
      }
    } }
}

// ---------------- K-rank (verbatim) ----------------
__global__ __launch_bounds__(128) void k_rank(const u64* __restrict__ keys, u32* __restrict__ ctr,
                                              const float4* __restrict__ boxes,
                                              float4* __restrict__ topB, float* __restrict__ topA){
  __shared__ u64 ks[2048];
  const int t  = threadIdx.x;
  const int gi = blockIdx.x * 128 + t;
  u32 count = ctr[0]; if (count > CAP) count = CAP;
  u64 my = (gi < (int)count) ? keys[gi] : 0ull;
  int rank = 0;
  for (int c0 = 0; c0 < CAP; c0 += 2048){
    __syncthreads();
    for (int s = t; s < 2048; s += 128){
      int j = c0 + s;
      ks[s] = (j < (int)count) ? keys[j] : 0ull;
    }
    __syncthreads();
    if (gi < (int)count){
      const ulonglong2* kp = reinterpret_cast<const ulonglong2*>(ks);
      #pragma unroll 8
      for (int s = 0; s < 1024; ++s){
        ulonglong2 kv = kp[s];
        rank += (kv.x > my) + (kv.y > my);
      }
    }
  }
  if (gi < (int)count && rank < PRE){
    if (!((my >> 32) & 0x80000000ull))
      atomicMin((int*)(ctr + 4), rank);
    u32 idx = ~(u32)my;
    float4 bv = make_float4(0.f,0.f,0.f,0.f);
    float area = 1.f;
    if (idx < NANCH){
      bv = boxes[idx];
      area = (bv.z - bv.x + 1.f) * (bv.w - bv.y + 1.f);
    }
    topB[rank] = bv;
    topA[rank] = area;
  }
}

// ---------- K5: chunked exact NMS, single wave — replaces k_iou + k_reduce ----------
// Only PICKED boxes suppress (greedy invariant), so: per 64-candidate chunk,
// Phase A tests lanes' boxes vs the kept-list (LDS broadcast reads, no HBM);
// Phase B resolves in-chunk order via ballot+shfl (registers only). Exact
// equivalence: candidate suppressed <=> IoU>0.7 with an earlier pick. IoU and
// area expressions bit-identical to the R11-R17 k_iou. Early exit at 300 kept.
// Eliminates the M matrix and the 300 serial ~900-cyc row reads entirely.
__global__ __launch_bounds__(64) void k_nms3(const float4* __restrict__ topB,
                                             const u32* __restrict__ ctr, float* __restrict__ out){
  __shared__ float4 kb[POST];
  __shared__ float  ka[POST];
  __shared__ int    kidx[POST];
  const int t = threadIdx.x;
  int validN = (int)ctr[0];
  int finN   = (int)ctr[4];
  if (finN < validN) validN = finN;
  if (validN > PRE)  validN = PRE;

  int nk = 0;   // kept count (wave-uniform)
  for (int base = 0; base < validN && nk < POST; base += 64){
    int c = base + t;
    bool alive = (c < validN);
    float4 b = make_float4(0.f,0.f,0.f,0.f);
    float ar = 1.f;
    if (alive){
      b = topB[c];
      ar = (b.z - b.x + 1.f) * (b.w - b.y + 1.f);
    }
    // Phase A: test vs existing kept list (LDS broadcast, conflict-free)
    for (int j = 0; j < nk; ++j){
      float4 kbx = kb[j];
      float kar = ka[j];
      float xx1 = fmaxf(kbx.x, b.x);
      float yy1 = fmaxf(kbx.y, b.y);
      float xx2 = fminf(kbx.z, b.z);
      float yy2 = fminf(kbx.w, b.w);
      float iw = fmaxf(xx2 - xx1 + 1.f, 0.f);
      float ih = fmaxf(yy2 - yy1 + 1.f, 0.f);
      float inter = iw * ih;
      float iou = inter / (kar + ar - inter);
      if (iou > 0.7f) alive = false;
    }
    // Phase B: in-chunk greedy resolve (ballot + shfl, wave-synchronous)
    while (nk < POST){
      u64 bal = __ballot(alive);
      if (!bal) break;
      int L = (int)__ffsll((unsigned long long)bal) - 1;
      float px = __shfl(b.x, L, 64);
      float py = __shfl(b.y, L, 64);
      float pz = __shfl(b.z, L, 64);
      float pw = __shfl(b.w, L, 64);
      float pa = __shfl(ar, L, 64);
      if (t == 0){
        kb[nk]   = make_float4(px, py, pz, pw);
        ka[nk]   = pa;
        kidx[nk] = base + L;
      }
      nk++;
      if (t == L) alive = false;     // the pick itself
      if (alive){
        float xx1 = fmaxf(px, b.x);
        float yy1 = fmaxf(py, b.y);
        float xx2 = fminf(pz, b.z);
        float yy2 = fminf(pw, b.w);
        float iw = fmaxf(xx2 - xx1 + 1.f, 0.f);
        float ih = fmaxf(yy2 - yy1 + 1.f, 0.f);
        float inter = iw * ih;
        float iou = inter / (pa + ar - inter);
        if (iou > 0.7f) alive = false;
      }
    }
  }
  __syncthreads();
  for (int q = t; q < 1500; q += 64){
    int r = q / 5, c = q - r*5;
    float v = 0.f;
    if (r < nk && c > 0){
      float4 bx = kb[r];
      v = (c == 1) ? bx.x : (c == 2) ? bx.y : (c == 3) ? bx.z : bx.w;
    }
    out[q] = v;
  }
}

// ---------------- launch ----------------
extern "C" void kernel_launch(void* const* d_in, const int* in_sizes, int n_in,
                              void* d_out, int out_size, void* d_ws, size_t ws_size,
                              hipStream_t stream)
{
  const float* fm   = (const float*)d_in[0];
  const float* info = (const float*)d_in[1];
  const float* cw3  = (const float*)d_in[2];
  const float* cb3  = (const float*)d_in[3];
  const float* clw  = (const float*)d_in[4];
  const float* clb  = (const float*)d_in[5];
  const float* bbw  = (const float*)d_in[6];
  const float* bbb  = (const float*)d_in[7];
  float* out = (float*)d_out;

  char* base = (char*)d_ws;
  u32*   hist   = (u32*)  (base + 0);          // 65536 u32
  u32*   hist2  = (u32*)  (base + 262144);     // 65536 u32
  u32*   ctr    = (u32*)  (base + 524288);     // [0]=count [4]=finiteN
  float* Y      = (float*)(base + 524544);     // 12.58 MB
  float* scores = (float*)(base + 13107456);
  float4* boxes = (float4*)(base + 13328640);
  u64*   keys   = (u64*)  (base + 14213376);
  float4* topB  = (float4*)(base + 14278912);
  float* topA   = (float*)(base + 14375168);
  unsigned short* Xih = (unsigned short*)(base + 14399488);
  unsigned short* Xil = (unsigned short*)(base + 21022720);
  unsigned short* Wh2 = (unsigned short*)(base + 27645952);
  unsigned short* Wl2 = (unsigned short*)(base + 32364544);
  // total ws use: ~37.1 MB

  k_cvt   <<<1040, 256, 0, stream>>>(fm, cw3, Xih, Xil, Wh2, Wl2, (u32*)base);
  k_conv3 <<<dim3(16, 16), 256, 0, stream>>>(Xih, Xil, Wh2, Wl2, cb3, Y);
  k_head  <<<192, 256, 0, stream>>>(Y, clw, clb, bbw, bbb, info, scores, boxes, hist);
  k_sel   <<<1,  1024, 0, stream>>>(hist, hist2, scores, ctr, keys);
  k_rank  <<<64,  128, 0, stream>>>(keys, ctr, boxes, topB, topA);
  k_nms3  <<<1,    64, 0, stream>>>(topB, ctr, out);
}

// Round 19
// 630.840 us; speedup vs baseline: 1.3928x; 1.0099x over previous
//
#include <hip/hip_runtime.h>
#include <stdint.h>

typedef unsigned int u32;
typedef unsigned long long u64;
typedef __attribute__((ext_vector_type(8))) short v8s;   // 8 bf16 = 4 VGPR (MFMA A/B frag)
typedef __attribute__((ext_vector_type(4))) float v4f;   // MFMA C/D frag

#define HH 64
#define WW 96
#define HW 6144
#define CC 512
#define NANCH 55296
#define PRE 6000
#define POST 300
#define CAP 8192
#define PW 98
#define PH 66
#define ICPAD 40

__device__ __constant__ float c_aw[9] = {184.f,368.f,736.f,128.f,256.f,512.f,88.f,176.f,352.f};
__device__ __constant__ float c_ah[9] = {96.f,192.f,384.f,128.f,256.f,512.f,176.f,352.f,704.f};

__device__ __forceinline__ unsigned short bf16_rne(float x){
  u32 u = __float_as_uint(x);
  return (unsigned short)((u + 0x7FFFu + ((u >> 16) & 1u)) >> 16);
}
__device__ __forceinline__ u32 sortkey(float s){
  u32 u = __float_as_uint(s);
  return u ^ ((u & 0x80000000u) ? 0xFFFFFFFFu : 0x80000000u);
}

// ---------- K0: merged convert (X: 528 blocks, W: 512 blocks) + ws zeroing ----------
__global__ __launch_bounds__(256) void k_cvt(const float* __restrict__ X, const float* __restrict__ Wt,
                                             unsigned short* __restrict__ Xih, unsigned short* __restrict__ Xil,
                                             unsigned short* __restrict__ Wh2, unsigned short* __restrict__ Wl2,
                                             u32* __restrict__ zero_region){
  __shared__ float Ls[64][97];
  __shared__ float Ws[4608];
  const int b = blockIdx.x, tid = threadIdx.x;
  { int gid = b*256 + tid;
    if (gid < 131072) zero_region[gid] = 0u;          // hist + hist2
    if (gid < 16) zero_region[131072 + gid] = 0u; }   // ctr
  if (b < 528){
    const int rp  = b % 66;
    const int ic0 = (b / 66) * 64;
    const bool zrow = (rp == 0 || rp == PH-1);
    if (!zrow){
      int r = rp - 1;
      for (int i = tid; i < 6144; i += 256){
        int ii = i / 96, c = i - ii*96;
        Ls[ii][c] = X[(ic0+ii)*HW + r*WW + c];
      }
    }
    __syncthreads();
    for (int i = tid; i < PW*64; i += 256){
      int cp = i >> 6, icl = i & 63;
      float x = 0.f;
      if (!zrow && cp >= 1 && cp <= 96) x = Ls[icl][cp-1];
      unsigned short h = bf16_rne(x);
      float hf = __uint_as_float(((u32)h) << 16);
      unsigned short l = bf16_rne(x - hf);
      long o = ((long)(rp*PW + cp) << 9) + ic0 + icl;
      Xih[o] = h; Xil[o] = l;
    }
  } else {
    const int oc = b - 528;
    for (int i = tid; i < 4608; i += 256) Ws[i] = Wt[oc*4608 + i];
    __syncthreads();
    for (int i = tid; i < 4608; i += 256){
      int tap = i / 512, ic = i - tap*512;
      float x = Ws[ic*9 + tap];
      unsigned short h = bf16_rne(x);
      float hf = __uint_as_float(((u32)h) << 16);
      unsigned short l = bf16_rne(x - hf);
      long o = ((long)(tap*512 + oc) << 9) + ic;
      Wh2[o] = h; Wl2[o] = l;
    }
  }
}

// ---------- K1: MFMA conv, LDS-staged + register double-buffer (R15-proven, bit-exact) ----------
__global__ __launch_bounds__(256, 1) void k_conv3(
    const unsigned short* __restrict__ Xih, const unsigned short* __restrict__ Xil,
    const unsigned short* __restrict__ Wh2, const unsigned short* __restrict__ Wl2,
    const float* __restrict__ Bc, float* __restrict__ Y)
{
  __shared__ __attribute__((aligned(16))) unsigned short Ah[6*98*ICPAD];
  __shared__ __attribute__((aligned(16))) unsigned short Al[6*98*ICPAD];
  __shared__ __attribute__((aligned(16))) unsigned short Bh[9*32*ICPAD];
  __shared__ __attribute__((aligned(16))) unsigned short Bl[9*32*ICPAD];
  const int tid  = threadIdx.x;
  const int w    = tid >> 6;
  const int lane = tid & 63;
  const int lm   = lane & 15;
  const int q    = lane >> 4;
  const int y0   = blockIdx.x * 4;
  const int oc0  = blockIdx.y * 32;

  v4f acc[6][2];
  #pragma unroll
  for (int t = 0; t < 6; ++t)
    #pragma unroll
    for (int n = 0; n < 2; ++n)
      acc[t][n] = (v4f){0.f,0.f,0.f,0.f};

  u64 ra[19][2], rb[9][2];
  auto loadSlab = [&](int icg){
    #pragma unroll
    for (int n = 0; n < 19; ++n){
      int it = tid + 256*n;
      if (it < 4704){
        int i4 = it & 7, rc = it >> 3;
        int c = rc % 98, r = rc / 98;
        long src = ((long)((y0 + r)*PW + c) << 9) + icg*32 + i4*4;
        ra[n][0] = *reinterpret_cast<const u64*>(Xih + src);
        ra[n][1] = *reinterpret_cast<const u64*>(Xil + src);
      }
    }
    #pragma unroll
    for (int n = 0; n < 9; ++n){
      int it = tid + 256*n;
      if (it < 2304){
        int i4 = it & 7, to = it >> 3;
        int oc = to & 31, tap = to >> 5;
        long src = ((long)(tap*512 + oc0 + oc) << 9) + icg*32 + i4*4;
        rb[n][0] = *reinterpret_cast<const u64*>(Wh2 + src);
        rb[n][1] = *reinterpret_cast<const u64*>(Wl2 + src);
      }
    }
  };
  auto storeSlab = [&](){
    #pragma unroll
    for (int n = 0; n < 19; ++n){
      int it = tid + 256*n;
      if (it < 4704){
        int i4 = it & 7, rc = it >> 3;
        int dst = rc*ICPAD + i4*4;
        *reinterpret_cast<u64*>(Ah + dst) = ra[n][0];
        *reinterpret_cast<u64*>(Al + dst) = ra[n][1];
      }
    }
    #pragma unroll
    for (int n = 0; n < 9; ++n){
      int it = tid + 256*n;
      if (it < 2304){
        int i4 = it & 7, to = it >> 3;
        int dst = to*ICPAD + i4*4;
        *reinterpret_cast<u64*>(Bh + dst) = rb[n][0];
        *reinterpret_cast<u64*>(Bl + dst) = rb[n][1];
      }
    }
  };

  loadSlab(0);
  for (int icg = 0; icg < 16; ++icg){
    __syncthreads();
    storeSlab();
    __syncthreads();
    if (icg < 15) loadSlab(icg + 1);
    #pragma unroll
    for (int tap = 0; tap < 9; ++tap){
      const int dy = tap / 3, dx = tap - dy*3;
      v8s ah[6], al[6], bh[2], bl[2];
      #pragma unroll
      for (int t = 0; t < 6; ++t){
        int a = ((w + dy)*98 + 16*t + lm + dx)*ICPAD + q*8;
        ah[t] = *reinterpret_cast<const v8s*>(Ah + a);
        al[t] = *reinterpret_cast<const v8s*>(Al + a);
      }
      #pragma unroll
      for (int n = 0; n < 2; ++n){
        int a = (tap*32 + n*16 + lm)*ICPAD + q*8;
        bh[n] = *reinterpret_cast<const v8s*>(Bh + a);
        bl[n] = *reinterpret_cast<const v8s*>(Bl + a);
      }
      #pragma unroll
      for (int t = 0; t < 6; ++t)
        #pragma unroll
        for (int n = 0; n < 2; ++n){
          acc[t][n] = __builtin_amdgcn_mfma_f32_16x16x32_bf16(al[t], bl[n], acc[t][n], 0, 0, 0);
          acc[t][n] = __builtin_amdgcn_mfma_f32_16x16x32_bf16(al[t], bh[n], acc[t][n], 0, 0, 0);
          acc[t][n] = __builtin_amdgcn_mfma_f32_16x16x32_bf16(ah[t], bl[n], acc[t][n], 0, 0, 0);
          acc[t][n] = __builtin_amdgcn_mfma_f32_16x16x32_bf16(ah[t], bh[n], acc[t][n], 0, 0, 0);
        }
    }
  }
  const int yrow = y0 + w;
  #pragma unroll
  for (int n = 0; n < 2; ++n){
    int oc = oc0 + n*16 + lm;
    float b = Bc[oc];
    #pragma unroll
    for (int t = 0; t < 6; ++t){
      float4 v;
      v.x = fmaxf(acc[t][n].x + b, 0.f);
      v.y = fmaxf(acc[t][n].y + b, 0.f);
      v.z = fmaxf(acc[t][n].z + b, 0.f);
      v.w = fmaxf(acc[t][n].w + b, 0.f);
      *reinterpret_cast<float4*>(Y + (long)oc*HW + yrow*WW + 16*t + q*4) = v;
    }
  }
}

// ---------------- K2: 1x1 heads + softmax + box decode (+ hist) — R17 verbatim ----------------
__global__ __launch_bounds__(256) void k_head(
    const float* __restrict__ Y, const float* __restrict__ cw,
    const float* __restrict__ cb, const float* __restrict__ bw,
    const float* __restrict__ bb, const float* __restrict__ info,
    float* __restrict__ scores, float4* __restrict__ boxes, u32* __restrict__ hist)
{
  __shared__ float Ys[4096];
  __shared__ float Wsh[4096];
  const int tid = threadIdx.x;
  const int p0  = blockIdx.x * 32;
  const int po  = tid & 15;
  const int oj  = tid >> 4;
  float accM[2][4], accC[2][4];
  #pragma unroll
  for (int p = 0; p < 2; ++p)
    #pragma unroll
    for (int k = 0; k < 4; ++k){ accM[p][k] = 0.f; accC[p][k] = 0.f; }

  for (int c0 = 0; c0 < CC; c0 += 64){
    __syncthreads();
    for (int i = tid; i < 2048; i += 256){
      int c = i >> 5, p = i & 31;
      Ys[i] = Y[(c0 + c) * HW + p0 + p];
    }
    for (int i = tid; i < 4096; i += 256){
      int c = i >> 6, o = i & 63;
      int gc = c0 + c;
      float v = 0.f;
      if (o < 18) v = cw[o * 512 + gc];
      else if (o < 54) v = bw[(o - 18) * 512 + gc];
      Wsh[i] = v;
    }
    __syncthreads();
    for (int c = 0; c < 64; ++c){
      const float2 xv = *reinterpret_cast<const float2*>(Ys + c*32 + po*2);
      float xa[2] = {xv.x, xv.y};
      const float* wrd = Wsh + c*64 + oj;
      float wv[4] = {wrd[0], wrd[16], wrd[32], wrd[48]};
      #pragma unroll
      for (int p = 0; p < 2; ++p)
        #pragma unroll
        for (int k = 0; k < 4; ++k)
          accC[p][k] = __fmaf_rn(xa[p], wv[k], accC[p][k]);
    }
    #pragma unroll
    for (int p = 0; p < 2; ++p)
      #pragma unroll
      for (int k = 0; k < 4; ++k){ accM[p][k] += accC[p][k]; accC[p][k] = 0.f; }
  }
  __syncthreads();
  #pragma unroll
  for (int p = 0; p < 2; ++p)
    #pragma unroll
    for (int k = 0; k < 4; ++k){
      int o = oj + 16*k;
      float bias = (o < 18) ? cb[o] : ((o < 54) ? bb[o - 18] : 0.f);
      Ys[(po*2 + p)*64 + o] = accM[p][k] + bias;
    }
  __syncthreads();
  float imH = info[0], imW = info[1], imS = info[2];
  for (int it = tid; it < 288; it += 256){
    int pl = it / 9;
    int a  = it - pl*9;
    const float* L = Ys + pl*64;
    float l0 = L[a], l1 = L[9 + a];
    float mx = fmaxf(l0, l1);
    float e0 = expf(l0 - mx), e1 = expf(l1 - mx);
    float sc = e1 / (e0 + e1);
    float d0 = L[18 + a*4 + 0], d1 = L[18 + a*4 + 1];
    float d2 = L[18 + a*4 + 2], d3 = L[18 + a*4 + 3];
    int pos = p0 + pl;
    int yy = pos / 96;
    int xx = pos - yy * 96;
    float aw = c_aw[a], ah = c_ah[a];
    float acx = (float)(xx * 16 + 8);
    float acy = (float)(yy * 16 + 8);
    float cx = __fadd_rn(__fmul_rn(d0, aw), acx);
    float cy = __fadd_rn(__fmul_rn(d1, ah), acy);
    float pw = __fmul_rn(expf(d2), aw);
    float ph = __fmul_rn(expf(d3), ah);
    float hx = __fmul_rn(0.5f, pw);
    float hy = __fmul_rn(0.5f, ph);
    float x1 = fminf(fmaxf(__fadd_rn(cx, -hx), 0.f), imW - 1.f);
    float y1 = fminf(fmaxf(__fadd_rn(cy, -hy), 0.f), imH - 1.f);
    float x2 = fminf(fmaxf(__fadd_rn(cx,  hx), 0.f), imW - 1.f);
    float y2 = fminf(fmaxf(__fadd_rn(cy,  hy), 0.f), imH - 1.f);
    float ms = 16.f * imS;
    bool keep = ((x2 - x1 + 1.f) >= ms) && ((y2 - y1 + 1.f) >= ms);
    int g = pos * 9 + a;
    float val = keep ? sc : -__builtin_inff();
    scores[g] = val;
    boxes[g]  = make_float4(x1, y1, x2, y2);
    atomicAdd(&hist[sortkey(val) >> 16], 1u);
  }
}

// ---------- K3: fused selection — thresh1+hist2+thresh2+compact, ONE block (verbatim) ----------
__global__ __launch_bounds__(1024) void k_sel(const u32* __restrict__ hist, u32* __restrict__ hist2,
                                              const float* __restrict__ scores,
                                              u32* __restrict__ ctr, u64* __restrict__ keys){
  __shared__ u32 cs[1024];
  __shared__ u32 bs[64];
  __shared__ int selg;
  __shared__ u32 afterv, T16s, aboves, K32s;
  const int t = threadIdx.x;
  const int b0 = t * 64;

  if (t == 0) selg = -1;
  __syncthreads();
  { u32 s = 0;
    for (int i = 0; i < 64; ++i) s += hist[b0 + i];
    cs[t] = s; }
  __syncthreads();
  for (int off = 1; off < 1024; off <<= 1){
    u32 v = cs[t];
    u32 ad = (t + off < 1024) ? cs[t + off] : 0u;
    __syncthreads();
    cs[t] = v + ad;
    __syncthreads();
  }
  { u32 here  = cs[t];
    u32 after = (t < 1023) ? cs[t + 1] : 0u;
    if (here >= 6000u && after < 6000u){ selg = t; afterv = after; } }
  __syncthreads();
  { int g = selg;
    if (g >= 0 && t < 64) bs[t] = hist[g*64 + t];
    __syncthreads();
    if (t == 0){
      if (g < 0){ T16s = 0u; aboves = 0u; }
      else {
        u32 acc = afterv;
        for (int b = 63; b >= 0; --b){
          u32 h = bs[b];
          acc += h;
          if (acc >= 6000u){ T16s = (u32)(g*64 + b); aboves = acc - h; break; }
        }
      }
    } }
  __syncthreads();

  { u32 pfx = T16s;
    for (int i = t; i < NANCH; i += 1024){
      u32 key = sortkey(scores[i]);
      if ((key >> 16) == pfx) atomicAdd(&hist2[key & 0xFFFFu], 1u);
    } }
  __threadfence();
  __syncthreads();

  if (t == 0) selg = -1;
  __syncthreads();
  const u32 target = 6000u - aboves;
  { u32 s = 0;
    for (int i = 0; i < 64; ++i) s += hist2[b0 + i];
    cs[t] = s; }
  __syncthreads();
  for (int off = 1; off < 1024; off <<= 1){
    u32 v = cs[t];
    u32 ad = (t + off < 1024) ? cs[t + off] : 0u;
    __syncthreads();
    cs[t] = v + ad;
    __syncthreads();
  }
  { u32 here  = cs[t];
    u32 after = (t < 1023) ? cs[t + 1] : 0u;
    if (here >= target && after < target){ selg = t; afterv = after; } }
  __syncthreads();
  { int g = selg;
    if (g >= 0 && t < 64) bs[t] = hist2[g*64 + t];
    __syncthreads();
    if (t == 0){
      if (g < 0) K32s = (T16s << 16);
      else {
        u32 acc = afterv;
        for (int b = 63; b >= 0; --b){
          u32 h = bs[b];
          acc += h;
          if (acc >= target){ K32s = (T16s << 16) | (u32)(g*64 + b); break; }
        }
      }
      ctr[4] = 6000u;
    } }
  __syncthreads();

  { u32 K = K32s;
    for (int i = t; i < NANCH; i += 1024){
      u32 key = sortkey(scores[i]);
      if (key >= K){
        u32 pos = atomicAdd(&ctr[0], 1u);
        if (pos < CAP) keys[pos] = ((u64)key << 32) | (u64)(u32)(~(u32)i);
      }
    } }
}

// ---------------- K-rank (verbatim) ----------------
__global__ __launch_bounds__(128) void k_rank(const u64* __restrict__ keys, u32* __restrict__ ctr,
                                              const float4* __restrict__ boxes,
                                              float4* __restrict__ topB, float* __restrict__ topA){
  __shared__ u64 ks[2048];
  const int t  = threadIdx.x;
  const int gi = blockIdx.x * 128 + t;
  u32 count = ctr[0]; if (count > CAP) count = CAP;
  u64 my = (gi < (int)count) ? keys[gi] : 0ull;
  int rank = 0;
  for (int c0 = 0; c0 < CAP; c0 += 2048){
    __syncthreads();
    for (int s = t; s < 2048; s += 128){
      int j = c0 + s;
      ks[s] = (j < (int)count) ? keys[j] : 0ull;
    }
    __syncthreads();
    if (gi < (int)count){
      const ulonglong2* kp = reinterpret_cast<const ulonglong2*>(ks);
      #pragma unroll 8
      for (int s = 0; s < 1024; ++s){
        ulonglong2 kv = kp[s];
        rank += (kv.x > my) + (kv.y > my);
      }
    }
  }
  if (gi < (int)count && rank < PRE){
    if (!((my >> 32) & 0x80000000ull))
      atomicMin((int*)(ctr + 4), rank);
    u32 idx = ~(u32)my;
    float4 bv = make_float4(0.f,0.f,0.f,0.f);
    float area = 1.f;
    if (idx < NANCH){
      bv = boxes[idx];
      area = (bv.z - bv.x + 1.f) * (bv.w - bv.y + 1.f);
    }
    topB[rank] = bv;
    topA[rank] = area;
  }
}

// ---------- K5: chunked exact NMS, single wave (R18 algorithm; R19: Phase A batched by 8) ----------
// R18 post-mortem: Phase A's runtime-bound loop = one ds_read_b128 + full LDS
// latency PER KEPT TEST (~450k cyc total). Batch 8 kept-box loads into registers
// per iteration -> one latency amortized over 8 tests. Same picks, same output.
__global__ __launch_bounds__(64) void k_nms3(const float4* __restrict__ topB,
                                             const u32* __restrict__ ctr, float* __restrict__ out){
  __shared__ float4 kb[POST];
  __shared__ float  ka[POST];
  const int t = threadIdx.x;
  int validN = (int)ctr[0];
  int finN   = (int)ctr[4];
  if (finN < validN) validN = finN;
  if (validN > PRE)  validN = PRE;

  int nk = 0;   // kept count (wave-uniform)
  for (int base = 0; base < validN && nk < POST; base += 64){
    int c = base + t;
    bool alive = (c < validN);
    float4 b = make_float4(0.f,0.f,0.f,0.f);
    float ar = 1.f;
    if (alive){
      b = topB[c];
      ar = (b.z - b.x + 1.f) * (b.w - b.y + 1.f);
    }
    // Phase A: test vs kept list, batched 8 at a time (amortize LDS latency)
    int j = 0;
    for (; j + 8 <= nk; j += 8){
      float4 kx[8]; float kaa[8];
      #pragma unroll
      for (int u = 0; u < 8; ++u){ kx[u] = kb[j+u]; kaa[u] = ka[j+u]; }
      #pragma unroll
      for (int u = 0; u < 8; ++u){
        float xx1 = fmaxf(kx[u].x, b.x);
        float yy1 = fmaxf(kx[u].y, b.y);
        float xx2 = fminf(kx[u].z, b.z);
        float yy2 = fminf(kx[u].w, b.w);
        float iw = fmaxf(xx2 - xx1 + 1.f, 0.f);
        float ih = fmaxf(yy2 - yy1 + 1.f, 0.f);
        float inter = iw * ih;
        float iou = inter / (kaa[u] + ar - inter);
        if (iou > 0.7f) alive = false;
      }
    }
    for (; j < nk; ++j){
      float4 kbx = kb[j];
      float kar = ka[j];
      float xx1 = fmaxf(kbx.x, b.x);
      float yy1 = fmaxf(kbx.y, b.y);
      float xx2 = fminf(kbx.z, b.z);
      float yy2 = fminf(kbx.w, b.w);
      float iw = fmaxf(xx2 - xx1 + 1.f, 0.f);
      float ih = fmaxf(yy2 - yy1 + 1.f, 0.f);
      float inter = iw * ih;
      float iou = inter / (kar + ar - inter);
      if (iou > 0.7f) alive = false;
    }
    // Phase B: in-chunk greedy resolve (ballot + shfl, wave-synchronous)
    while (nk < POST){
      u64 bal = __ballot(alive);
      if (!bal) break;
      int L = (int)__ffsll((unsigned long long)bal) - 1;
      float px = __shfl(b.x, L, 64);
      float py = __shfl(b.y, L, 64);
      float pz = __shfl(b.z, L, 64);
      float pw = __shfl(b.w, L, 64);
      float pa = __shfl(ar, L, 64);
      if (t == 0){
        kb[nk] = make_float4(px, py, pz, pw);
        ka[nk] = pa;
      }
      nk++;
      if (t == L) alive = false;
      if (alive){
        float xx1 = fmaxf(px, b.x);
        float yy1 = fmaxf(py, b.y);
        float xx2 = fminf(pz, b.z);
        float yy2 = fminf(pw, b.w);
        float iw = fmaxf(xx2 - xx1 + 1.f, 0.f);
        float ih = fmaxf(yy2 - yy1 + 1.f, 0.f);
        float inter = iw * ih;
        float iou = inter / (pa + ar - inter);
        if (iou > 0.7f) alive = false;
      }
    }
  }
  __syncthreads();
  for (int q = t; q < 1500; q += 64){
    int r = q / 5, c = q - r*5;
    float v = 0.f;
    if (r < nk && c > 0){
      float4 bx = kb[r];
      v = (c == 1) ? bx.x : (c == 2) ? bx.y : (c == 3) ? bx.z : bx.w;
    }
    out[q] = v;
  }
}

// ---------------- launch ----------------
extern "C" void kernel_launch(void* const* d_in, const int* in_sizes, int n_in,
                              void* d_out, int out_size, void* d_ws, size_t ws_size,
                              hipStream_t stream)
{
  const float* fm   = (const float*)d_in[0];
  const float* info = (const float*)d_in[1];
  const float* cw3  = (const float*)d_in[2];
  const float* cb3  = (const float*)d_in[3];
  const float* clw  = (const float*)d_in[4];
  const float* clb  = (const float*)d_in[5];
  const float* bbw  = (const float*)d_in[6];
  const float* bbb  = (const float*)d_in[7];
  float* out = (float*)d_out;

  char* base = (char*)d_ws;
  u32*   hist   = (u32*)  (base + 0);          // 65536 u32
  u32*   hist2  = (u32*)  (base + 262144);     // 65536 u32
  u32*   ctr    = (u32*)  (base + 524288);     // [0]=count [4]=finiteN
  float* Y      = (float*)(base + 524544);     // 12.58 MB
  float* scores = (float*)(base + 13107456);
  float4* boxes = (float4*)(base + 13328640);
  u64*   keys   = (u64*)  (base + 14213376);
  float4* topB  = (float4*)(base + 14278912);
  float* topA   = (float*)(base + 14375168);
  unsigned short* Xih = (unsigned short*)(base + 14399488);
  unsigned short* Xil = (unsigned short*)(base + 21022720);
  unsigned short* Wh2 = (unsigned short*)(base + 27645952);
  unsigned short* Wl2 = (unsigned short*)(base + 32364544);
  // total ws use: ~37.1 MB

  k_cvt   <<<1040, 256, 0, stream>>>(fm, cw3, Xih, Xil, Wh2, Wl2, (u32*)base);
  k_conv3 <<<dim3(16, 16), 256, 0, stream>>>(Xih, Xil, Wh2, Wl2, cb3, Y);
  k_head  <<<192, 256, 0, stream>>>(Y, clw, clb, bbw, bbb, info, scores, boxes, hist);
  k_sel   <<<1,  1024, 0, stream>>>(hist, hist2, scores, ctr, keys);
  k_rank  <<<64,  128, 0, stream>>>(keys, ctr, boxes, topB, topA);
  k_nms3  <<<1,    64, 0, stream>>>(topB, ctr, out);
}

// Round 20
// 570.943 us; speedup vs baseline: 1.5389x; 1.1049x over previous
//
#include <hip/hip_runtime.h>
#include <stdint.h>

typedef unsigned int u32;
typedef unsigned long long u64;
typedef __attribute__((ext_vector_type(8))) short v8s;   // 8 bf16 = 4 VGPR (MFMA A/B frag)
typedef __attribute__((ext_vector_type(4))) float v4f;   // MFMA C/D frag

#define HH 64
#define WW 96
#define HW 6144
#define CC 512
#define NANCH 55296
#define PRE 6000
#define POST 300
#define CAP 8192
#define PW 98
#define PH 66
#define ICPAD 40

__device__ __constant__ float c_aw[9] = {184.f,368.f,736.f,128.f,256.f,512.f,88.f,176.f,352.f};
__device__ __constant__ float c_ah[9] = {96.f,192.f,384.f,128.f,256.f,512.f,176.f,352.f,704.f};

__device__ __forceinline__ unsigned short bf16_rne(float x){
  u32 u = __float_as_uint(x);
  return (unsigned short)((u + 0x7FFFu + ((u >> 16) & 1u)) >> 16);
}
__device__ __forceinline__ u32 sortkey(float s){
  u32 u = __float_as_uint(s);
  return u ^ ((u & 0x80000000u) ? 0xFFFFFFFFu : 0x80000000u);
}

// ---------- K0: merged convert (X: 528 blocks, W: 512 blocks) + ws zeroing ----------
__global__ __launch_bounds__(256) void k_cvt(const float* __restrict__ X, const float* __restrict__ Wt,
                                             unsigned short* __restrict__ Xih, unsigned short* __restrict__ Xil,
                                             unsigned short* __restrict__ Wh2, unsigned short* __restrict__ Wl2,
                                             u32* __restrict__ zero_region){
  __shared__ float Ls[64][97];
  __shared__ float Ws[4608];
  const int b = blockIdx.x, tid = threadIdx.x;
  { int gid = b*256 + tid;
    if (gid < 131072) zero_region[gid] = 0u;          // hist + hist2
    if (gid < 16) zero_region[131072 + gid] = 0u; }   // ctr
  if (b < 528){
    const int rp  = b % 66;
    const int ic0 = (b / 66) * 64;
    const bool zrow = (rp == 0 || rp == PH-1);
    if (!zrow){
      int r = rp - 1;
      for (int i = tid; i < 6144; i += 256){
        int ii = i / 96, c = i - ii*96;
        Ls[ii][c] = X[(ic0+ii)*HW + r*WW + c];
      }
    }
    __syncthreads();
    for (int i = tid; i < PW*64; i += 256){
      int cp = i >> 6, icl = i & 63;
      float x = 0.f;
      if (!zrow && cp >= 1 && cp <= 96) x = Ls[icl][cp-1];
      unsigned short h = bf16_rne(x);
      float hf = __uint_as_float(((u32)h) << 16);
      unsigned short l = bf16_rne(x - hf);
      long o = ((long)(rp*PW + cp) << 9) + ic0 + icl;
      Xih[o] = h; Xil[o] = l;
    }
  } else {
    const int oc = b - 528;
    for (int i = tid; i < 4608; i += 256) Ws[i] = Wt[oc*4608 + i];
    __syncthreads();
    for (int i = tid; i < 4608; i += 256){
      int tap = i / 512, ic = i - tap*512;
      float x = Ws[ic*9 + tap];
      unsigned short h = bf16_rne(x);
      float hf = __uint_as_float(((u32)h) << 16);
      unsigned short l = bf16_rne(x - hf);
      long o = ((long)(tap*512 + oc) << 9) + ic;
      Wh2[o] = h; Wl2[o] = l;
    }
  }
}

// ---------- K1: MFMA conv, LDS-staged + register double-buffer (R15-proven, bit-exact) ----------
__global__ __launch_bounds__(256, 1) void k_conv3(
    const unsigned short* __restrict__ Xih, const unsigned short* __restrict__ Xil,
    const unsigned short* __restrict__ Wh2, const unsigned short* __restrict__ Wl2,
    const float* __restrict__ Bc, float* __restrict__ Y)
{
  __shared__ __attribute__((aligned(16))) unsigned short Ah[6*98*ICPAD];
  __shared__ __attribute__((aligned(16))) unsigned short Al[6*98*ICPAD];
  __shared__ __attribute__((aligned(16))) unsigned short Bh[9*32*ICPAD];
  __shared__ __attribute__((aligned(16))) unsigned short Bl[9*32*ICPAD];
  const int tid  = threadIdx.x;
  const int w    = tid >> 6;
  const int lane = tid & 63;
  const int lm   = lane & 15;
  const int q    = lane >> 4;
  const int y0   = blockIdx.x * 4;
  const int oc0  = blockIdx.y * 32;

  v4f acc[6][2];
  #pragma unroll
  for (int t = 0; t < 6; ++t)
    #pragma unroll
    for (int n = 0; n < 2; ++n)
      acc[t][n] = (v4f){0.f,0.f,0.f,0.f};

  u64 ra[19][2], rb[9][2];
  auto loadSlab = [&](int icg){
    #pragma unroll
    for (int n = 0; n < 19; ++n){
      int it = tid + 256*n;
      if (it < 4704){
        int i4 = it & 7, rc = it >> 3;
        int c = rc % 98, r = rc / 98;
        long src = ((long)((y0 + r)*PW + c) << 9) + icg*32 + i4*4;
        ra[n][0] = *reinterpret_cast<const u64*>(Xih + src);
        ra[n][1] = *reinterpret_cast<const u64*>(Xil + src);
      }
    }
    #pragma unroll
    for (int n = 0; n < 9; ++n){
      int it = tid + 256*n;
      if (it < 2304){
        int i4 = it & 7, to = it >> 3;
        int oc = to & 31, tap = to >> 5;
        long src = ((long)(tap*512 + oc0 + oc) << 9) + icg*32 + i4*4;
        rb[n][0] = *reinterpret_cast<const u64*>(Wh2 + src);
        rb[n][1] = *reinterpret_cast<const u64*>(Wl2 + src);
      }
    }
  };
  auto storeSlab = [&](){
    #pragma unroll
    for (int n = 0; n < 19; ++n){
      int it = tid + 256*n;
      if (it < 4704){
        int i4 = it & 7, rc = it >> 3;
        int dst = rc*ICPAD + i4*4;
        *reinterpret_cast<u64*>(Ah + dst) = ra[n][0];
        *reinterpret_cast<u64*>(Al + dst) = ra[n][1];
      }
    }
    #pragma unroll
    for (int n = 0; n < 9; ++n){
      int it = tid + 256*n;
      if (it < 2304){
        int i4 = it & 7, to = it >> 3;
        int dst = to*ICPAD + i4*4;
        *reinterpret_cast<u64*>(Bh + dst) = rb[n][0];
        *reinterpret_cast<u64*>(Bl + dst) = rb[n][1];
      }
    }
  };

  loadSlab(0);
  for (int icg = 0; icg < 16; ++icg){
    __syncthreads();
    storeSlab();
    __syncthreads();
    if (icg < 15) loadSlab(icg + 1);
    #pragma unroll
    for (int tap = 0; tap < 9; ++tap){
      const int dy = tap / 3, dx = tap - dy*3;
      v8s ah[6], al[6], bh[2], bl[2];
      #pragma unroll
      for (int t = 0; t < 6; ++t){
        int a = ((w + dy)*98 + 16*t + lm + dx)*ICPAD + q*8;
        ah[t] = *reinterpret_cast<const v8s*>(Ah + a);
        al[t] = *reinterpret_cast<const v8s*>(Al + a);
      }
      #pragma unroll
      for (int n = 0; n < 2; ++n){
        int a = (tap*32 + n*16 + lm)*ICPAD + q*8;
        bh[n] = *reinterpret_cast<const v8s*>(Bh + a);
        bl[n] = *reinterpret_cast<const v8s*>(Bl + a);
      }
      #pragma unroll
      for (int t = 0; t < 6; ++t)
        #pragma unroll
        for (int n = 0; n < 2; ++n){
          acc[t][n] = __builtin_amdgcn_mfma_f32_16x16x32_bf16(al[t], bl[n], acc[t][n], 0, 0, 0);
          acc[t][n] = __builtin_amdgcn_mfma_f32_16x16x32_bf16(al[t], bh[n], acc[t][n], 0, 0, 0);
          acc[t][n] = __builtin_amdgcn_mfma_f32_16x16x32_bf16(ah[t], bl[n], acc[t][n], 0, 0, 0);
          acc[t][n] = __builtin_amdgcn_mfma_f32_16x16x32_bf16(ah[t], bh[n], acc[t][n], 0, 0, 0);
        }
    }
  }
  const int yrow = y0 + w;
  #pragma unroll
  for (int n = 0; n < 2; ++n){
    int oc = oc0 + n*16 + lm;
    float b = Bc[oc];
    #pragma unroll
    for (int t = 0; t < 6; ++t){
      float4 v;
      v.x = fmaxf(acc[t][n].x + b, 0.f);
      v.y = fmaxf(acc[t][n].y + b, 0.f);
      v.z = fmaxf(acc[t][n].z + b, 0.f);
      v.w = fmaxf(acc[t][n].w + b, 0.f);
      *reinterpret_cast<float4*>(Y + (long)oc*HW + yrow*WW + 16*t + q*4) = v;
    }
  }
}

// ---------------- K2: 1x1 heads + softmax + box decode (+ hist) — R17 verbatim ----------------
__global__ __launch_bounds__(256) void k_head(
    const float* __restrict__ Y, const float* __restrict__ cw,
    const float* __restrict__ cb, const float* __restrict__ bw,
    const float* __restrict__ bb, const float* __restrict__ info,
    float* __restrict__ scores, float4* __restrict__ boxes, u32* __restrict__ hist)
{
  __shared__ float Ys[4096];
  __shared__ float Wsh[4096];
  const int tid = threadIdx.x;
  const int p0  = blockIdx.x * 32;
  const int po  = tid & 15;
  const int oj  = tid >> 4;
  float accM[2][4], accC[2][4];
  #pragma unroll
  for (int p = 0; p < 2; ++p)
    #pragma unroll
    for (int k = 0; k < 4; ++k){ accM[p][k] = 0.f; accC[p][k] = 0.f; }

  for (int c0 = 0; c0 < CC; c0 += 64){
    __syncthreads();
    for (int i = tid; i < 2048; i += 256){
      int c = i >> 5, p = i & 31;
      Ys[i] = Y[(c0 + c) * HW + p0 + p];
    }
    for (int i = tid; i < 4096; i += 256){
      int c = i >> 6, o = i & 63;
      int gc = c0 + c;
      float v = 0.f;
      if (o < 18) v = cw[o * 512 + gc];
      else if (o < 54) v = bw[(o - 18) * 512 + gc];
      Wsh[i] = v;
    }
    __syncthreads();
    for (int c = 0; c < 64; ++c){
      const float2 xv = *reinterpret_cast<const float2*>(Ys + c*32 + po*2);
      float xa[2] = {xv.x, xv.y};
      const float* wrd = Wsh + c*64 + oj;
      float wv[4] = {wrd[0], wrd[16], wrd[32], wrd[48]};
      #pragma unroll
      for (int p = 0; p < 2; ++p)
        #pragma unroll
        for (int k = 0; k < 4; ++k)
          accC[p][k] = __fmaf_rn(xa[p], wv[k], accC[p][k]);
    }
    #pragma unroll
    for (int p = 0; p < 2; ++p)
      #pragma unroll
      for (int k = 0; k < 4; ++k){ accM[p][k] += accC[p][k]; accC[p][k] = 0.f; }
  }
  __syncthreads();
  #pragma unroll
  for (int p = 0; p < 2; ++p)
    #pragma unroll
    for (int k = 0; k < 4; ++k){
      int o = oj + 16*k;
      float bias = (o < 18) ? cb[o] : ((o < 54) ? bb[o - 18] : 0.f);
      Ys[(po*2 + p)*64 + o] = accM[p][k] + bias;
    }
  __syncthreads();
  float imH = info[0], imW = info[1], imS = info[2];
  for (int it = tid; it < 288; it += 256){
    int pl = it / 9;
    int a  = it - pl*9;
    const float* L = Ys + pl*64;
    float l0 = L[a], l1 = L[9 + a];
    float mx = fmaxf(l0, l1);
    float e0 = expf(l0 - mx), e1 = expf(l1 - mx);
    float sc = e1 / (e0 + e1);
    float d0 = L[18 + a*4 + 0], d1 = L[18 + a*4 + 1];
    float d2 = L[18 + a*4 + 2], d3 = L[18 + a*4 + 3];
    int pos = p0 + pl;
    int yy = pos / 96;
    int xx = pos - yy * 96;
    float aw = c_aw[a], ah = c_ah[a];
    float acx = (float)(xx * 16 + 8);
    float acy = (float)(yy * 16 + 8);
    float cx = __fadd_rn(__fmul_rn(d0, aw), acx);
    float cy = __fadd_rn(__fmul_rn(d1, ah), acy);
    float pw = __fmul_rn(expf(d2), aw);
    float ph = __fmul_rn(expf(d3), ah);
    float hx = __fmul_rn(0.5f, pw);
    float hy = __fmul_rn(0.5f, ph);
    float x1 = fminf(fmaxf(__fadd_rn(cx, -hx), 0.f), imW - 1.f);
    float y1 = fminf(fmaxf(__fadd_rn(cy, -hy), 0.f), imH - 1.f);
    float x2 = fminf(fmaxf(__fadd_rn(cx,  hx), 0.f), imW - 1.f);
    float y2 = fminf(fmaxf(__fadd_rn(cy,  hy), 0.f), imH - 1.f);
    float ms = 16.f * imS;
    bool keep = ((x2 - x1 + 1.f) >= ms) && ((y2 - y1 + 1.f) >= ms);
    int g = pos * 9 + a;
    float val = keep ? sc : -__builtin_inff();
    scores[g] = val;
    boxes[g]  = make_float4(x1, y1, x2, y2);
    atomicAdd(&hist[sortkey(val) >> 16], 1u);
  }
}

// ---------- K3: fused selection — thresh1+hist2+thresh2+compact, ONE block (verbatim) ----------
__global__ __launch_bounds__(1024) void k_sel(const u32* __restrict__ hist, u32* __restrict__ hist2,
                                              const float* __restrict__ scores,
                                              u32* __restrict__ ctr, u64* __restrict__ keys){
  __shared__ u32 cs[1024];
  __shared__ u32 bs[64];
  __shared__ int selg;
  __shared__ u32 afterv, T16s, aboves, K32s;
  const int t = threadIdx.x;
  const int b0 = t * 64;

  if (t == 0) selg = -1;
  __syncthreads();
  { u32 s = 0;
    for (int i = 0; i < 64; ++i) s += hist[b0 + i];
    cs[t] = s; }
  __syncthreads();
  for (int off = 1; off < 1024; off <<= 1){
    u32 v = cs[t];
    u32 ad = (t + off < 1024) ? cs[t + off] : 0u;
    __syncthreads();
    cs[t] = v + ad;
    __syncthreads();
  }
  { u32 here  = cs[t];
    u32 after = (t < 1023) ? cs[t + 1] : 0u;
    if (here >= 6000u && after < 6000u){ selg = t; afterv = after; } }
  __syncthreads();
  { int g = selg;
    if (g >= 0 && t < 64) bs[t] = hist[g*64 + t];
    __syncthreads();
    if (t == 0){
      if (g < 0){ T16s = 0u; aboves = 0u; }
      else {
        u32 acc = afterv;
        for (int b = 63; b >= 0; --b){
          u32 h = bs[b];
          acc += h;
          if (acc >= 6000u){ T16s = (u32)(g*64 + b); aboves = acc - h; break; }
        }
      }
    } }
  __syncthreads();

  { u32 pfx = T16s;
    for (int i = t; i < NANCH; i += 1024){
      u32 key = sortkey(scores[i]);
      if ((key >> 16) == pfx) atomicAdd(&hist2[key & 0xFFFFu], 1u);
    } }
  __threadfence();
  __syncthreads();

  if (t == 0) selg = -1;
  __syncthreads();
  const u32 target = 6000u - aboves;
  { u32 s = 0;
    for (int i = 0; i < 64; ++i) s += hist2[b0 + i];
    cs[t] = s; }
  __syncthreads();
  for (int off = 1; off < 1024; off <<= 1){
    u32 v = cs[t];
    u32 ad = (t + off < 1024) ? cs[t + off] : 0u;
    __syncthreads();
    cs[t] = v + ad;
    __syncthreads();
  }
  { u32 here  = cs[t];
    u32 after = (t < 1023) ? cs[t + 1] : 0u;
    if (here >= target && after < target){ selg = t; afterv = after; } }
  __syncthreads();
  { int g = selg;
    if (g >= 0 && t < 64) bs[t] = hist2[g*64 + t];
    __syncthreads();
    if (t == 0){
      if (g < 0) K32s = (T16s << 16);
      else {
        u32 acc = afterv;
        for (int b = 63; b >= 0; --b){
          u32 h = bs[b];
          acc += h;
          if (acc >= target){ K32s = (T16s << 16) | (u32)(g*64 + b); break; }
        }
      }
      ctr[4] = 6000u;
    } }
  __syncthreads();

  { u32 K = K32s;
    for (int i = t; i < NANCH; i += 1024){
      u32 key = sortkey(scores[i]);
      if (key >= K){
        u32 pos = atomicAdd(&ctr[0], 1u);
        if (pos < CAP) keys[pos] = ((u64)key << 32) | (u64)(u32)(~(u32)i);
      }
    } }
}

// ---------------- K-rank (verbatim) ----------------
__global__ __launch_bounds__(128) void k_rank(const u64* __restrict__ keys, u32* __restrict__ ctr,
                                              const float4* __restrict__ boxes,
                                              float4* __restrict__ topB, float* __restrict__ topA){
  __shared__ u64 ks[2048];
  const int t  = threadIdx.x;
  const int gi = blockIdx.x * 128 + t;
  u32 count = ctr[0]; if (count > CAP) count = CAP;
  u64 my = (gi < (int)count) ? keys[gi] : 0ull;
  int rank = 0;
  for (int c0 = 0; c0 < CAP; c0 += 2048){
    __syncthreads();
    for (int s = t; s < 2048; s += 128){
      int j = c0 + s;
      ks[s] = (j < (int)count) ? keys[j] : 0ull;
    }
    __syncthreads();
    if (gi < (int)count){
      const ulonglong2* kp = reinterpret_cast<const ulonglong2*>(ks);
      #pragma unroll 8
      for (int s = 0; s < 1024; ++s){
        ulonglong2 kv = kp[s];
        rank += (kv.x > my) + (kv.y > my);
      }
    }
  }
  if (gi < (int)count && rank < PRE){
    if (!((my >> 32) & 0x80000000ull))
      atomicMin((int*)(ctr + 4), rank);
    u32 idx = ~(u32)my;
    float4 bv = make_float4(0.f,0.f,0.f,0.f);
    float area = 1.f;
    if (idx < NANCH){
      bv = boxes[idx];
      area = (bv.z - bv.x + 1.f) * (bv.w - bv.y + 1.f);
    }
    topB[rank] = bv;
    topA[rank] = area;
  }
}

// ---------- K5: chunked exact NMS — R20: 4-wave Phase A split + wave-0 Phase B ----------
// R19 post-mortem: single-wave VALU volume (~15k kept-tests x ~25cyc) was the bound,
// not LDS latency. Phase A tests are independent across kept boxes: all 4 waves hold
// the SAME 64 candidates; wave w tests kept[j], j = w mod 4; per-wave ballots combined
// in LDS (AND). Phase B (serial greedy resolve) stays on wave 0. Same picks/output.
// Next chunk's candidates prefetched into registers (vmcnt overlaps Phase A lgkm work).
__global__ __launch_bounds__(256) void k_nms3(const float4* __restrict__ topB,
                                              const u32* __restrict__ ctr, float* __restrict__ out){
  __shared__ float4 kb[POST];
  __shared__ float  ka[POST];
  __shared__ u64    am[4];
  __shared__ int    nkS;
  const int tid  = threadIdx.x;
  const int wv   = tid >> 6;
  const int lane = tid & 63;
  int validN = (int)ctr[0];
  int finN   = (int)ctr[4];
  if (finN < validN) validN = finN;
  if (validN > PRE)  validN = PRE;
  if (tid == 0) nkS = 0;
  __syncthreads();

  // prefetch chunk 0 candidates
  float4 bnx = make_float4(0.f,0.f,0.f,0.f);
  if (lane < validN) bnx = topB[lane];

  for (int base = 0; base < validN; base += 64){
    int nk = nkS;                      // uniform (post-barrier)
    if (nk >= POST) break;
    int c = base + lane;
    bool alive = (c < validN);
    float4 b = bnx;
    float ar = alive ? (b.z - b.x + 1.f) * (b.w - b.y + 1.f) : 1.f;
    // prefetch next chunk (in flight during Phase A/B)
    { int cn = base + 64 + lane;
      if (cn < validN) bnx = topB[cn]; }
    // Phase A: wave wv tests kept[j], j = wv, wv+4, ... ; batched by 8 for ILP
    int j = wv;
    for (; j + 28 < nk; j += 32){
      float4 kx[8]; float kaa[8];
      #pragma unroll
      for (int u = 0; u < 8; ++u){ kx[u] = kb[j + 4*u]; kaa[u] = ka[j + 4*u]; }
      #pragma unroll
      for (int u = 0; u < 8; ++u){
        float xx1 = fmaxf(kx[u].x, b.x);
        float yy1 = fmaxf(kx[u].y, b.y);
        float xx2 = fminf(kx[u].z, b.z);
        float yy2 = fminf(kx[u].w, b.w);
        float iw = fmaxf(xx2 - xx1 + 1.f, 0.f);
        float ih = fmaxf(yy2 - yy1 + 1.f, 0.f);
        float inter = iw * ih;
        float iou = inter / (kaa[u] + ar - inter);
        if (iou > 0.7f) alive = false;
      }
    }
    for (; j < nk; j += 4){
      float4 kbx = kb[j];
      float kar = ka[j];
      float xx1 = fmaxf(kbx.x, b.x);
      float yy1 = fmaxf(kbx.y, b.y);
      float xx2 = fminf(kbx.z, b.z);
      float yy2 = fminf(kbx.w, b.w);
      float iw = fmaxf(xx2 - xx1 + 1.f, 0.f);
      float ih = fmaxf(yy2 - yy1 + 1.f, 0.f);
      float inter = iw * ih;
      float iou = inter / (kar + ar - inter);
      if (iou > 0.7f) alive = false;
    }
    { u64 bal = __ballot(alive);
      if (lane == 0) am[wv] = bal; }
    __syncthreads();
    // Phase B: wave 0 resolves in-chunk order with combined mask
    if (wv == 0){
      u64 comb = am[0] & am[1] & am[2] & am[3];
      alive = ((comb >> lane) & 1ull) != 0ull;
      int nkl = nk;
      while (nkl < POST){
        u64 bal = __ballot(alive);
        if (!bal) break;
        int L = (int)__ffsll((unsigned long long)bal) - 1;
        float px = __shfl(b.x, L, 64);
        float py = __shfl(b.y, L, 64);
        float pz = __shfl(b.z, L, 64);
        float pw = __shfl(b.w, L, 64);
        float pa = __shfl(ar, L, 64);
        if (lane == 0){
          kb[nkl] = make_float4(px, py, pz, pw);
          ka[nkl] = pa;
        }
        nkl++;
        if (lane == L) alive = false;
        if (alive){
          float xx1 = fmaxf(px, b.x);
          float yy1 = fmaxf(py, b.y);
          float xx2 = fminf(pz, b.z);
          float yy2 = fminf(pw, b.w);
          float iw = fmaxf(xx2 - xx1 + 1.f, 0.f);
          float ih = fmaxf(yy2 - yy1 + 1.f, 0.f);
          float inter = iw * ih;
          float iou = inter / (pa + ar - inter);
          if (iou > 0.7f) alive = false;
        }
      }
      if (lane == 0) nkS = nkl;
    }
    __syncthreads();
  }
  int nk = nkS;
  for (int q = tid; q < 1500; q += 256){
    int r = q / 5, c = q - r*5;
    float v = 0.f;
    if (r < nk && c > 0){
      float4 bx = kb[r];
      v = (c == 1) ? bx.x : (c == 2) ? bx.y : (c == 3) ? bx.z : bx.w;
    }
    out[q] = v;
  }
}

// ---------------- launch ----------------
extern "C" void kernel_launch(void* const* d_in, const int* in_sizes, int n_in,
                              void* d_out, int out_size, void* d_ws, size_t ws_size,
                              hipStream_t stream)
{
  const float* fm   = (const float*)d_in[0];
  const float* info = (const float*)d_in[1];
  const float* cw3  = (const float*)d_in[2];
  const float* cb3  = (const float*)d_in[3];
  const float* clw  = (const float*)d_in[4];
  const float* clb  = (const float*)d_in[5];
  const float* bbw  = (const float*)d_in[6];
  const float* bbb  = (const float*)d_in[7];
  float* out = (float*)d_out;

  char* base = (char*)d_ws;
  u32*   hist   = (u32*)  (base + 0);          // 65536 u32
  u32*   hist2  = (u32*)  (base + 262144);     // 65536 u32
  u32*   ctr    = (u32*)  (base + 524288);     // [0]=count [4]=finiteN
  float* Y      = (float*)(base + 524544);     // 12.58 MB
  float* scores = (float*)(base + 13107456);
  float4* boxes = (float4*)(base + 13328640);
  u64*   keys   = (u64*)  (base + 14213376);
  float4* topB  = (float4*)(base + 14278912);
  float* topA   = (float*)(base + 14375168);
  unsigned short* Xih = (unsigned short*)(base + 14399488);
  unsigned short* Xil = (unsigned short*)(base + 21022720);
  unsigned short* Wh2 = (unsigned short*)(base + 27645952);
  unsigned short* Wl2 = (unsigned short*)(base + 32364544);
  // total ws use: ~37.1 MB

  k_cvt   <<<1040, 256, 0, stream>>>(fm, cw3, Xih, Xil, Wh2, Wl2, (u32*)base);
  k_conv3 <<<dim3(16, 16), 256, 0, stream>>>(Xih, Xil, Wh2, Wl2, cb3, Y);
  k_head  <<<192, 256, 0, stream>>>(Y, clw, clb, bbw, bbb, info, scores, boxes, hist);
  k_sel   <<<1,  1024, 0, stream>>>(hist, hist2, scores, ctr, keys);
  k_rank  <<<64,  128, 0, stream>>>(keys, ctr, boxes, topB, topA);
  k_nms3  <<<1,   256, 0, stream>>>(topB, ctr, out);
}

// Round 21
// 557.340 us; speedup vs baseline: 1.5765x; 1.0244x over previous
//
#include <hip/hip_runtime.h>
#include <stdint.h>

typedef unsigned int u32;
typedef unsigned long long u64;
typedef __attribute__((ext_vector_type(8))) short v8s;   // 8 bf16 = 4 VGPR (MFMA A/B frag)
typedef __attribute__((ext_vector_type(4))) float v4f;   // MFMA C/D frag

#define HH 64
#define WW 96
#define HW 6144
#define CC 512
#define NANCH 55296
#define PRE 6000
#define POST 300
#define CAP 8192
#define PW 98
#define PH 66
#define ICPAD 40

__device__ __constant__ float c_aw[9] = {184.f,368.f,736.f,128.f,256.f,512.f,88.f,176.f,352.f};
__device__ __constant__ float c_ah[9] = {96.f,192.f,384.f,128.f,256.f,512.f,176.f,352.f,704.f};

__device__ __forceinline__ unsigned short bf16_rne(float x){
  u32 u = __float_as_uint(x);
  return (unsigned short)((u + 0x7FFFu + ((u >> 16) & 1u)) >> 16);
}
__device__ __forceinline__ u32 sortkey(float s){
  u32 u = __float_as_uint(s);
  return u ^ ((u & 0x80000000u) ? 0xFFFFFFFFu : 0x80000000u);
}

// ---------- K0: merged convert (X: 528, W-conv: 512, W-head transpose: 128 blocks) + zeroing ----------
__global__ __launch_bounds__(256) void k_cvt(const float* __restrict__ X, const float* __restrict__ Wt,
                                             const float* __restrict__ cw, const float* __restrict__ bw,
                                             unsigned short* __restrict__ Xih, unsigned short* __restrict__ Xil,
                                             unsigned short* __restrict__ Wh2, unsigned short* __restrict__ Wl2,
                                             float* __restrict__ Whd, u32* __restrict__ zero_region){
  __shared__ float Ls[64][97];
  __shared__ float Ws[4608];
  const int b = blockIdx.x, tid = threadIdx.x;
  { int gid = b*256 + tid;
    if (gid < 131072) zero_region[gid] = 0u;          // hist + hist2
    if (gid < 16) zero_region[131072 + gid] = 0u; }   // ctr
  if (b < 528){
    const int rp  = b % 66;
    const int ic0 = (b / 66) * 64;
    const bool zrow = (rp == 0 || rp == PH-1);
    if (!zrow){
      int r = rp - 1;
      for (int i = tid; i < 6144; i += 256){
        int ii = i / 96, c = i - ii*96;
        Ls[ii][c] = X[(ic0+ii)*HW + r*WW + c];
      }
    }
    __syncthreads();
    for (int i = tid; i < PW*64; i += 256){
      int cp = i >> 6, icl = i & 63;
      float x = 0.f;
      if (!zrow && cp >= 1 && cp <= 96) x = Ls[icl][cp-1];
      unsigned short h = bf16_rne(x);
      float hf = __uint_as_float(((u32)h) << 16);
      unsigned short l = bf16_rne(x - hf);
      long o = ((long)(rp*PW + cp) << 9) + ic0 + icl;
      Xih[o] = h; Xil[o] = l;
    }
  } else if (b < 1040){
    const int oc = b - 528;
    for (int i = tid; i < 4608; i += 256) Ws[i] = Wt[oc*4608 + i];
    __syncthreads();
    for (int i = tid; i < 4608; i += 256){
      int tap = i / 512, ic = i - tap*512;
      float x = Ws[ic*9 + tap];
      unsigned short h = bf16_rne(x);
      float hf = __uint_as_float(((u32)h) << 16);
      unsigned short l = bf16_rne(x - hf);
      long o = ((long)(tap*512 + oc) << 9) + ic;
      Wh2[o] = h; Wl2[o] = l;
    }
  } else {
    // head-weight transpose: Whd[gc*64 + o] = (o<18 ? cw[o*512+gc] : o<54 ? bw[(o-18)*512+gc] : 0)
    int idx = (b - 1040)*256 + tid;          // 0..32767 (gc fast -> coalesced source reads)
    int o  = idx >> 9;
    int gc = idx & 511;
    float v = 0.f;
    if (o < 18) v = cw[o*512 + gc];
    else if (o < 54) v = bw[(o-18)*512 + gc];
    Whd[gc*64 + o] = v;
  }
}

// ---------- K1: MFMA conv, LDS-staged + register double-buffer (R15-proven, bit-exact) ----------
__global__ __launch_bounds__(256, 1) void k_conv3(
    const unsigned short* __restrict__ Xih, const unsigned short* __restrict__ Xil,
    const unsigned short* __restrict__ Wh2, const unsigned short* __restrict__ Wl2,
    const float* __restrict__ Bc, float* __restrict__ Y)
{
  __shared__ __attribute__((aligned(16))) unsigned short Ah[6*98*ICPAD];
  __shared__ __attribute__((aligned(16))) unsigned short Al[6*98*ICPAD];
  __shared__ __attribute__((aligned(16))) unsigned short Bh[9*32*ICPAD];
  __shared__ __attribute__((aligned(16))) unsigned short Bl[9*32*ICPAD];
  const int tid  = threadIdx.x;
  const int w    = tid >> 6;
  const int lane = tid & 63;
  const int lm   = lane & 15;
  const int q    = lane >> 4;
  const int y0   = blockIdx.x * 4;
  const int oc0  = blockIdx.y * 32;

  v4f acc[6][2];
  #pragma unroll
  for (int t = 0; t < 6; ++t)
    #pragma unroll
    for (int n = 0; n < 2; ++n)
      acc[t][n] = (v4f){0.f,0.f,0.f,0.f};

  u64 ra[19][2], rb[9][2];
  auto loadSlab = [&](int icg){
    #pragma unroll
    for (int n = 0; n < 19; ++n){
      int it = tid + 256*n;
      if (it < 4704){
        int i4 = it & 7, rc = it >> 3;
        int c = rc % 98, r = rc / 98;
        long src = ((long)((y0 + r)*PW + c) << 9) + icg*32 + i4*4;
        ra[n][0] = *reinterpret_cast<const u64*>(Xih + src);
        ra[n][1] = *reinterpret_cast<const u64*>(Xil + src);
      }
    }
    #pragma unroll
    for (int n = 0; n < 9; ++n){
      int it = tid + 256*n;
      if (it < 2304){
        int i4 = it & 7, to = it >> 3;
        int oc = to & 31, tap = to >> 5;
        long src = ((long)(tap*512 + oc0 + oc) << 9) + icg*32 + i4*4;
        rb[n][0] = *reinterpret_cast<const u64*>(Wh2 + src);
        rb[n][1] = *reinterpret_cast<const u64*>(Wl2 + src);
      }
    }
  };
  auto storeSlab = [&](){
    #pragma unroll
    for (int n = 0; n < 19; ++n){
      int it = tid + 256*n;
      if (it < 4704){
        int i4 = it & 7, rc = it >> 3;
        int dst = rc*ICPAD + i4*4;
        *reinterpret_cast<u64*>(Ah + dst) = ra[n][0];
        *reinterpret_cast<u64*>(Al + dst) = ra[n][1];
      }
    }
    #pragma unroll
    for (int n = 0; n < 9; ++n){
      int it = tid + 256*n;
      if (it < 2304){
        int i4 = it & 7, to = it >> 3;
        int dst = to*ICPAD + i4*4;
        *reinterpret_cast<u64*>(Bh + dst) = rb[n][0];
        *reinterpret_cast<u64*>(Bl + dst) = rb[n][1];
      }
    }
  };

  loadSlab(0);
  for (int icg = 0; icg < 16; ++icg){
    __syncthreads();
    storeSlab();
    __syncthreads();
    if (icg < 15) loadSlab(icg + 1);
    #pragma unroll
    for (int tap = 0; tap < 9; ++tap){
      const int dy = tap / 3, dx = tap - dy*3;
      v8s ah[6], al[6], bh[2], bl[2];
      #pragma unroll
      for (int t = 0; t < 6; ++t){
        int a = ((w + dy)*98 + 16*t + lm + dx)*ICPAD + q*8;
        ah[t] = *reinterpret_cast<const v8s*>(Ah + a);
        al[t] = *reinterpret_cast<const v8s*>(Al + a);
      }
      #pragma unroll
      for (int n = 0; n < 2; ++n){
        int a = (tap*32 + n*16 + lm)*ICPAD + q*8;
        bh[n] = *reinterpret_cast<const v8s*>(Bh + a);
        bl[n] = *reinterpret_cast<const v8s*>(Bl + a);
      }
      #pragma unroll
      for (int t = 0; t < 6; ++t)
        #pragma unroll
        for (int n = 0; n < 2; ++n){
          acc[t][n] = __builtin_amdgcn_mfma_f32_16x16x32_bf16(al[t], bl[n], acc[t][n], 0, 0, 0);
          acc[t][n] = __builtin_amdgcn_mfma_f32_16x16x32_bf16(al[t], bh[n], acc[t][n], 0, 0, 0);
          acc[t][n] = __builtin_amdgcn_mfma_f32_16x16x32_bf16(ah[t], bl[n], acc[t][n], 0, 0, 0);
          acc[t][n] = __builtin_amdgcn_mfma_f32_16x16x32_bf16(ah[t], bh[n], acc[t][n], 0, 0, 0);
        }
    }
  }
  const int yrow = y0 + w;
  #pragma unroll
  for (int n = 0; n < 2; ++n){
    int oc = oc0 + n*16 + lm;
    float b = Bc[oc];
    #pragma unroll
    for (int t = 0; t < 6; ++t){
      float4 v;
      v.x = fmaxf(acc[t][n].x + b, 0.f);
      v.y = fmaxf(acc[t][n].y + b, 0.f);
      v.z = fmaxf(acc[t][n].z + b, 0.f);
      v.w = fmaxf(acc[t][n].w + b, 0.f);
      *reinterpret_cast<float4*>(Y + (long)oc*HW + yrow*WW + 16*t + q*4) = v;
    }
  }
}

// ---------------- K2: 1x1 heads + softmax + box decode (+ hist) ----------------
// R21: 384 blocks x 16 positions (6 waves/CU, was 3) + coalesced W staging from
// the pre-transposed Whd (R16-R20's cw/bw loads were 64-lane stride-2KB gathers).
// Per-(pos,out) accumulation order IDENTICAL -> bit-identical scores/boxes.
__global__ __launch_bounds__(256) void k_head(
    const float* __restrict__ Y, const float* __restrict__ Whd,
    const float* __restrict__ cb, const float* __restrict__ bb,
    const float* __restrict__ info,
    float* __restrict__ scores, float4* __restrict__ boxes, u32* __restrict__ hist)
{
  __shared__ float Ys[1024];    // chunk: [c][16 pos]; epilogue: [16 pos][64 outs]
  __shared__ float Wsh[4096];   // [c][64 outs]
  const int tid = threadIdx.x;
  const int p0  = blockIdx.x * 16;
  const int po  = tid & 15;     // position p0+po
  const int oj  = tid >> 4;     // outputs oj + 16k
  float accM[4], accC[4];
  #pragma unroll
  for (int k = 0; k < 4; ++k){ accM[k] = 0.f; accC[k] = 0.f; }

  for (int c0 = 0; c0 < CC; c0 += 64){
    __syncthreads();
    for (int i = tid; i < 1024; i += 256){
      int c = i >> 4, p = i & 15;
      Ys[i] = Y[(c0 + c) * HW + p0 + p];
    }
    { const float4* src = reinterpret_cast<const float4*>(Whd + c0*64);
      float4* dst = reinterpret_cast<float4*>(Wsh);
      for (int i = tid; i < 1024; i += 256) dst[i] = src[i]; }
    __syncthreads();
    for (int c = 0; c < 64; ++c){
      float xa = Ys[c*16 + po];
      const float* wrd = Wsh + c*64 + oj;
      float wv[4] = {wrd[0], wrd[16], wrd[32], wrd[48]};
      #pragma unroll
      for (int k = 0; k < 4; ++k)
        accC[k] = __fmaf_rn(xa, wv[k], accC[k]);
    }
    #pragma unroll
    for (int k = 0; k < 4; ++k){ accM[k] += accC[k]; accC[k] = 0.f; }
  }
  __syncthreads();
  #pragma unroll
  for (int k = 0; k < 4; ++k){
    int o = oj + 16*k;
    float bias = (o < 18) ? cb[o] : ((o < 54) ? bb[o - 18] : 0.f);
    Ys[po*64 + o] = accM[k] + bias;
  }
  __syncthreads();
  float imH = info[0], imW = info[1], imS = info[2];
  for (int it = tid; it < 144; it += 256){
    int pl = it / 9;
    int a  = it - pl*9;
    const float* L = Ys + pl*64;
    float l0 = L[a], l1 = L[9 + a];
    float mx = fmaxf(l0, l1);
    float e0 = expf(l0 - mx), e1 = expf(l1 - mx);
    float sc = e1 / (e0 + e1);
    float d0 = L[18 + a*4 + 0], d1 = L[18 + a*4 + 1];
    float d2 = L[18 + a*4 + 2], d3 = L[18 + a*4 + 3];
    int pos = p0 + pl;
    int yy = pos / 96;
    int xx = pos - yy * 96;
    float aw = c_aw[a], ah = c_ah[a];
    float acx = (float)(xx * 16 + 8);
    float acy = (float)(yy * 16 + 8);
    float cx = __fadd_rn(__fmul_rn(d0, aw), acx);
    float cy = __fadd_rn(__fmul_rn(d1, ah), acy);
    float pw = __fmul_rn(expf(d2), aw);
    float ph = __fmul_rn(expf(d3), ah);
    float hx = __fmul_rn(0.5f, pw);
    float hy = __fmul_rn(0.5f, ph);
    float x1 = fminf(fmaxf(__fadd_rn(cx, -hx), 0.f), imW - 1.f);
    float y1 = fminf(fmaxf(__fadd_rn(cy, -hy), 0.f), imH - 1.f);
    float x2 = fminf(fmaxf(__fadd_rn(cx,  hx), 0.f), imW - 1.f);
    float y2 = fminf(fmaxf(__fadd_rn(cy,  hy), 0.f), imH - 1.f);
    float ms = 16.f * imS;
    bool keep = ((x2 - x1 + 1.f) >= ms) && ((y2 - y1 + 1.f) >= ms);
    int g = pos * 9 + a;
    float val = keep ? sc : -__builtin_inff();
    scores[g] = val;
    boxes[g]  = make_float4(x1, y1, x2, y2);
    atomicAdd(&hist[sortkey(val) >> 16], 1u);
  }
}

// ---------- K3: fused selection — thresh1+hist2+thresh2+compact, ONE block (verbatim) ----------
__global__ __launch_bounds__(1024) void k_sel(const u32* __restrict__ hist, u32* __restrict__ hist2,
                                              const float* __restrict__ scores,
                                              u32* __restrict__ ctr, u64* __restrict__ keys){
  __shared__ u32 cs[1024];
  __shared__ u32 bs[64];
  __shared__ int selg;
  __shared__ u32 afterv, T16s, aboves, K32s;
  const int t = threadIdx.x;
  const int b0 = t * 64;

  if (t == 0) selg = -1;
  __syncthreads();
  { u32 s = 0;
    for (int i = 0; i < 64; ++i) s += hist[b0 + i];
    cs[t] = s; }
  __syncthreads();
  for (int off = 1; off < 1024; off <<= 1){
    u32 v = cs[t];
    u32 ad = (t + off < 1024) ? cs[t + off] : 0u;
    __syncthreads();
    cs[t] = v + ad;
    __syncthreads();
  }
  { u32 here  = cs[t];
    u32 after = (t < 1023) ? cs[t + 1] : 0u;
    if (here >= 6000u && after < 6000u){ selg = t; afterv = after; } }
  __syncthreads();
  { int g = selg;
    if (g >= 0 && t < 64) bs[t] = hist[g*64 + t];
    __syncthreads();
    if (t == 0){
      if (g < 0){ T16s = 0u; aboves = 0u; }
      else {
        u32 acc = afterv;
        for (int b = 63; b >= 0; --b){
          u32 h = bs[b];
          acc += h;
          if (acc >= 6000u){ T16s = (u32)(g*64 + b); aboves = acc - h; break; }
        }
      }
    } }
  __syncthreads();

  { u32 pfx = T16s;
    for (int i = t; i < NANCH; i += 1024){
      u32 key = sortkey(scores[i]);
      if ((key >> 16) == pfx) atomicAdd(&hist2[key & 0xFFFFu], 1u);
    } }
  __threadfence();
  __syncthreads();

  if (t == 0) selg = -1;
  __syncthreads();
  const u32 target = 6000u - aboves;
  { u32 s = 0;
    for (int i = 0; i < 64; ++i) s += hist2[b0 + i];
    cs[t] = s; }
  __syncthreads();
  for (int off = 1; off < 1024; off <<= 1){
    u32 v = cs[t];
    u32 ad = (t + off < 1024) ? cs[t + off] : 0u;
    __syncthreads();
    cs[t] = v + ad;
    __syncthreads();
  }
  { u32 here  = cs[t];
    u32 after = (t < 1023) ? cs[t + 1] : 0u;
    if (here >= target && after < target){ selg = t; afterv = after; } }
  __syncthreads();
  { int g = selg;
    if (g >= 0 && t < 64) bs[t] = hist2[g*64 + t];
    __syncthreads();
    if (t == 0){
      if (g < 0) K32s = (T16s << 16);
      else {
        u32 acc = afterv;
        for (int b = 63; b >= 0; --b){
          u32 h = bs[b];
          acc += h;
          if (acc >= target){ K32s = (T16s << 16) | (u32)(g*64 + b); break; }
        }
      }
      ctr[4] = 6000u;
    } }
  __syncthreads();

  { u32 K = K32s;
    for (int i = t; i < NANCH; i += 1024){
      u32 key = sortkey(scores[i]);
      if (key >= K){
        u32 pos = atomicAdd(&ctr[0], 1u);
        if (pos < CAP) keys[pos] = ((u64)key << 32) | (u64)(u32)(~(u32)i);
      }
    } }
}

// ---------------- K-rank (verbatim) ----------------
__global__ __launch_bounds__(128) void k_rank(const u64* __restrict__ keys, u32* __restrict__ ctr,
                                              const float4* __restrict__ boxes,
                                              float4* __restrict__ topB, float* __restrict__ topA){
  __shared__ u64 ks[2048];
  const int t  = threadIdx.x;
  const int gi = blockIdx.x * 128 + t;
  u32 count = ctr[0]; if (count > CAP) count = CAP;
  u64 my = (gi < (int)count) ? keys[gi] : 0ull;
  int rank = 0;
  for (int c0 = 0; c0 < CAP; c0 += 2048){
    __syncthreads();
    for (int s = t; s < 2048; s += 128){
      int j = c0 + s;
      ks[s] = (j < (int)count) ? keys[j] : 0ull;
    }
    __syncthreads();
    if (gi < (int)count){
      const ulonglong2* kp = reinterpret_cast<const ulonglong2*>(ks);
      #pragma unroll 8
      for (int s = 0; s < 1024; ++s){
        ulonglong2 kv = kp[s];
        rank += (kv.x > my) + (kv.y > my);
      }
    }
  }
  if (gi < (int)count && rank < PRE){
    if (!((my >> 32) & 0x80000000ull))
      atomicMin((int*)(ctr + 4), rank);
    u32 idx = ~(u32)my;
    float4 bv = make_float4(0.f,0.f,0.f,0.f);
    float area = 1.f;
    if (idx < NANCH){
      bv = boxes[idx];
      area = (bv.z - bv.x + 1.f) * (bv.w - bv.y + 1.f);
    }
    topB[rank] = bv;
    topA[rank] = area;
  }
}

// ---------- K5: chunked exact NMS — 4-wave Phase A split + wave-0 Phase B (R20-proven) ----------
__global__ __launch_bounds__(256) void k_nms3(const float4* __restrict__ topB,
                                              const u32* __restrict__ ctr, float* __restrict__ out){
  __shared__ float4 kb[POST];
  __shared__ float  ka[POST];
  __shared__ u64    am[4];
  __shared__ int    nkS;
  const int tid  = threadIdx.x;
  const int wv   = tid >> 6;
  const int lane = tid & 63;
  int validN = (int)ctr[0];
  int finN   = (int)ctr[4];
  if (finN < validN) validN = finN;
  if (validN > PRE)  validN = PRE;
  if (tid == 0) nkS = 0;
  __syncthreads();

  float4 bnx = make_float4(0.f,0.f,0.f,0.f);
  if (lane < validN) bnx = topB[lane];

  for (int base = 0; base < validN; base += 64){
    int nk = nkS;
    if (nk >= POST) break;
    int c = base + lane;
    bool alive = (c < validN);
    float4 b = bnx;
    float ar = alive ? (b.z - b.x + 1.f) * (b.w - b.y + 1.f) : 1.f;
    { int cn = base + 64 + lane;
      if (cn < validN) bnx = topB[cn]; }
    int j = wv;
    for (; j + 28 < nk; j += 32){
      float4 kx[8]; float kaa[8];
      #pragma unroll
      for (int u = 0; u < 8; ++u){ kx[u] = kb[j + 4*u]; kaa[u] = ka[j + 4*u]; }
      #pragma unroll
      for (int u = 0; u < 8; ++u){
        float xx1 = fmaxf(kx[u].x, b.x);
        float yy1 = fmaxf(kx[u].y, b.y);
        float xx2 = fminf(kx[u].z, b.z);
        float yy2 = fminf(kx[u].w, b.w);
        float iw = fmaxf(xx2 - xx1 + 1.f, 0.f);
        float ih = fmaxf(yy2 - yy1 + 1.f, 0.f);
        float inter = iw * ih;
        float iou = inter / (kaa[u] + ar - inter);
        if (iou > 0.7f) alive = false;
      }
    }
    for (; j < nk; j += 4){
      float4 kbx = kb[j];
      float kar = ka[j];
      float xx1 = fmaxf(kbx.x, b.x);
      float yy1 = fmaxf(kbx.y, b.y);
      float xx2 = fminf(kbx.z, b.z);
      float yy2 = fminf(kbx.w, b.w);
      float iw = fmaxf(xx2 - xx1 + 1.f, 0.f);
      float ih = fmaxf(yy2 - yy1 + 1.f, 0.f);
      float inter = iw * ih;
      float iou = inter / (kar + ar - inter);
      if (iou > 0.7f) alive = false;
    }
    { u64 bal = __ballot(alive);
      if (lane == 0) am[wv] = bal; }
    __syncthreads();
    if (wv == 0){
      u64 comb = am[0] & am[1] & am[2] & am[3];
      alive = ((comb >> lane) & 1ull) != 0ull;
      int nkl = nk;
      while (nkl < POST){
        u64 bal = __ballot(alive);
        if (!bal) break;
        int L = (int)__ffsll((unsigned long long)bal) - 1;
        float px = __shfl(b.x, L, 64);
        float py = __shfl(b.y, L, 64);
        float pz = __shfl(b.z, L, 64);
        float pw = __shfl(b.w, L, 64);
        float pa = __shfl(ar, L, 64);
        if (lane == 0){
          kb[nkl] = make_float4(px, py, pz, pw);
          ka[nkl] = pa;
        }
        nkl++;
        if (lane == L) alive = false;
        if (alive){
          float xx1 = fmaxf(px, b.x);
          float yy1 = fmaxf(py, b.y);
          float xx2 = fminf(pz, b.z);
          float yy2 = fminf(pw, b.w);
          float iw = fmaxf(xx2 - xx1 + 1.f, 0.f);
          float ih = fmaxf(yy2 - yy1 + 1.f, 0.f);
          float inter = iw * ih;
          float iou = inter / (pa + ar - inter);
          if (iou > 0.7f) alive = false;
        }
      }
      if (lane == 0) nkS = nkl;
    }
    __syncthreads();
  }
  int nk = nkS;
  for (int q = tid; q < 1500; q += 256){
    int r = q / 5, c = q - r*5;
    float v = 0.f;
    if (r < nk && c > 0){
      float4 bx = kb[r];
      v = (c == 1) ? bx.x : (c == 2) ? bx.y : (c == 3) ? bx.z : bx.w;
    }
    out[q] = v;
  }
}

// ---------------- launch ----------------
extern "C" void kernel_launch(void* const* d_in, const int* in_sizes, int n_in,
                              void* d_out, int out_size, void* d_ws, size_t ws_size,
                              hipStream_t stream)
{
  const float* fm   = (const float*)d_in[0];
  const float* info = (const float*)d_in[1];
  const float* cw3  = (const float*)d_in[2];
  const float* cb3  = (const float*)d_in[3];
  const float* clw  = (const float*)d_in[4];
  const float* clb  = (const float*)d_in[5];
  const float* bbw  = (const float*)d_in[6];
  const float* bbb  = (const float*)d_in[7];
  float* out = (float*)d_out;

  char* base = (char*)d_ws;
  u32*   hist   = (u32*)  (base + 0);          // 65536 u32
  u32*   hist2  = (u32*)  (base + 262144);     // 65536 u32
  u32*   ctr    = (u32*)  (base + 524288);     // [0]=count [4]=finiteN
  float* Y      = (float*)(base + 524544);     // 12.58 MB
  float* scores = (float*)(base + 13107456);
  float4* boxes = (float4*)(base + 13328640);
  u64*   keys   = (u64*)  (base + 14213376);
  float4* topB  = (float4*)(base + 14278912);
  float* topA   = (float*)(base + 14375168);
  unsigned short* Xih = (unsigned short*)(base + 14399488);
  unsigned short* Xil = (unsigned short*)(base + 21022720);
  unsigned short* Wh2 = (unsigned short*)(base + 27645952);
  unsigned short* Wl2 = (unsigned short*)(base + 32364544);
  float* Whd = (float*)(base + 37083136);      // 512*64 f32 = 131072 B
  // total ws use: 37214208 B (~37.2 MB)

  k_cvt   <<<1168, 256, 0, stream>>>(fm, cw3, clw, bbw, Xih, Xil, Wh2, Wl2, Whd, (u32*)base);
  k_conv3 <<<dim3(16, 16), 256, 0, stream>>>(Xih, Xil, Wh2, Wl2, cb3, Y);
  k_head  <<<384, 256, 0, stream>>>(Y, Whd, clb, bbb, info, scores, boxes, hist);
  k_sel   <<<1,  1024, 0, stream>>>(hist, hist2, scores, ctr, keys);
  k_rank  <<<64,  128, 0, stream>>>(keys, ctr, boxes, topB, topA);
  k_nms3  <<<1,   256, 0, stream>>>(topB, ctr, out);
}

// Round 22
// 528.049 us; speedup vs baseline: 1.6639x; 1.0555x over previous
//
#include <hip/hip_runtime.h>
#include <stdint.h>

typedef unsigned int u32;
typedef unsigned long long u64;
typedef __attribute__((ext_vector_type(8))) short v8s;   // 8 bf16 = 4 VGPR (MFMA A/B frag)
typedef __attribute__((ext_vector_type(4))) float v4f;   // MFMA C/D frag

#define HH 64
#define WW 96
#define HW 6144
#define CC 512
#define NANCH 55296
#define PRE 6000
#define POST 300
#define CAP 8192
#define PW 98
#define PH 66
#define ICPAD 40

__device__ __constant__ float c_aw[9] = {184.f,368.f,736.f,128.f,256.f,512.f,88.f,176.f,352.f};
__device__ __constant__ float c_ah[9] = {96.f,192.f,384.f,128.f,256.f,512.f,176.f,352.f,704.f};

__device__ __forceinline__ unsigned short bf16_rne(float x){
  u32 u = __float_as_uint(x);
  return (unsigned short)((u + 0x7FFFu + ((u >> 16) & 1u)) >> 16);
}
__device__ __forceinline__ u32 sortkey(float s){
  u32 u = __float_as_uint(s);
  return u ^ ((u & 0x80000000u) ? 0xFFFFFFFFu : 0x80000000u);
}

// ---------- K0: merged convert (X: 528, W-conv: 512, W-head transpose: 128 blocks) + zeroing ----------
__global__ __launch_bounds__(256) void k_cvt(const float* __restrict__ X, const float* __restrict__ Wt,
                                             const float* __restrict__ cw, const float* __restrict__ bw,
                                             unsigned short* __restrict__ Xih, unsigned short* __restrict__ Xil,
                                             unsigned short* __restrict__ Wh2, unsigned short* __restrict__ Wl2,
                                             float* __restrict__ Whd, u32* __restrict__ zero_region){
  __shared__ float Ls[64][97];
  __shared__ float Ws[4608];
  const int b = blockIdx.x, tid = threadIdx.x;
  { int gid = b*256 + tid;
    if (gid < 131072) zero_region[gid] = 0u;          // hist + hist2
    if (gid < 16) zero_region[131072 + gid] = 0u; }   // ctr
  if (b < 528){
    const int rp  = b % 66;
    const int ic0 = (b / 66) * 64;
    const bool zrow = (rp == 0 || rp == PH-1);
    if (!zrow){
      int r = rp - 1;
      for (int i = tid; i < 6144; i += 256){
        int ii = i / 96, c = i - ii*96;
        Ls[ii][c] = X[(ic0+ii)*HW + r*WW + c];
      }
    }
    __syncthreads();
    for (int i = tid; i < PW*64; i += 256){
      int cp = i >> 6, icl = i & 63;
      float x = 0.f;
      if (!zrow && cp >= 1 && cp <= 96) x = Ls[icl][cp-1];
      unsigned short h = bf16_rne(x);
      float hf = __uint_as_float(((u32)h) << 16);
      unsigned short l = bf16_rne(x - hf);
      long o = ((long)(rp*PW + cp) << 9) + ic0 + icl;
      Xih[o] = h; Xil[o] = l;
    }
  } else if (b < 1040){
    const int oc = b - 528;
    for (int i = tid; i < 4608; i += 256) Ws[i] = Wt[oc*4608 + i];
    __syncthreads();
    for (int i = tid; i < 4608; i += 256){
      int tap = i / 512, ic = i - tap*512;
      float x = Ws[ic*9 + tap];
      unsigned short h = bf16_rne(x);
      float hf = __uint_as_float(((u32)h) << 16);
      unsigned short l = bf16_rne(x - hf);
      long o = ((long)(tap*512 + oc) << 9) + ic;
      Wh2[o] = h; Wl2[o] = l;
    }
  } else {
    // head-weight transpose: Whd[gc*64 + o]
    int idx = (b - 1040)*256 + tid;
    int o  = idx >> 9;
    int gc = idx & 511;
    float v = 0.f;
    if (o < 18) v = cw[o*512 + gc];
    else if (o < 54) v = bw[(o-18)*512 + gc];
    Whd[gc*64 + o] = v;
  }
}

// ---------- K1: MFMA conv, LDS-staged + register double-buffer (R15-proven, bit-exact) ----------
__global__ __launch_bounds__(256, 1) void k_conv3(
    const unsigned short* __restrict__ Xih, const unsigned short* __restrict__ Xil,
    const unsigned short* __restrict__ Wh2, const unsigned short* __restrict__ Wl2,
    const float* __restrict__ Bc, float* __restrict__ Y)
{
  __shared__ __attribute__((aligned(16))) unsigned short Ah[6*98*ICPAD];
  __shared__ __attribute__((aligned(16))) unsigned short Al[6*98*ICPAD];
  __shared__ __attribute__((aligned(16))) unsigned short Bh[9*32*ICPAD];
  __shared__ __attribute__((aligned(16))) unsigned short Bl[9*32*ICPAD];
  const int tid  = threadIdx.x;
  const int w    = tid >> 6;
  const int lane = tid & 63;
  const int lm   = lane & 15;
  const int q    = lane >> 4;
  const int y0   = blockIdx.x * 4;
  const int oc0  = blockIdx.y * 32;

  v4f acc[6][2];
  #pragma unroll
  for (int t = 0; t < 6; ++t)
    #pragma unroll
    for (int n = 0; n < 2; ++n)
      acc[t][n] = (v4f){0.f,0.f,0.f,0.f};

  u64 ra[19][2], rb[9][2];
  auto loadSlab = [&](int icg){
    #pragma unroll
    for (int n = 0; n < 19; ++n){
      int it = tid + 256*n;
      if (it < 4704){
        int i4 = it & 7, rc = it >> 3;
        int c = rc % 98, r = rc / 98;
        long src = ((long)((y0 + r)*PW + c) << 9) + icg*32 + i4*4;
        ra[n][0] = *reinterpret_cast<const u64*>(Xih + src);
        ra[n][1] = *reinterpret_cast<const u64*>(Xil + src);
      }
    }
    #pragma unroll
    for (int n = 0; n < 9; ++n){
      int it = tid + 256*n;
      if (it < 2304){
        int i4 = it & 7, to = it >> 3;
        int oc = to & 31, tap = to >> 5;
        long src = ((long)(tap*512 + oc0 + oc) << 9) + icg*32 + i4*4;
        rb[n][0] = *reinterpret_cast<const u64*>(Wh2 + src);
        rb[n][1] = *reinterpret_cast<const u64*>(Wl2 + src);
      }
    }
  };
  auto storeSlab = [&](){
    #pragma unroll
    for (int n = 0; n < 19; ++n){
      int it = tid + 256*n;
      if (it < 4704){
        int i4 = it & 7, rc = it >> 3;
        int dst = rc*ICPAD + i4*4;
        *reinterpret_cast<u64*>(Ah + dst) = ra[n][0];
        *reinterpret_cast<u64*>(Al + dst) = ra[n][1];
      }
    }
    #pragma unroll
    for (int n = 0; n < 9; ++n){
      int it = tid + 256*n;
      if (it < 2304){
        int i4 = it & 7, to = it >> 3;
        int dst = to*ICPAD + i4*4;
        *reinterpret_cast<u64*>(Bh + dst) = rb[n][0];
        *reinterpret_cast<u64*>(Bl + dst) = rb[n][1];
      }
    }
  };

  loadSlab(0);
  for (int icg = 0; icg < 16; ++icg){
    __syncthreads();
    storeSlab();
    __syncthreads();
    if (icg < 15) loadSlab(icg + 1);
    #pragma unroll
    for (int tap = 0; tap < 9; ++tap){
      const int dy = tap / 3, dx = tap - dy*3;
      v8s ah[6], al[6], bh[2], bl[2];
      #pragma unroll
      for (int t = 0; t < 6; ++t){
        int a = ((w + dy)*98 + 16*t + lm + dx)*ICPAD + q*8;
        ah[t] = *reinterpret_cast<const v8s*>(Ah + a);
        al[t] = *reinterpret_cast<const v8s*>(Al + a);
      }
      #pragma unroll
      for (int n = 0; n < 2; ++n){
        int a = (tap*32 + n*16 + lm)*ICPAD + q*8;
        bh[n] = *reinterpret_cast<const v8s*>(Bh + a);
        bl[n] = *reinterpret_cast<const v8s*>(Bl + a);
      }
      #pragma unroll
      for (int t = 0; t < 6; ++t)
        #pragma unroll
        for (int n = 0; n < 2; ++n){
          acc[t][n] = __builtin_amdgcn_mfma_f32_16x16x32_bf16(al[t], bl[n], acc[t][n], 0, 0, 0);
          acc[t][n] = __builtin_amdgcn_mfma_f32_16x16x32_bf16(al[t], bh[n], acc[t][n], 0, 0, 0);
          acc[t][n] = __builtin_amdgcn_mfma_f32_16x16x32_bf16(ah[t], bl[n], acc[t][n], 0, 0, 0);
          acc[t][n] = __builtin_amdgcn_mfma_f32_16x16x32_bf16(ah[t], bh[n], acc[t][n], 0, 0, 0);
        }
    }
  }
  const int yrow = y0 + w;
  #pragma unroll
  for (int n = 0; n < 2; ++n){
    int oc = oc0 + n*16 + lm;
    float b = Bc[oc];
    #pragma unroll
    for (int t = 0; t < 6; ++t){
      float4 v;
      v.x = fmaxf(acc[t][n].x + b, 0.f);
      v.y = fmaxf(acc[t][n].y + b, 0.f);
      v.z = fmaxf(acc[t][n].z + b, 0.f);
      v.w = fmaxf(acc[t][n].w + b, 0.f);
      *reinterpret_cast<float4*>(Y + (long)oc*HW + yrow*WW + 16*t + q*4) = v;
    }
  }
}

// ---------------- K2: 1x1 heads + softmax + box decode (+ hist) — R21 verbatim ----------------
__global__ __launch_bounds__(256) void k_head(
    const float* __restrict__ Y, const float* __restrict__ Whd,
    const float* __restrict__ cb, const float* __restrict__ bb,
    const float* __restrict__ info,
    float* __restrict__ scores, float4* __restrict__ boxes, u32* __restrict__ hist)
{
  __shared__ float Ys[1024];
  __shared__ float Wsh[4096];
  const int tid = threadIdx.x;
  const int p0  = blockIdx.x * 16;
  const int po  = tid & 15;
  const int oj  = tid >> 4;
  float accM[4], accC[4];
  #pragma unroll
  for (int k = 0; k < 4; ++k){ accM[k] = 0.f; accC[k] = 0.f; }

  for (int c0 = 0; c0 < CC; c0 += 64){
    __syncthreads();
    for (int i = tid; i < 1024; i += 256){
      int c = i >> 4, p = i & 15;
      Ys[i] = Y[(c0 + c) * HW + p0 + p];
    }
    { const float4* src = reinterpret_cast<const float4*>(Whd + c0*64);
      float4* dst = reinterpret_cast<float4*>(Wsh);
      for (int i = tid; i < 1024; i += 256) dst[i] = src[i]; }
    __syncthreads();
    for (int c = 0; c < 64; ++c){
      float xa = Ys[c*16 + po];
      const float* wrd = Wsh + c*64 + oj;
      float wv[4] = {wrd[0], wrd[16], wrd[32], wrd[48]};
      #pragma unroll
      for (int k = 0; k < 4; ++k)
        accC[k] = __fmaf_rn(xa, wv[k], accC[k]);
    }
    #pragma unroll
    for (int k = 0; k < 4; ++k){ accM[k] += accC[k]; accC[k] = 0.f; }
  }
  __syncthreads();
  #pragma unroll
  for (int k = 0; k < 4; ++k){
    int o = oj + 16*k;
    float bias = (o < 18) ? cb[o] : ((o < 54) ? bb[o - 18] : 0.f);
    Ys[po*64 + o] = accM[k] + bias;
  }
  __syncthreads();
  float imH = info[0], imW = info[1], imS = info[2];
  for (int it = tid; it < 144; it += 256){
    int pl = it / 9;
    int a  = it - pl*9;
    const float* L = Ys + pl*64;
    float l0 = L[a], l1 = L[9 + a];
    float mx = fmaxf(l0, l1);
    float e0 = expf(l0 - mx), e1 = expf(l1 - mx);
    float sc = e1 / (e0 + e1);
    float d0 = L[18 + a*4 + 0], d1 = L[18 + a*4 + 1];
    float d2 = L[18 + a*4 + 2], d3 = L[18 + a*4 + 3];
    int pos = p0 + pl;
    int yy = pos / 96;
    int xx = pos - yy * 96;
    float aw = c_aw[a], ah = c_ah[a];
    float acx = (float)(xx * 16 + 8);
    float acy = (float)(yy * 16 + 8);
    float cx = __fadd_rn(__fmul_rn(d0, aw), acx);
    float cy = __fadd_rn(__fmul_rn(d1, ah), acy);
    float pw = __fmul_rn(expf(d2), aw);
    float ph = __fmul_rn(expf(d3), ah);
    float hx = __fmul_rn(0.5f, pw);
    float hy = __fmul_rn(0.5f, ph);
    float x1 = fminf(fmaxf(__fadd_rn(cx, -hx), 0.f), imW - 1.f);
    float y1 = fminf(fmaxf(__fadd_rn(cy, -hy), 0.f), imH - 1.f);
    float x2 = fminf(fmaxf(__fadd_rn(cx,  hx), 0.f), imW - 1.f);
    float y2 = fminf(fmaxf(__fadd_rn(cy,  hy), 0.f), imH - 1.f);
    float ms = 16.f * imS;
    bool keep = ((x2 - x1 + 1.f) >= ms) && ((y2 - y1 + 1.f) >= ms);
    int g = pos * 9 + a;
    float val = keep ? sc : -__builtin_inff();
    scores[g] = val;
    boxes[g]  = make_float4(x1, y1, x2, y2);
    atomicAdd(&hist[sortkey(val) >> 16], 1u);
  }
}

// ---------- K3: fused selection — R22: float4 score scans in phases 2 & 4 ----------
__global__ __launch_bounds__(1024) void k_sel(const u32* __restrict__ hist, u32* __restrict__ hist2,
                                              const float* __restrict__ scores,
                                              u32* __restrict__ ctr, u64* __restrict__ keys){
  __shared__ u32 cs[1024];
  __shared__ u32 bs[64];
  __shared__ int selg;
  __shared__ u32 afterv, T16s, aboves, K32s;
  const int t = threadIdx.x;
  const int b0 = t * 64;

  if (t == 0) selg = -1;
  __syncthreads();
  { u32 s = 0;
    for (int i = 0; i < 64; ++i) s += hist[b0 + i];
    cs[t] = s; }
  __syncthreads();
  for (int off = 1; off < 1024; off <<= 1){
    u32 v = cs[t];
    u32 ad = (t + off < 1024) ? cs[t + off] : 0u;
    __syncthreads();
    cs[t] = v + ad;
    __syncthreads();
  }
  { u32 here  = cs[t];
    u32 after = (t < 1023) ? cs[t + 1] : 0u;
    if (here >= 6000u && after < 6000u){ selg = t; afterv = after; } }
  __syncthreads();
  { int g = selg;
    if (g >= 0 && t < 64) bs[t] = hist[g*64 + t];
    __syncthreads();
    if (t == 0){
      if (g < 0){ T16s = 0u; aboves = 0u; }
      else {
        u32 acc = afterv;
        for (int b = 63; b >= 0; --b){
          u32 h = bs[b];
          acc += h;
          if (acc >= 6000u){ T16s = (u32)(g*64 + b); aboves = acc - h; break; }
        }
      }
    } }
  __syncthreads();

  // phase 2: hist2 — float4 scan (13824 vec loads; same values -> same histogram)
  { u32 pfx = T16s;
    const float4* s4 = reinterpret_cast<const float4*>(scores);
    for (int i = t; i < NANCH/4; i += 1024){
      float4 v = s4[i];
      u32 k0 = sortkey(v.x), k1 = sortkey(v.y), k2 = sortkey(v.z), k3 = sortkey(v.w);
      if ((k0 >> 16) == pfx) atomicAdd(&hist2[k0 & 0xFFFFu], 1u);
      if ((k1 >> 16) == pfx) atomicAdd(&hist2[k1 & 0xFFFFu], 1u);
      if ((k2 >> 16) == pfx) atomicAdd(&hist2[k2 & 0xFFFFu], 1u);
      if ((k3 >> 16) == pfx) atomicAdd(&hist2[k3 & 0xFFFFu], 1u);
    } }
  __threadfence();
  __syncthreads();

  if (t == 0) selg = -1;
  __syncthreads();
  const u32 target = 6000u - aboves;
  { u32 s = 0;
    for (int i = 0; i < 64; ++i) s += hist2[b0 + i];
    cs[t] = s; }
  __syncthreads();
  for (int off = 1; off < 1024; off <<= 1){
    u32 v = cs[t];
    u32 ad = (t + off < 1024) ? cs[t + off] : 0u;
    __syncthreads();
    cs[t] = v + ad;
    __syncthreads();
  }
  { u32 here  = cs[t];
    u32 after = (t < 1023) ? cs[t + 1] : 0u;
    if (here >= target && after < target){ selg = t; afterv = after; } }
  __syncthreads();
  { int g = selg;
    if (g >= 0 && t < 64) bs[t] = hist2[g*64 + t];
    __syncthreads();
    if (t == 0){
      if (g < 0) K32s = (T16s << 16);
      else {
        u32 acc = afterv;
        for (int b = 63; b >= 0; --b){
          u32 h = bs[b];
          acc += h;
          if (acc >= target){ K32s = (T16s << 16) | (u32)(g*64 + b); break; }
        }
      }
      ctr[4] = 6000u;
    } }
  __syncthreads();

  // phase 4: compact — float4 scan (compaction order is irrelevant: k_rank re-ranks exactly)
  { u32 K = K32s;
    const float4* s4 = reinterpret_cast<const float4*>(scores);
    for (int i = t; i < NANCH/4; i += 1024){
      float4 v = s4[i];
      u32 kk[4] = {sortkey(v.x), sortkey(v.y), sortkey(v.z), sortkey(v.w)};
      #pragma unroll
      for (int u = 0; u < 4; ++u){
        if (kk[u] >= K){
          u32 pos = atomicAdd(&ctr[0], 1u);
          if (pos < CAP) keys[pos] = ((u64)kk[u] << 32) | (u64)(u32)(~(u32)(i*4 + u));
        }
      }
    } }
}

// ---------------- K-rank (verbatim) ----------------
__global__ __launch_bounds__(128) void k_rank(const u64* __restrict__ keys, u32* __restrict__ ctr,
                                              const float4* __restrict__ boxes,
                                              float4* __restrict__ topB, float* __restrict__ topA){
  __shared__ u64 ks[2048];
  const int t  = threadIdx.x;
  const int gi = blockIdx.x * 128 + t;
  u32 count = ctr[0]; if (count > CAP) count = CAP;
  u64 my = (gi < (int)count) ? keys[gi] : 0ull;
  int rank = 0;
  for (int c0 = 0; c0 < CAP; c0 += 2048){
    __syncthreads();
    for (int s = t; s < 2048; s += 128){
      int j = c0 + s;
      ks[s] = (j < (int)count) ? keys[j] : 0ull;
    }
    __syncthreads();
    if (gi < (int)count){
      const ulonglong2* kp = reinterpret_cast<const ulonglong2*>(ks);
      #pragma unroll 8
      for (int s = 0; s < 1024; ++s){
        ulonglong2 kv = kp[s];
        rank += (kv.x > my) + (kv.y > my);
      }
    }
  }
  if (gi < (int)count && rank < PRE){
    if (!((my >> 32) & 0x80000000ull))
      atomicMin((int*)(ctr + 4), rank);
    u32 idx = ~(u32)my;
    float4 bv = make_float4(0.f,0.f,0.f,0.f);
    float area = 1.f;
    if (idx < NANCH){
      bv = boxes[idx];
      area = (bv.z - bv.x + 1.f) * (bv.w - bv.y + 1.f);
    }
    topB[rank] = bv;
    topA[rank] = area;
  }
}

// ---------- K5: chunked exact NMS — 4-wave Phase A split + wave-0 Phase B (R20-proven) ----------
__global__ __launch_bounds__(256) void k_nms3(const float4* __restrict__ topB,
                                              const u32* __restrict__ ctr, float* __restrict__ out){
  __shared__ float4 kb[POST];
  __shared__ float  ka[POST];
  __shared__ u64    am[4];
  __shared__ int    nkS;
  const int tid  = threadIdx.x;
  const int wv   = tid >> 6;
  const int lane = tid & 63;
  int validN = (int)ctr[0];
  int finN   = (int)ctr[4];
  if (finN < validN) validN = finN;
  if (validN > PRE)  validN = PRE;
  if (tid == 0) nkS = 0;
  __syncthreads();

  float4 bnx = make_float4(0.f,0.f,0.f,0.f);
  if (lane < validN) bnx = topB[lane];

  for (int base = 0; base < validN; base += 64){
    int nk = nkS;
    if (nk >= POST) break;
    int c = base + lane;
    bool alive = (c < validN);
    float4 b = bnx;
    float ar = alive ? (b.z - b.x + 1.f) * (b.w - b.y + 1.f) : 1.f;
    { int cn = base + 64 + lane;
      if (cn < validN) bnx = topB[cn]; }
    int j = wv;
    for (; j + 28 < nk; j += 32){
      float4 kx[8]; float kaa[8];
      #pragma unroll
      for (int u = 0; u < 8; ++u){ kx[u] = kb[j + 4*u]; kaa[u] = ka[j + 4*u]; }
      #pragma unroll
      for (int u = 0; u < 8; ++u){
        float xx1 = fmaxf(kx[u].x, b.x);
        float yy1 = fmaxf(kx[u].y, b.y);
        float xx2 = fminf(kx[u].z, b.z);
        float yy2 = fminf(kx[u].w, b.w);
        float iw = fmaxf(xx2 - xx1 + 1.f, 0.f);
        float ih = fmaxf(yy2 - yy1 + 1.f, 0.f);
        float inter = iw * ih;
        float iou = inter / (kaa[u] + ar - inter);
        if (iou > 0.7f) alive = false;
      }
    }
    for (; j < nk; j += 4){
      float4 kbx = kb[j];
      float kar = ka[j];
      float xx1 = fmaxf(kbx.x, b.x);
      float yy1 = fmaxf(kbx.y, b.y);
      float xx2 = fminf(kbx.z, b.z);
      float yy2 = fminf(kbx.w, b.w);
      float iw = fmaxf(xx2 - xx1 + 1.f, 0.f);
      float ih = fmaxf(yy2 - yy1 + 1.f, 0.f);
      float inter = iw * ih;
      float iou = inter / (kar + ar - inter);
      if (iou > 0.7f) alive = false;
    }
    { u64 bal = __ballot(alive);
      if (lane == 0) am[wv] = bal; }
    __syncthreads();
    if (wv == 0){
      u64 comb = am[0] & am[1] & am[2] & am[3];
      alive = ((comb >> lane) & 1ull) != 0ull;
      int nkl = nk;
      while (nkl < POST){
        u64 bal = __ballot(alive);
        if (!bal) break;
        int L = (int)__ffsll((unsigned long long)bal) - 1;
        float px = __shfl(b.x, L, 64);
        float py = __shfl(b.y, L, 64);
        float pz = __shfl(b.z, L, 64);
        float pw = __shfl(b.w, L, 64);
        float pa = __shfl(ar, L, 64);
        if (lane == 0){
          kb[nkl] = make_float4(px, py, pz, pw);
          ka[nkl] = pa;
        }
        nkl++;
        if (lane == L) alive = false;
        if (alive){
          float xx1 = fmaxf(px, b.x);
          float yy1 = fmaxf(py, b.y);
          float xx2 = fminf(pz, b.z);
          float yy2 = fminf(pw, b.w);
          float iw = fmaxf(xx2 - xx1 + 1.f, 0.f);
          float ih = fmaxf(yy2 - yy1 + 1.f, 0.f);
          float inter = iw * ih;
          float iou = inter / (pa + ar - inter);
          if (iou > 0.7f) alive = false;
        }
      }
      if (lane == 0) nkS = nkl;
    }
    __syncthreads();
  }
  int nk = nkS;
  for (int q = tid; q < 1500; q += 256){
    int r = q / 5, c = q - r*5;
    float v = 0.f;
    if (r < nk && c > 0){
      float4 bx = kb[r];
      v = (c == 1) ? bx.x : (c == 2) ? bx.y : (c == 3) ? bx.z : bx.w;
    }
    out[q] = v;
  }
}

// ---------------- launch ----------------
extern "C" void kernel_launch(void* const* d_in, const int* in_sizes, int n_in,
                              void* d_out, int out_size, void* d_ws, size_t ws_size,
                              hipStream_t stream)
{
  const float* fm   = (const float*)d_in[0];
  const float* info = (const float*)d_in[1];
  const float* cw3  = (const float*)d_in[2];
  const float* cb3  = (const float*)d_in[3];
  const float* clw  = (const float*)d_in[4];
  const float* clb  = (const float*)d_in[5];
  const float* bbw  = (const float*)d_in[6];
  const float* bbb  = (const float*)d_in[7];
  float* out = (float*)d_out;

  char* base = (char*)d_ws;
  u32*   hist   = (u32*)  (base + 0);          // 65536 u32
  u32*   hist2  = (u32*)  (base + 262144);     // 65536 u32
  u32*   ctr    = (u32*)  (base + 524288);     // [0]=count [4]=finiteN
  float* Y      = (float*)(base + 524544);     // 12.58 MB
  float* scores = (float*)(base + 13107456);
  float4* boxes = (float4*)(base + 13328640);
  u64*   keys   = (u64*)  (base + 14213376);
  float4* topB  = (float4*)(base + 14278912);
  float* topA   = (float*)(base + 14375168);
  unsigned short* Xih = (unsigned short*)(base + 14399488);
  unsigned short* Xil = (unsigned short*)(base + 21022720);
  unsigned short* Wh2 = (unsigned short*)(base + 27645952);
  unsigned short* Wl2 = (unsigned short*)(base + 32364544);
  float* Whd = (float*)(base + 37083136);      // 512*64 f32
  // total ws use: ~37.2 MB

  k_cvt   <<<1168, 256, 0, stream>>>(fm, cw3, clw, bbw, Xih, Xil, Wh2, Wl2, Whd, (u32*)base);
  k_conv3 <<<dim3(16, 16), 256, 0, stream>>>(Xih, Xil, Wh2, Wl2, cb3, Y);
  k_head  <<<384, 256, 0, stream>>>(Y, Whd, clb, bbb, info, scores, boxes, hist);
  k_sel   <<<1,  1024, 0, stream>>>(hist, hist2, scores, ctr, keys);
  k_rank  <<<64,  128, 0, stream>>>(keys, ctr, boxes, topB, topA);
  k_nms3  <<<1,   256, 0, stream>>>(topB, ctr, out);
}